// Round 7
// baseline (13631.441 us; speedup 1.0000x reference)
//
#include <hip/hip_runtime.h>

typedef unsigned int uint32;
typedef unsigned short u16;
typedef unsigned long long u64;
typedef __attribute__((ext_vector_type(8))) short bf8;   // 8 x bf16 (4 VGPRs)
typedef __attribute__((ext_vector_type(4))) float f4;    // 4 x f32

#define DEV static __device__ __forceinline__

DEV f4 MFMA(bf8 a, bf8 b, f4 c) {
  return __builtin_amdgcn_mfma_f32_16x16x32_bf16(a, b, c, 0, 0, 0);
}
DEV u16 f2bf(float f) {
  uint32 u = __float_as_uint(f);
  return (u16)((u + 0x7FFFu + ((u >> 16) & 1u)) >> 16);
}
DEV float bf2f(u16 h) { return __uint_as_float(((uint32)h) << 16); }
DEV float bfLO(uint32 u) { return __uint_as_float(u << 16); }
DEV float bfHI(uint32 u) { return __uint_as_float(u & 0xFFFF0000u); }
DEV float sigmoid_(float x) { return 1.f / (1.f + __expf(-x)); }
DEV float tanh_(float x) {
  float cx = fminf(fmaxf(x, -15.f), 15.f);
  float e = __expf(2.f * cx);
  return (e - 1.f) / (e + 1.f);
}

namespace L {
// sizes: B=32,S=60,T=59,V=50000,E=300(pad320),H=512,3H=1536
constexpr size_t o_flags  = 0;          // 1024 int (unused; kept zeroed)
constexpr size_t o_rowsum = 4096;       // 1920 f32
constexpr size_t o_bcomb  = 11776;      // 1536 f32
constexpr size_t o_gistat = 17920;      // 32x1536 f32
constexpr size_t o_xbuf   = 214528;     // 2x32x1024 bf16  (attn | h) - state0 handoff
constexpr size_t o_henc   = 345600;     // (unused)
constexpr size_t o_haff   = 411136;     // (unused)
constexpr size_t o_cat    = 476672;     // 32x1024 bf16 (state_enc | state_aff)
constexpr size_t o_Kbuf   = 542208;     // 1920x512 bf16 (row = s*32+b)
constexpr size_t o_KA     = 2508288;    // 1920x512 bf16
constexpr size_t o_embP   = 4474368;    // 1920x320 bf16
constexpr size_t o_embA   = 5703168;    // 1920x320 bf16
constexpr size_t o_embD   = 6931968;    // 1888x320 bf16
constexpr size_t o_encWi  = 8140288;    // 1536x320 bf16
constexpr size_t o_affWi  = 9123328;    // 1536x320 bf16
constexpr size_t o_Whe    = 10106368;   // 1536x512 bf16
constexpr size_t o_Wha    = 11679232;   // 1536x512 bf16
constexpr size_t o_decWi  = 13252096;   // 1536x512 bf16
constexpr size_t o_WlT    = 14824960;   // 1328x512 bf16
constexpr size_t o_Wa     = 16184832;   // 512x512 bf16
constexpr size_t o_Wp     = 16709120;   // 512x1024 bf16
constexpr size_t o_WcB    = 17757696;   // 512x512 bf16 (Wc row-major)
constexpr size_t o_Wcomb  = 18281984;   // 1536x1328 f32
constexpr size_t o_WdE    = 26441216;   // 1536x320 bf16
constexpr size_t o_WdA    = 27424256;   // 1536x512 bf16
constexpr size_t o_Wd2    = 28997120;   // 1536x1024 bf16 (Wcomb_attn | dec_Wh)
constexpr size_t o_giE    = 32142848;   // 1920x1536 f32
constexpr size_t o_giA    = 43939328;   // 1920x1536 f32
constexpr size_t o_giD    = 55735808;   // 1888x1536 f32
constexpr size_t o_outsB  = 67335680;   // 1920x1024 bf16 (row = b*59+t : h|attn)
constexpr size_t o_WvB    = 71267840;   // 50176x1024 bf16 (optional)
constexpr size_t WS_FULL  = 174028288;
constexpr size_t WOFF = 94400000;       // weights output offset (floats)
}

// ---------------- prep: embedding gathers -> bf16, padded K=320 ----------------
__global__ __launch_bounds__(256) void kp_gather(
    const int* __restrict__ posts, const int* __restrict__ resp,
    const float* __restrict__ emb, const float* __restrict__ aemb, char* ws)
{
  using namespace L;
  const int gid = blockIdx.x * 256 + threadIdx.x;
  const int r = gid / 320, e = gid - r * 320;
  u16* embP = (u16*)(ws + o_embP);
  u16* embA = (u16*)(ws + o_embA);
  u16* embD = (u16*)(ws + o_embD);
  if (r < 1920) {
    const int b = r & 31, s = r >> 5;
    const int tok = posts[b * 60 + s];
    embP[r * 320 + e] = f2bf(e < 300 ? emb[(size_t)tok * 300 + e] : 0.f);
    embA[r * 320 + e] = f2bf(e < 300 ? aemb[(size_t)tok * 300 + e] : 0.f);
  } else if (r < 3808) {
    const int r2 = r - 1920;
    const int b = r2 & 31, t = r2 >> 5;
    const int tok = resp[b * 60 + t];
    embD[r2 * 320 + e] = f2bf(e < 300 ? emb[(size_t)tok * 300 + e] : 0.f);
  }
}

// ---------------- prep: weight conversions / transposes / zeroing ----------------
__global__ __launch_bounds__(256) void kp_wconv(
    const float* __restrict__ encWi, const float* __restrict__ affWi,
    const float* __restrict__ encWh, const float* __restrict__ affWh,
    const float* __restrict__ dWi, const float* __restrict__ Wl,
    const float* __restrict__ Wa, const float* __restrict__ Wp,
    const float* __restrict__ Wc, char* ws)
{
  using namespace L;
  long gid = (long)blockIdx.x * 256 + threadIdx.x;
  if (gid < 983040) {  // enc_Wi / aff_Wi -> [1536][320] bf16 (pad)
    const int g = gid >= 491520;
    const long u = gid - (g ? 491520 : 0);
    const int n = (int)(u / 320), e = (int)(u - (long)n * 320);
    const float* src = g ? affWi : encWi;
    u16* dst = (u16*)(ws + (g ? o_affWi : o_encWi));
    dst[u] = f2bf(e < 300 ? src[(size_t)n * 300 + e] : 0.f);
    return;
  }
  gid -= 983040;
  if (gid < 2359296) {  // enc_Wh / aff_Wh / dec_Wi -> bf16 direct
    const int g = (int)(gid / 786432);
    const long u = gid - (long)g * 786432;
    const float* src = g == 0 ? encWh : (g == 1 ? affWh : dWi);
    u16* dst = (u16*)(ws + (g == 0 ? o_Whe : (g == 1 ? o_Wha : o_decWi)));
    dst[u] = f2bf(src[u]);
    return;
  }
  gid -= 2359296;
  if (gid < 679936) {  // Wl^T -> [1328][512] bf16 (pad rows)
    const int j = (int)(gid >> 9), k = (int)(gid & 511);
    ((u16*)(ws + o_WlT))[gid] = f2bf(j < 1324 ? Wl[(size_t)k * 1324 + j] : 0.f);
    return;
  }
  gid -= 679936;
  if (gid < 262144) { ((u16*)(ws + o_Wa))[gid] = f2bf(Wa[gid]); return; }
  gid -= 262144;
  if (gid < 524288) { ((u16*)(ws + o_Wp))[gid] = f2bf(Wp[gid]); return; }
  gid -= 524288;
  if (gid < 131072) {  // WcB: straight bf16 row-major copy (2 elems per gid)
    const long e = gid * 2;
    const uint32 lo = f2bf(Wc[e]);
    const uint32 hi = f2bf(Wc[e + 1]);
    ((uint32*)(ws + o_WcB))[gid] = lo | (hi << 16);
    return;
  }
  gid -= 131072;
  if (gid < 2944) {  // zero flags + rowsum
    if (gid < 1024) ((uint32*)(ws + o_flags))[gid] = 0;
    else ((uint32*)(ws + o_rowsum))[gid - 1024] = 0;
    return;
  }
  gid -= 2944;
  if (gid < 16384) {  // zero: outsB pad rows
    ((uint32*)(ws + o_outsB + (size_t)1888 * 1024 * 2))[gid] = 0;
  }
}

// ---------------- prep: bcomb = dec_Wi @ bl + dec_bi ----------------
__global__ __launch_bounds__(256) void kp_bcomb(
    const float* __restrict__ dWi, const float* __restrict__ bl,
    const float* __restrict__ dbi, char* ws)
{
  const int i = blockIdx.x * 256 + threadIdx.x;
  if (i >= 1536) return;
  float a = dbi[i];
  for (int k = 0; k < 512; ++k) a += dWi[(size_t)i * 512 + k] * bl[k];
  ((float*)(ws + L::o_bcomb))[i] = a;
}

// ---------------- prep: Wv -> bf16 (padded rows) ----------------
__global__ __launch_bounds__(256) void kp_wv(const float* __restrict__ Wv, char* ws)
{
  const long gid = (long)blockIdx.x * 256 + threadIdx.x;
  const int r = (int)(gid >> 8), q = (int)(gid & 255);
  u16* WvB = (u16*)(ws + L::o_WvB);
  uint2 o;
  if (r < 50000) {
    const float4 f = *(const float4*)(Wv + (size_t)r * 1024 + q * 4);
    o.x = (uint32)f2bf(f.x) | ((uint32)f2bf(f.y) << 16);
    o.y = (uint32)f2bf(f.z) | ((uint32)f2bf(f.w) << 16);
  } else { o.x = 0u; o.y = 0u; }
  *(uint2*)(WvB + (size_t)r * 1024 + q * 4) = o;
}

// ---------------- prep: split Wcomb into bf16 pieces ----------------
__global__ __launch_bounds__(256) void kp_pack2(
    const float* __restrict__ Wcomb, const float* __restrict__ dWh, char* ws)
{
  using namespace L;
  long gid = (long)blockIdx.x * 256 + threadIdx.x;
  if (gid < 491520) {  // Wd_emb [1536][320] <- Wcomb[:,0:300]
    const int n = (int)(gid / 320), e = (int)(gid - (long)n * 320);
    ((u16*)(ws + o_WdE))[gid] = f2bf(e < 300 ? Wcomb[(size_t)n * 1328 + e] : 0.f);
    return;
  }
  gid -= 491520;
  if (gid < 786432) {  // Wd_aff [1536][512] <- Wcomb[:,300:812]
    const int n = (int)(gid >> 9), k = (int)(gid & 511);
    ((u16*)(ws + o_WdA))[gid] = f2bf(Wcomb[(size_t)n * 1328 + 300 + k]);
    return;
  }
  gid -= 786432;
  if (gid < 1572864) {  // Wd2 [1536][1024] = [Wcomb[:,812:1324] | dec_Wh]
    const int n = (int)(gid >> 10), k = (int)(gid & 1023);
    const float v = (k < 512) ? Wcomb[(size_t)n * 1328 + 812 + k]
                              : dWh[(size_t)n * 512 + (k - 512)];
    ((u16*)(ws + o_Wd2))[gid] = f2bf(v);
  }
}

// ---------------- generic MFMA GEMM: C[M][N] = A[M][Kp] * B[N][Kp]^T (+bias) ----------------
__global__ __launch_bounds__(256) void k_gemm_nt(
    const u16* __restrict__ A, const u16* __restrict__ Bm,
    float* __restrict__ C, const float* __restrict__ bias,
    const int M, const int N, const int Kp)
{
  const int mt = blockIdx.x, cb = blockIdx.y;
  const int w = threadIdx.x >> 6, lane = threadIdx.x & 63;
  const int l15 = lane & 15, lhi = lane >> 4;
  const u16* arow = A + (size_t)(mt * 16 + l15) * Kp + lhi * 8;
  const int c0 = cb * 256 + w * 64;
  f4 acc[4];
#pragma unroll
  for (int nn = 0; nn < 4; ++nn) acc[nn] = (f4){0.f, 0.f, 0.f, 0.f};
  for (int k = 0; k < Kp; k += 32) {
    const bf8 a = *(const bf8*)(arow + k);
#pragma unroll
    for (int nn = 0; nn < 4; ++nn) {
      const int cs = c0 + nn * 16;
      if (cs < N) {
        const bf8 b = *(const bf8*)(Bm + (size_t)(cs + l15) * Kp + k + lhi * 8);
        acc[nn] = MFMA(a, b, acc[nn]);
      }
    }
  }
#pragma unroll
  for (int nn = 0; nn < 4; ++nn) {
    const int cs = c0 + nn * 16;
    if (cs >= N) continue;
    const int c = cs + l15;
    const float bb = bias ? bias[c] : 0.f;
#pragma unroll
    for (int j = 0; j < 4; ++j) {
      const int r = mt * 16 + lhi * 4 + j;
      C[(size_t)r * N + c] = acc[nn][j] + bb;
    }
  }
}

// ---------------- encoder: batch-diagonal, 64 independent blocks (g,b) --------
// One block per (GRU, batch). h lives in LDS; NO inter-block sync at all.
// MFMA batch=1: B-frag row 0 = h, rows 1-15 zero; results in lanes l15==0.
__global__ __launch_bounds__(512, 1) void k_enc(
    char* __restrict__ ws, const float* __restrict__ enc_bh,
    const float* __restrict__ aff_bh)
{
  using namespace L;
  const int tid = threadIdx.x, blk = blockIdx.x;
  const int wave = tid >> 6, lane = tid & 63;
  const int l15 = lane & 15, lhi = lane >> 4;
  const int g = blk >> 5, b = blk & 31;
  const u16* Wh = (const u16*)(ws + (g ? o_Wha : o_Whe));
  const float* gi = (const float*)(ws + (g ? o_giA : o_giE));
  const float* bh = g ? aff_bh : enc_bh;
  u16* cat = (u16*)(ws + o_cat);
  u16* Kb = (u16*)(ws + o_Kbuf);

  __shared__ u16 h_lds[512];
  __shared__ float gate_lds[1536];

  if (tid < 128) *(u64*)&h_lds[tid * 4] = 0;
  f4 bhr4 = {0.f,0.f,0.f,0.f}, bhz4 = bhr4, bhn4 = bhr4;
  if (tid < 128) {
    const int c0 = tid * 4;
    bhr4 = *(const f4*)(bh + c0);
    bhz4 = *(const f4*)(bh + 512 + c0);
    bhn4 = *(const f4*)(bh + 1024 + c0);
  }
  __syncthreads();

  const bf8 zf = {0, 0, 0, 0, 0, 0, 0, 0};
  for (int s = 0; s < 60; ++s) {
    // gate_lds[c] = sum_k h[k] * Wh[c][k]  (96 ctiles over 8 waves)
    bf8 xf[16];
#pragma unroll
    for (int kc = 0; kc < 16; ++kc)
      xf[kc] = (l15 == 0) ? *(const bf8*)&h_lds[kc * 32 + lhi * 8] : zf;
    f4 acc[12];
#pragma unroll
    for (int ci = 0; ci < 12; ++ci) acc[ci] = (f4){0.f, 0.f, 0.f, 0.f};
#pragma unroll
    for (int ci = 0; ci < 12; ++ci) {
      const int ctile = wave + ci * 8;
      const u16* wrow = Wh + (size_t)(ctile * 16 + l15) * 512 + lhi * 8;
#pragma unroll
      for (int kc = 0; kc < 16; ++kc)
        acc[ci] = MFMA(*(const bf8*)(wrow + kc * 32), xf[kc], acc[ci]);
    }
    if (l15 == 0) {
#pragma unroll
      for (int ci = 0; ci < 12; ++ci) {
        const int ctile = wave + ci * 8;
#pragma unroll
        for (int j = 0; j < 4; ++j)
          gate_lds[ctile * 16 + lhi * 4 + j] = acc[ci][j];
      }
    }
    __syncthreads();
    if (tid < 128) {
      const int c0 = tid * 4;
      const float* gr = gi + (size_t)(s * 32 + b) * 1536;
      const f4 g0 = *(const f4*)(gr + c0);
      const f4 g1 = *(const f4*)(gr + 512 + c0);
      const f4 g2 = *(const f4*)(gr + 1024 + c0);
      const f4 a0 = *(const f4*)&gate_lds[c0];
      const f4 a1 = *(const f4*)&gate_lds[512 + c0];
      const f4 a2 = *(const f4*)&gate_lds[1024 + c0];
      const u64 hq = *(const u64*)&h_lds[c0];
      u64 pk = 0;
#pragma unroll
      for (int j = 0; j < 4; ++j) {
        const float r = sigmoid_(g0[j] + a0[j] + bhr4[j]);
        const float z = sigmoid_(g1[j] + a1[j] + bhz4[j]);
        const float n = tanh_(g2[j] + r * (a2[j] + bhn4[j]));
        const float hold = bf2f((u16)(hq >> (16 * j)));
        pk |= (u64)f2bf((1.f - z) * n + z * hold) << (16 * j);
      }
      *(u64*)&h_lds[c0] = pk;
      if (g) *(u64*)(Kb + (size_t)(s * 32 + b) * 512 + c0) = pk;
      if (s == 59) *(u64*)(cat + b * 1024 + g * 512 + c0) = pk;
    }
    __syncthreads();
  }
}

// ---------------- mid kernel: state0 | gi_static | KA (no sync needed) ----------
__global__ __launch_bounds__(256) void k_mid(char* __restrict__ ws,
                                             const float* __restrict__ bp)
{
  using namespace L;
  const int tid = threadIdx.x, blk = blockIdx.x;
  const int wave = tid >> 6, lane = tid & 63;
  const int l15 = lane & 15, lhi = lane >> 4;
  u16* xb = (u16*)(ws + o_xbuf);
  u16* cat = (u16*)(ws + o_cat);
  u16* Kb = (u16*)(ws + o_Kbuf);

  if (blk < 16) {  // state0 = tanh(cat @ Wp^T + bp) -> xbuf[0]; zero attn half
    const u16* Wp_ = (const u16*)(ws + o_Wp);
    const int wid = blk * 4 + wave;
    const int btile = wid >> 5, ctile = wid & 31;
    const int bl = btile * 16 + l15;
    const int c0 = ctile * 16 + lhi * 4;
    const u16* arow = Wp_ + (size_t)(ctile * 16 + l15) * 1024 + lhi * 8;
    const u16* brow = cat + bl * 1024 + lhi * 8;
    f4 acc = {0.f, 0.f, 0.f, 0.f};
    for (int k = 0; k < 1024; k += 32)
      acc = MFMA(*(const bf8*)(arow + k), *(const bf8*)(brow + k), acc);
    const f4 bp4 = *(const f4*)(bp + c0);
    u64 pk = 0;
#pragma unroll
    for (int j = 0; j < 4; ++j)
      pk |= (u64)f2bf(tanh_(acc[j] + bp4[j])) << (16 * j);
    *(u64*)(xb + bl * 1024 + 512 + c0) = pk;
    *(u64*)(xb + bl * 1024 + c0) = 0;          // init attn = 0
  } else if (blk < 32) {  // gi_static = ctx_aff @ Wd_aff^T + bcomb
    const u16* WdA = (const u16*)(ws + o_WdA);
    const float* bco = (const float*)(ws + o_bcomb);
    float* gst = (float*)(ws + o_gistat);
    const int wid = (blk - 16) * 4 + wave;
    const int btile = wid >> 5, ctb = wid & 31;
    const int bl = btile * 16 + l15;
    const int c0 = ctb * 16 + lhi * 4;
    const u16* brow = cat + bl * 1024 + 512 + lhi * 8;
    const u16* a0p = WdA + (size_t)(ctb * 16 + l15) * 512 + lhi * 8;
    const u16* a1p = a0p + (size_t)512 * 512;
    const u16* a2p = a1p + (size_t)512 * 512;
    f4 a0 = {0.f, 0.f, 0.f, 0.f}, a1 = a0, a2 = a0;
    for (int k = 0; k < 512; k += 32) {
      const bf8 bfr = *(const bf8*)(brow + k);
      a0 = MFMA(*(const bf8*)(a0p + k), bfr, a0);
      a1 = MFMA(*(const bf8*)(a1p + k), bfr, a1);
      a2 = MFMA(*(const bf8*)(a2p + k), bfr, a2);
    }
    const f4 v0 = *(const f4*)(bco + c0);
    const f4 v1 = *(const f4*)(bco + 512 + c0);
    const f4 v2 = *(const f4*)(bco + 1024 + c0);
    *(f4*)(gst + bl * 1536 + c0) = a0 + v0;
    *(f4*)(gst + bl * 1536 + 512 + c0) = a1 + v1;
    *(f4*)(gst + bl * 1536 + 1024 + c0) = a2 + v2;
  } else {  // KA = K @ Wa^T
    const u16* Wa_ = (const u16*)(ws + o_Wa);
    u16* KAp = (u16*)(ws + o_KA);
    const int widK = (blk - 32) * 4 + wave;
    for (int task = widK; task < 3840; task += 192) {
      const int mt = task >> 5, ct = task & 31;
      const int m = mt * 16 + l15;
      const int c0 = ct * 16 + lhi * 4;
      const u16* arow = Wa_ + (size_t)(ct * 16 + l15) * 512 + lhi * 8;
      const u16* brow = Kb + (size_t)m * 512 + lhi * 8;
      f4 acc = {0.f, 0.f, 0.f, 0.f};
      for (int k = 0; k < 512; k += 32)
        acc = MFMA(*(const bf8*)(arow + k), *(const bf8*)(brow + k), acc);
      u64 pk = 0;
#pragma unroll
      for (int j = 0; j < 4; ++j) pk |= (u64)f2bf(acc[j]) << (16 * j);
      *(u64*)(KAp + (size_t)m * 512 + c0) = pk;
    }
  }
}

// ---------------- decoder: batch-diagonal, 32 independent blocks --------------
// Block b owns batch b end-to-end: GRU + attention, state in LDS, no inter-block
// sync. GRU/attn GEMVs via MFMA (batch=1 in B row 0). n-gate split kept by
// separating the K halves (kb=0: attn part -> gnx; kb=1: h part -> gate_lds).
__global__ __launch_bounds__(512, 1) void k_dec(
    char* __restrict__ ws, float* __restrict__ out,
    const float* __restrict__ dec_bh, const float* __restrict__ bc)
{
  using namespace L;
  const int tid = threadIdx.x, b = blockIdx.x;
  const int wave = tid >> 6, lane = tid & 63;
  const int l15 = lane & 15, lhi = lane >> 4;
  const u16* Wd2 = (const u16*)(ws + o_Wd2);
  const u16* WcB = (const u16*)(ws + o_WcB);
  const u16* KAp = (const u16*)(ws + o_KA);
  const u16* Kb = (const u16*)(ws + o_Kbuf);
  const float* gst = (const float*)(ws + o_gistat);
  const float* gD = (const float*)(ws + o_giD);
  u16* xb = (u16*)(ws + o_xbuf);
  u16* outs = (u16*)(ws + o_outsB);

  __shared__ u16 x_lds[1024];      // [attn(0..511) | h(512..1023)]
  __shared__ float gate_lds[1536];
  __shared__ float gnx_lds[512];   // n-gate attn-part
  __shared__ float hsm[512];
  __shared__ float scb[64];
  __shared__ float wsb[64];
  __shared__ u16 cxb[512];

  if (tid < 256) *(u64*)&x_lds[tid * 4] = *(const u64*)(xb + b * 1024 + tid * 4);
  f4 bhr4 = {0.f,0.f,0.f,0.f}, bhz4 = bhr4, bhn4 = bhr4;
  f4 s0 = bhr4, s1 = bhr4, s2 = bhr4;
  if (tid < 128) {
    const int c0 = tid * 4;
    bhr4 = *(const f4*)(dec_bh + c0);
    bhz4 = *(const f4*)(dec_bh + 512 + c0);
    bhn4 = *(const f4*)(dec_bh + 1024 + c0);
    s0 = *(const f4*)(gst + b * 1536 + c0);
    s1 = *(const f4*)(gst + b * 1536 + 512 + c0);
    s2 = *(const f4*)(gst + b * 1536 + 1024 + c0);
  }
  f4 bcv[4];
#pragma unroll
  for (int ci = 0; ci < 4; ++ci) bcv[ci] = (f4){0.f, 0.f, 0.f, 0.f};
  if (l15 == 0) {
#pragma unroll
    for (int ci = 0; ci < 4; ++ci) {
      const int ctile = wave + ci * 8;
      bcv[ci] = *(const f4*)(bc + ctile * 16 + lhi * 4);
    }
  }
  __syncthreads();

  const bf8 zf = {0, 0, 0, 0, 0, 0, 0, 0};
  for (int t = 0; t < 59; ++t) {
    // ---- G: gate pre-activations via MFMA (96 ctiles over 8 waves) ----
    f4 acc[12];
#pragma unroll
    for (int ci = 0; ci < 12; ++ci) acc[ci] = (f4){0.f, 0.f, 0.f, 0.f};
#pragma unroll
    for (int kb = 0; kb < 2; ++kb) {
      bf8 xf[16];
#pragma unroll
      for (int kc = 0; kc < 16; ++kc)
        xf[kc] = (l15 == 0) ? *(const bf8*)&x_lds[kb * 512 + kc * 32 + lhi * 8] : zf;
#pragma unroll
      for (int ci = 0; ci < 12; ++ci) {
        const int ctile = wave + ci * 8;
        const u16* wrow = Wd2 + (size_t)(ctile * 16 + l15) * 1024 + kb * 512 + lhi * 8;
#pragma unroll
        for (int kc = 0; kc < 16; ++kc)
          acc[ci] = MFMA(*(const bf8*)(wrow + kc * 32), xf[kc], acc[ci]);
      }
      if (kb == 0) {  // n-gate (ci>=8 => ctile>=64): stash attn-part, reset
        if (l15 == 0) {
#pragma unroll
          for (int ci = 8; ci < 12; ++ci) {
            const int ctile = wave + ci * 8;
#pragma unroll
            for (int j = 0; j < 4; ++j)
              gnx_lds[ctile * 16 - 1024 + lhi * 4 + j] = acc[ci][j];
          }
        }
#pragma unroll
        for (int ci = 8; ci < 12; ++ci) acc[ci] = (f4){0.f, 0.f, 0.f, 0.f};
      }
    }
    if (l15 == 0) {
#pragma unroll
      for (int ci = 0; ci < 12; ++ci) {
        const int ctile = wave + ci * 8;
#pragma unroll
        for (int j = 0; j < 4; ++j)
          gate_lds[ctile * 16 + lhi * 4 + j] = acc[ci][j];
      }
    }
    __syncthreads();
    // ---- G2: gates -> h_new ----
    if (tid < 128) {
      const int c0 = tid * 4;
      const float* g2p = gD + (size_t)(t * 32 + b) * 1536;
      const f4 d0 = *(const f4*)(g2p + c0);
      const f4 d1 = *(const f4*)(g2p + 512 + c0);
      const f4 d2 = *(const f4*)(g2p + 1024 + c0);
      const f4 a0 = *(const f4*)&gate_lds[c0];
      const f4 a1 = *(const f4*)&gate_lds[512 + c0];
      const f4 ah = *(const f4*)&gate_lds[1024 + c0];
      const f4 ax = *(const f4*)&gnx_lds[c0];
      const u64 hq = *(const u64*)&x_lds[512 + c0];
      u64 pk = 0;
#pragma unroll
      for (int j = 0; j < 4; ++j) {
        const float r = sigmoid_(s0[j] + d0[j] + a0[j] + bhr4[j]);
        const float z = sigmoid_(s1[j] + d1[j] + a1[j] + bhz4[j]);
        const float n = tanh_(s2[j] + d2[j] + ax[j] + r * (ah[j] + bhn4[j]));
        const float hold = bf2f((u16)(hq >> (16 * j)));
        const float hv = (1.f - z) * n + z * hold;
        pk |= (u64)f2bf(hv) << (16 * j);
        hsm[c0 + j] = hv;
      }
      *(u64*)&x_lds[512 + c0] = pk;
      *(u64*)(outs + (size_t)(b * 59 + t) * 1024 + c0) = pk;
    }
    __syncthreads();
    // ---- A1: scores[s] = h . KA[s,b,:]  (8 lanes per s) ----
    if (tid < 480) {
      const int s = tid >> 3, q = tid & 7;
      const u16* kr = KAp + (size_t)(s * 32 + b) * 512 + q * 64;
      const float* hqp = &hsm[q * 64];
      float a0 = 0.f, a1 = 0.f;
#pragma unroll 4
      for (int i = 0; i < 64; i += 8) {
        const uint2 k4 = *(const uint2*)(kr + i);
        const uint2 k5 = *(const uint2*)(kr + i + 4);
        const float4 h4 = *(const float4*)(hqp + i);
        const float4 h5 = *(const float4*)(hqp + i + 4);
        a0 += h4.x * bfLO(k4.x) + h4.y * bfHI(k4.x)
            + h4.z * bfLO(k4.y) + h4.w * bfHI(k4.y);
        a1 += h5.x * bfLO(k5.x) + h5.y * bfHI(k5.x)
            + h5.z * bfLO(k5.y) + h5.w * bfHI(k5.y);
      }
      float a = a0 + a1;
      a += __shfl_xor(a, 1);
      a += __shfl_xor(a, 2);
      a += __shfl_xor(a, 4);
      if (q == 0) scb[s] = a;
    }
    __syncthreads();
    // ---- A2: softmax over 60 + weights output ----
    if (tid < 64) {
      const float v = (tid < 60) ? scb[tid] : -1e30f;
      float m = v;
#pragma unroll
      for (int d = 1; d < 64; d <<= 1) m = fmaxf(m, __shfl_xor(m, d));
      const float e = (tid < 60) ? __expf(v - m) : 0.f;
      float sm = e;
#pragma unroll
      for (int d = 1; d < 64; d <<= 1) sm += __shfl_xor(sm, d);
      const float w = e / sm;
      if (tid < 60) {
        wsb[tid] = w;
        out[WOFF + (size_t)(b * 59 + t) * 60 + tid] = w;
      }
    }
    __syncthreads();
    // ---- A3: ctx[d] = sum_s w[s]*K[s,b,d] -> bf16 ----
    {
      const u16* kb0 = Kb + (size_t)b * 512 + tid;
      float c0 = 0.f, c1 = 0.f, c2 = 0.f, c3 = 0.f;
#pragma unroll 3
      for (int s = 0; s < 60; s += 4) {
        c0 += wsb[s]     * bf2f(kb0[(size_t)(s)     * 16384]);
        c1 += wsb[s + 1] * bf2f(kb0[(size_t)(s + 1) * 16384]);
        c2 += wsb[s + 2] * bf2f(kb0[(size_t)(s + 2) * 16384]);
        c3 += wsb[s + 3] * bf2f(kb0[(size_t)(s + 3) * 16384]);
      }
      cxb[tid] = f2bf((c0 + c1) + (c2 + c3));
    }
    __syncthreads();
    // ---- A4: attn = tanh(Wc @ ctx + bc) via MFMA (32 ctiles over 8 waves) ----
    {
      bf8 cf[16];
#pragma unroll
      for (int kc = 0; kc < 16; ++kc)
        cf[kc] = (l15 == 0) ? *(const bf8*)&cxb[kc * 32 + lhi * 8] : zf;
      f4 ac[4];
#pragma unroll
      for (int ci = 0; ci < 4; ++ci) ac[ci] = (f4){0.f, 0.f, 0.f, 0.f};
#pragma unroll
      for (int ci = 0; ci < 4; ++ci) {
        const int ctile = wave + ci * 8;
        const u16* wrow = WcB + (size_t)(ctile * 16 + l15) * 512 + lhi * 8;
#pragma unroll
        for (int kc = 0; kc < 16; ++kc)
          ac[ci] = MFMA(*(const bf8*)(wrow + kc * 32), cf[kc], ac[ci]);
      }
      if (l15 == 0) {
#pragma unroll
        for (int ci = 0; ci < 4; ++ci) {
          const int ctile = wave + ci * 8;
#pragma unroll
          for (int j = 0; j < 4; ++j)
            x_lds[ctile * 16 + lhi * 4 + j] = f2bf(tanh_(ac[ci][j] + bcv[ci][j]));
        }
      }
    }
    __syncthreads();
    // pack attn -> outs (reads x_lds attn half; disjoint from next-G writes)
    if (tid < 64)
      *(u64*)(outs + (size_t)(b * 59 + t) * 1024 + 512 + tid * 4) =
          *(const u64*)&x_lds[tid * 4];
  }
}

// ---------------- vocab GEMM v2: LDS-staged, double-buffered, exp+rowsum ------
__global__ __launch_bounds__(512, 2) void k_vocab2(
    const u16* __restrict__ A, const u16* __restrict__ Bm,
    const float* __restrict__ bvv, float* __restrict__ out,
    float* __restrict__ rowsum)
{
  __shared__ u16 As[2][128][40];
  __shared__ u16 Bs[2][256][40];
  const int tid = threadIdx.x;
  const int bid = blockIdx.x;
  const int xcd = bid & 7, sub = bid >> 3;
  const int wgid = (xcd < 4 ? xcd * 368 : 4 * 368 + (xcd - 4) * 367) + sub;
  const int mtile = wgid % 15, ntile = wgid / 15;
  const int rbase = mtile * 128, cbase = ntile * 256;

  const int wave = tid >> 6, lane = tid & 63;
  const int l15 = lane & 15, lhi = lane >> 4;
  const int m0 = (wave >> 2) * 64, n0 = (wave & 3) * 64;

  const int sar = tid >> 2, sak = (tid & 3) * 8;
  const u16* gA = A + (size_t)(rbase + sar) * 1024 + sak;
  const u16* gB0 = Bm + (size_t)(cbase + sar) * 1024 + sak;
  const u16* gB1 = Bm + (size_t)(cbase + 128 + sar) * 1024 + sak;

  f4 acc[4][4];
#pragma unroll
  for (int mi = 0; mi < 4; ++mi)
#pragma unroll
    for (int ni = 0; ni < 4; ++ni) acc[mi][ni] = (f4){0.f, 0.f, 0.f, 0.f};

  uint4 ra, rb0, rb1;
  ra = *(const uint4*)(gA);
  rb0 = *(const uint4*)(gB0);
  rb1 = *(const uint4*)(gB1);
  *(uint4*)&As[0][sar][sak] = ra;
  *(uint4*)&Bs[0][sar][sak] = rb0;
  *(uint4*)&Bs[0][128 + sar][sak] = rb1;
  __syncthreads();

  int cur = 0;
#pragma unroll 1
  for (int t = 0; t < 32; ++t) {
    if (t < 31) {
      const int k0 = (t + 1) * 32;
      ra = *(const uint4*)(gA + k0);
      rb0 = *(const uint4*)(gB0 + k0);
      rb1 = *(const uint4*)(gB1 + k0);
    }
    bf8 af[4], bfr[4];
#pragma unroll
    for (int mi = 0; mi < 4; ++mi)
      af[mi] = *(const bf8*)&As[cur][m0 + mi * 16 + l15][lhi * 8];
#pragma unroll
    for (int ni = 0; ni < 4; ++ni)
      bfr[ni] = *(const bf8*)&Bs[cur][n0 + ni * 16 + l15][lhi * 8];
#pragma unroll
    for (int mi = 0; mi < 4; ++mi)
#pragma unroll
      for (int ni = 0; ni < 4; ++ni)
        acc[mi][ni] = MFMA(af[mi], bfr[ni], acc[mi][ni]);
    if (t < 31) {
      __syncthreads();
      *(uint4*)&As[cur ^ 1][sar][sak] = ra;
      *(uint4*)&Bs[cur ^ 1][sar][sak] = rb0;
      *(uint4*)&Bs[cur ^ 1][128 + sar][sak] = rb1;
      __syncthreads();
      cur ^= 1;
    }
  }

#pragma unroll
  for (int mi = 0; mi < 4; ++mi) {
    float rs[4] = {0.f, 0.f, 0.f, 0.f};
#pragma unroll
    for (int ni = 0; ni < 4; ++ni) {
      const int c = cbase + n0 + ni * 16 + l15;
      if (c < 50000) {
        const float bb = bvv[c];
#pragma unroll
        for (int j = 0; j < 4; ++j) {
          const int r = rbase + m0 + mi * 16 + lhi * 4 + j;
          if (r < 1888) {
            const float e = __expf(acc[mi][ni][j] + bb);
            out[(size_t)r * 50000 + c] = e;
            rs[j] += e;
          }
        }
      }
    }
#pragma unroll
    for (int j = 0; j < 4; ++j) {
#pragma unroll
      for (int d = 1; d < 16; d <<= 1) rs[j] += __shfl_xor(rs[j], d);
    }
    if (l15 == 0) {
#pragma unroll
      for (int j = 0; j < 4; ++j) {
        const int r = rbase + m0 + mi * 16 + lhi * 4 + j;
        if (r < 1888) atomicAdd(&rowsum[r], rs[j]);
      }
    }
  }
}

// ---------------- vocab GEMM fallback (no bf16 Wv copy) -----------------------
__global__ __launch_bounds__(512) void k_vocab0(
    const u16* __restrict__ A, const float* __restrict__ WvF,
    const float* __restrict__ bv, float* __restrict__ out,
    float* __restrict__ rowsum)
{
  const int bid = blockIdx.x;
  const int x = bid & 7, jj = bid >> 3;
  const int mtile = jj % 15, nseq = jj / 15;
  const int ntile = nseq * 8 + x;
  if (ntile >= 196) return;
  const int w = threadIdx.x >> 6, lane = threadIdx.x & 63;
  const int l15 = lane & 15, lhi = lane >> 4;
  const int rbase = mtile * 128 + w * 16;
  const u16* arow = A + (size_t)(rbase + l15) * 1024 + lhi * 8;
  const int cbase = ntile * 256;
  f4 acc[16];
#pragma unroll
  for (int nn = 0; nn < 16; ++nn) acc[nn] = (f4){0.f, 0.f, 0.f, 0.f};
  for (int k = 0; k < 1024; k += 32) {
    const bf8 a = *(const bf8*)(arow + k);
#pragma unroll
    for (int nn = 0; nn < 16; ++nn) {
      const int cs = cbase + nn * 16;
      bf8 bfr = {0, 0, 0, 0, 0, 0, 0, 0};
      if (cs < 50000) {
        const float* p = WvF + (size_t)(cs + l15) * 1024 + k + lhi * 8;
        const float4 f0 = *(const float4*)p;
        const float4 f1 = *(const float4*)(p + 4);
        bfr[0] = (short)(__float_as_uint(f0.x) >> 16);
        bfr[1] = (short)(__float_as_uint(f0.y) >> 16);
        bfr[2] = (short)(__float_as_uint(f0.z) >> 16);
        bfr[3] = (short)(__float_as_uint(f0.w) >> 16);
        bfr[4] = (short)(__float_as_uint(f1.x) >> 16);
        bfr[5] = (short)(__float_as_uint(f1.y) >> 16);
        bfr[6] = (short)(__float_as_uint(f1.z) >> 16);
        bfr[7] = (short)(__float_as_uint(f1.w) >> 16);
      }
      acc[nn] = MFMA(a, bfr, acc[nn]);
    }
  }
  float rsv[4] = {0.f, 0.f, 0.f, 0.f};
#pragma unroll
  for (int nn = 0; nn < 16; ++nn) {
    const int cs = cbase + nn * 16;
    if (cs >= 50000) continue;
    const int c = cs + l15;
    const float bb = bv[c];
#pragma unroll
    for (int j = 0; j < 4; ++j) {
      const int r = rbase + lhi * 4 + j;
      if (r < 1888) {
        const float e = __expf(acc[nn][j] + bb);
        out[(size_t)r * 50000 + c] = e;
        rsv[j] += e;
      }
    }
  }
#pragma unroll
  for (int j = 0; j < 4; ++j) {
#pragma unroll
    for (int d = 1; d < 16; d <<= 1) rsv[j] += __shfl_xor(rsv[j], d);
  }
  if (l15 == 0) {
#pragma unroll
    for (int j = 0; j < 4; ++j) {
      const int r = rbase + lhi * 4 + j;
      if (r < 1888) atomicAdd(&rowsum[r], rsv[j]);
    }
  }
}

// ---------------- rowsum -> 1/rowsum ----------------
__global__ void k_invrow(float* rs)
{
  const int i = blockIdx.x * 256 + threadIdx.x;
  if (i < 1920) {
    const float s = rs[i];
    rs[i] = (s > 0.f) ? 1.f / s : 0.f;
  }
}

// ---------------- scale exp values by 1/rowsum ----------------
__global__ __launch_bounds__(256) void k_scale(float* __restrict__ out,
                                               const float* __restrict__ inv)
{
  const int bid = blockIdx.x;
  const int r = bid / 49, ch = bid - r * 49;
  const int c = ch * 1024 + threadIdx.x * 4;
  if (c < 50000) {
    const float s = inv[r];
    float4* p = (float4*)(out + (size_t)r * 50000 + c);
    float4 v = *p;
    v.x *= s; v.y *= s; v.z *= s; v.w *= s;
    *p = v;
  }
}

extern "C" void kernel_launch(void* const* d_in, const int* in_sizes, int n_in,
                              void* d_out, int out_size, void* d_ws, size_t ws_size,
                              hipStream_t stream) {
  const int* posts = (const int*)d_in[0];
  const int* resp = (const int*)d_in[1];
  const float* emb = (const float*)d_in[3];
  const float* aemb = (const float*)d_in[4];
  const float* encWi = (const float*)d_in[5];
  const float* encWh = (const float*)d_in[6];
  const float* enc_bi = (const float*)d_in[7];
  const float* enc_bh = (const float*)d_in[8];
  const float* affWi = (const float*)d_in[9];
  const float* affWh = (const float*)d_in[10];
  const float* aff_bi = (const float*)d_in[11];
  const float* aff_bh = (const float*)d_in[12];
  const float* Wp = (const float*)d_in[13];
  const float* bp = (const float*)d_in[14];
  const float* Wl = (const float*)d_in[15];
  const float* bl = (const float*)d_in[16];
  const float* dWi = (const float*)d_in[17];
  const float* dWh = (const float*)d_in[18];
  const float* dbi = (const float*)d_in[19];
  const float* dbh = (const float*)d_in[20];
  const float* Wa = (const float*)d_in[21];
  const float* Wc = (const float*)d_in[22];
  const float* bc = (const float*)d_in[23];
  const float* Wv = (const float*)d_in[24];
  const float* bv = (const float*)d_in[25];
  char* ws = (char*)d_ws;
  float* out = (float*)d_out;
  const bool useWvB = ws_size >= L::WS_FULL;

  kp_gather<<<4760, 256, 0, stream>>>(posts, resp, emb, aemb, ws);
  kp_wconv<<<19500, 256, 0, stream>>>(encWi, affWi, encWh, affWh, dWi, Wl, Wa, Wp, Wc, ws);
  kp_bcomb<<<6, 256, 0, stream>>>(dWi, bl, dbi, ws);
  if (useWvB) kp_wv<<<50176, 256, 0, stream>>>(Wv, ws);

  // Wcomb = dec_Wi @ Wl  -> f32 [1536][1328]
  k_gemm_nt<<<dim3(96, 6), 256, 0, stream>>>(
      (const u16*)(ws + L::o_decWi), (const u16*)(ws + L::o_WlT),
      (float*)(ws + L::o_Wcomb), nullptr, 1536, 1328, 512);
  kp_pack2<<<11136, 256, 0, stream>>>((const float*)(ws + L::o_Wcomb), dWh, ws);

  // input-gate precomputes
  k_gemm_nt<<<dim3(120, 6), 256, 0, stream>>>(
      (const u16*)(ws + L::o_embP), (const u16*)(ws + L::o_encWi),
      (float*)(ws + L::o_giE), enc_bi, 1920, 1536, 320);
  k_gemm_nt<<<dim3(120, 6), 256, 0, stream>>>(
      (const u16*)(ws + L::o_embA), (const u16*)(ws + L::o_affWi),
      (float*)(ws + L::o_giA), aff_bi, 1920, 1536, 320);
  k_gemm_nt<<<dim3(118, 6), 256, 0, stream>>>(
      (const u16*)(ws + L::o_embD), (const u16*)(ws + L::o_WdE),
      (float*)(ws + L::o_giD), nullptr, 1888, 1536, 320);

  k_enc<<<64, 512, 0, stream>>>(ws, enc_bh, aff_bh);
  k_mid<<<80, 256, 0, stream>>>(ws, bp);
  k_dec<<<32, 512, 0, stream>>>(ws, out, dbh, bc);

  if (useWvB)
    k_vocab2<<<2940, 512, 0, stream>>>(
        (const u16*)(ws + L::o_outsB), (const u16*)(ws + L::o_WvB),
        bv, out, (float*)(ws + L::o_rowsum));
  else
    k_vocab0<<<2944, 512, 0, stream>>>(
        (const u16*)(ws + L::o_outsB), Wv, bv, out, (float*)(ws + L::o_rowsum));

  k_invrow<<<8, 256, 0, stream>>>((float*)(ws + L::o_rowsum));
  k_scale<<<92512, 256, 0, stream>>>(out, (const float*)(ws + L::o_rowsum));
}

// Round 8
// 3162.626 us; speedup vs baseline: 4.3102x; 4.3102x over previous
//
#include <hip/hip_runtime.h>

typedef unsigned int uint32;
typedef unsigned short u16;
typedef unsigned long long u64;
typedef __attribute__((ext_vector_type(8))) short bf8;   // 8 x bf16 (4 VGPRs)
typedef __attribute__((ext_vector_type(4))) float f4;    // 4 x f32
typedef __attribute__((ext_vector_type(4))) uint32 u32x4;

#define DEV static __device__ __forceinline__

DEV f4 MFMA(bf8 a, bf8 b, f4 c) {
  return __builtin_amdgcn_mfma_f32_16x16x32_bf16(a, b, c, 0, 0, 0);
}
DEV u16 f2bf(float f) {
  uint32 u = __float_as_uint(f);
  return (u16)((u + 0x7FFFu + ((u >> 16) & 1u)) >> 16);
}
DEV float bf2f(u16 h) { return __uint_as_float(((uint32)h) << 16); }
DEV float bfLO(uint32 u) { return __uint_as_float(u << 16); }
DEV float bfHI(uint32 u) { return __uint_as_float(u & 0xFFFF0000u); }
DEV float sigmoid_(float x) { return 1.f / (1.f + __expf(-x)); }
DEV float tanh_(float x) {
  float cx = fminf(fmaxf(x, -15.f), 15.f);
  float e = __expf(2.f * cx);
  return (e - 1.f) / (e + 1.f);
}

// ---- device-coherent (agent-scope, relaxed) data movement; compiler-tracked ----
DEV u64 ldA64(const void* p) {
  return __hip_atomic_load((u64*)p, __ATOMIC_RELAXED, __HIP_MEMORY_SCOPE_AGENT);
}
DEV void stA64(void* p, u64 v) {
  __hip_atomic_store((u64*)p, v, __ATOMIC_RELAXED, __HIP_MEMORY_SCOPE_AGENT);
}
DEV void stA32(int* p, int v) {
  __hip_atomic_store(p, v, __ATOMIC_RELAXED, __HIP_MEMORY_SCOPE_AGENT);
}
DEV bf8 pk_frag(u64 lo, u64 hi) {
  u32x4 v = {(uint32)lo, (uint32)(lo >> 32), (uint32)hi, (uint32)(hi >> 32)};
  return __builtin_bit_cast(bf8, v);
}

// ---- sync primitives ----
DEV void wait_vm0() { asm volatile("s_waitcnt vmcnt(0)" ::: "memory"); }
// slot-based barrier: producers WRITE slot[i]=tgt (no RMW); one wave polls all
// slots with a coalesced lane-load + ballot. Call from a full wave.
DEV void wait_slots(const int* slots, int n, int tgt) {
  const int lane = threadIdx.x & 63;
  for (int i = 0; i < (1 << 20); ++i) {
    int v = 0x7fffffff;
    if (lane < n)
      v = __hip_atomic_load((int*)(slots + lane), __ATOMIC_RELAXED,
                            __HIP_MEMORY_SCOPE_AGENT);
    if (__all(v >= tgt)) return;
    __builtin_amdgcn_s_sleep(1);
  }
}

namespace L {
// sizes: B=32,S=60,T=59,V=50000,E=300(pad320),H=512,3H=1536
constexpr size_t o_flags  = 0;          // 1024 int
constexpr size_t o_rowsum = 4096;       // 1920 f32
constexpr size_t o_bcomb  = 11776;      // 1536 f32
constexpr size_t o_gistat = 17920;      // 32x1536 f32
constexpr size_t o_xbuf   = 214528;     // 2x32x1024 bf16  (attn | h)
constexpr size_t o_henc   = 345600;     // 2x32x512 bf16
constexpr size_t o_haff   = 411136;     // 2x32x512 bf16
constexpr size_t o_cat    = 476672;     // 32x1024 bf16 (state_enc | state_aff)
constexpr size_t o_Kbuf   = 542208;     // 1920x512 bf16 (row = s*32+b)
constexpr size_t o_KA     = 2508288;    // 1920x512 bf16
constexpr size_t o_embP   = 4474368;    // 1920x320 bf16
constexpr size_t o_embA   = 5703168;    // 1920x320 bf16
constexpr size_t o_embD   = 6931968;    // 1888x320 bf16
constexpr size_t o_encWi  = 8140288;    // 1536x320 bf16
constexpr size_t o_affWi  = 9123328;    // 1536x320 bf16
constexpr size_t o_Whe    = 10106368;   // 1536x512 bf16
constexpr size_t o_Wha    = 11679232;   // 1536x512 bf16
constexpr size_t o_decWi  = 13252096;   // 1536x512 bf16
constexpr size_t o_WlT    = 14824960;   // 1328x512 bf16
constexpr size_t o_Wa     = 16184832;   // 512x512 bf16
constexpr size_t o_Wp     = 16709120;   // 512x1024 bf16
constexpr size_t o_WcB    = 17757696;   // 512x512 bf16 (Wc row-major)
constexpr size_t o_Wcomb  = 18281984;   // 1536x1328 f32
constexpr size_t o_WdE    = 26441216;   // 1536x320 bf16
constexpr size_t o_WdA    = 27424256;   // 1536x512 bf16
constexpr size_t o_Wd2    = 28997120;   // 1536x1024 bf16 (Wcomb_attn | dec_Wh)
constexpr size_t o_giE    = 32142848;   // 1920x1536 f32
constexpr size_t o_giA    = 43939328;   // 1920x1536 f32
constexpr size_t o_giD    = 55735808;   // 1888x1536 f32
constexpr size_t o_outsB  = 67335680;   // 1920x1024 bf16 (row = b*59+t : h|attn)
constexpr size_t o_WvB    = 71267840;   // 50176x1024 bf16 (optional)
constexpr size_t WS_FULL  = 174028288;
constexpr size_t WOFF = 94400000;       // weights output offset (floats)
// slots (ints): [0..31] dec A; [64..95] dec B; [128..159] enc g0; [192..223] enc g1
}

// ---------------- prep: embedding gathers -> bf16, padded K=320 ----------------
__global__ __launch_bounds__(256) void kp_gather(
    const int* __restrict__ posts, const int* __restrict__ resp,
    const float* __restrict__ emb, const float* __restrict__ aemb, char* ws)
{
  using namespace L;
  const int gid = blockIdx.x * 256 + threadIdx.x;
  const int r = gid / 320, e = gid - r * 320;
  u16* embP = (u16*)(ws + o_embP);
  u16* embA = (u16*)(ws + o_embA);
  u16* embD = (u16*)(ws + o_embD);
  if (r < 1920) {
    const int b = r & 31, s = r >> 5;
    const int tok = posts[b * 60 + s];
    embP[r * 320 + e] = f2bf(e < 300 ? emb[(size_t)tok * 300 + e] : 0.f);
    embA[r * 320 + e] = f2bf(e < 300 ? aemb[(size_t)tok * 300 + e] : 0.f);
  } else if (r < 3808) {
    const int r2 = r - 1920;
    const int b = r2 & 31, t = r2 >> 5;
    const int tok = resp[b * 60 + t];
    embD[r2 * 320 + e] = f2bf(e < 300 ? emb[(size_t)tok * 300 + e] : 0.f);
  }
}

// ---------------- prep: weight conversions / transposes / zeroing ----------------
__global__ __launch_bounds__(256) void kp_wconv(
    const float* __restrict__ encWi, const float* __restrict__ affWi,
    const float* __restrict__ encWh, const float* __restrict__ affWh,
    const float* __restrict__ dWi, const float* __restrict__ Wl,
    const float* __restrict__ Wa, const float* __restrict__ Wp,
    const float* __restrict__ Wc, char* ws)
{
  using namespace L;
  long gid = (long)blockIdx.x * 256 + threadIdx.x;
  if (gid < 983040) {  // enc_Wi / aff_Wi -> [1536][320] bf16 (pad)
    const int g = gid >= 491520;
    const long u = gid - (g ? 491520 : 0);
    const int n = (int)(u / 320), e = (int)(u - (long)n * 320);
    const float* src = g ? affWi : encWi;
    u16* dst = (u16*)(ws + (g ? o_affWi : o_encWi));
    dst[u] = f2bf(e < 300 ? src[(size_t)n * 300 + e] : 0.f);
    return;
  }
  gid -= 983040;
  if (gid < 2359296) {  // enc_Wh / aff_Wh / dec_Wi -> bf16 direct
    const int g = (int)(gid / 786432);
    const long u = gid - (long)g * 786432;
    const float* src = g == 0 ? encWh : (g == 1 ? affWh : dWi);
    u16* dst = (u16*)(ws + (g == 0 ? o_Whe : (g == 1 ? o_Wha : o_decWi)));
    dst[u] = f2bf(src[u]);
    return;
  }
  gid -= 2359296;
  if (gid < 679936) {  // Wl^T -> [1328][512] bf16 (pad rows)
    const int j = (int)(gid >> 9), k = (int)(gid & 511);
    ((u16*)(ws + o_WlT))[gid] = f2bf(j < 1324 ? Wl[(size_t)k * 1324 + j] : 0.f);
    return;
  }
  gid -= 679936;
  if (gid < 262144) { ((u16*)(ws + o_Wa))[gid] = f2bf(Wa[gid]); return; }
  gid -= 262144;
  if (gid < 524288) { ((u16*)(ws + o_Wp))[gid] = f2bf(Wp[gid]); return; }
  gid -= 524288;
  if (gid < 131072) {  // WcB: bf16 row-major copy (2 elems per gid)
    const long e = gid * 2;
    const uint32 lo = f2bf(Wc[e]);
    const uint32 hi = f2bf(Wc[e + 1]);
    ((uint32*)(ws + o_WcB))[gid] = lo | (hi << 16);
    return;
  }
  gid -= 131072;
  if (gid < 2944) {  // zero flags + rowsum
    if (gid < 1024) ((uint32*)(ws + o_flags))[gid] = 0;
    else ((uint32*)(ws + o_rowsum))[gid - 1024] = 0;
    return;
  }
  gid -= 2944;
  if (gid < 49152) {  // zero: outsB pad rows, henc, haff (u32 words)
    if (gid < 16384) ((uint32*)(ws + o_outsB + (size_t)1888 * 1024 * 2))[gid] = 0;
    else if (gid < 32768) ((uint32*)(ws + o_henc))[gid - 16384] = 0;
    else ((uint32*)(ws + o_haff))[gid - 32768] = 0;
  }
}

// ---------------- prep: bcomb = dec_Wi @ bl + dec_bi ----------------
__global__ __launch_bounds__(256) void kp_bcomb(
    const float* __restrict__ dWi, const float* __restrict__ bl,
    const float* __restrict__ dbi, char* ws)
{
  const int i = blockIdx.x * 256 + threadIdx.x;
  if (i >= 1536) return;
  float a = dbi[i];
  for (int k = 0; k < 512; ++k) a += dWi[(size_t)i * 512 + k] * bl[k];
  ((float*)(ws + L::o_bcomb))[i] = a;
}

// ---------------- prep: Wv -> bf16 (padded rows) ----------------
__global__ __launch_bounds__(256) void kp_wv(const float* __restrict__ Wv, char* ws)
{
  const long gid = (long)blockIdx.x * 256 + threadIdx.x;
  const int r = (int)(gid >> 8), q = (int)(gid & 255);
  u16* WvB = (u16*)(ws + L::o_WvB);
  uint2 o;
  if (r < 50000) {
    const float4 f = *(const float4*)(Wv + (size_t)r * 1024 + q * 4);
    o.x = (uint32)f2bf(f.x) | ((uint32)f2bf(f.y) << 16);
    o.y = (uint32)f2bf(f.z) | ((uint32)f2bf(f.w) << 16);
  } else { o.x = 0u; o.y = 0u; }
  *(uint2*)(WvB + (size_t)r * 1024 + q * 4) = o;
}

// ---------------- prep: split Wcomb into bf16 pieces ----------------
__global__ __launch_bounds__(256) void kp_pack2(
    const float* __restrict__ Wcomb, const float* __restrict__ dWh, char* ws)
{
  using namespace L;
  long gid = (long)blockIdx.x * 256 + threadIdx.x;
  if (gid < 491520) {  // Wd_emb [1536][320] <- Wcomb[:,0:300]
    const int n = (int)(gid / 320), e = (int)(gid - (long)n * 320);
    ((u16*)(ws + o_WdE))[gid] = f2bf(e < 300 ? Wcomb[(size_t)n * 1328 + e] : 0.f);
    return;
  }
  gid -= 491520;
  if (gid < 786432) {  // Wd_aff [1536][512] <- Wcomb[:,300:812]
    const int n = (int)(gid >> 9), k = (int)(gid & 511);
    ((u16*)(ws + o_WdA))[gid] = f2bf(Wcomb[(size_t)n * 1328 + 300 + k]);
    return;
  }
  gid -= 786432;
  if (gid < 1572864) {  // Wd2 [1536][1024] = [Wcomb[:,812:1324] | dec_Wh]
    const int n = (int)(gid >> 10), k = (int)(gid & 1023);
    const float v = (k < 512) ? Wcomb[(size_t)n * 1328 + 812 + k]
                              : dWh[(size_t)n * 512 + (k - 512)];
    ((u16*)(ws + o_Wd2))[gid] = f2bf(v);
  }
}

// ---------------- generic MFMA GEMM: C[M][N] = A[M][Kp] * B[N][Kp]^T (+bias) ----------------
__global__ __launch_bounds__(256) void k_gemm_nt(
    const u16* __restrict__ A, const u16* __restrict__ Bm,
    float* __restrict__ C, const float* __restrict__ bias,
    const int M, const int N, const int Kp)
{
  const int mt = blockIdx.x, cb = blockIdx.y;
  const int w = threadIdx.x >> 6, lane = threadIdx.x & 63;
  const int l15 = lane & 15, lhi = lane >> 4;
  const u16* arow = A + (size_t)(mt * 16 + l15) * Kp + lhi * 8;
  const int c0 = cb * 256 + w * 64;
  f4 acc[4];
#pragma unroll
  for (int nn = 0; nn < 4; ++nn) acc[nn] = (f4){0.f, 0.f, 0.f, 0.f};
  for (int k = 0; k < Kp; k += 32) {
    const bf8 a = *(const bf8*)(arow + k);
#pragma unroll
    for (int nn = 0; nn < 4; ++nn) {
      const int cs = c0 + nn * 16;
      if (cs < N) {
        const bf8 b = *(const bf8*)(Bm + (size_t)(cs + l15) * Kp + k + lhi * 8);
        acc[nn] = MFMA(a, b, acc[nn]);
      }
    }
  }
#pragma unroll
  for (int nn = 0; nn < 4; ++nn) {
    const int cs = c0 + nn * 16;
    if (cs >= N) continue;
    const int c = cs + l15;
    const float bb = bias ? bias[c] : 0.f;
#pragma unroll
    for (int j = 0; j < 4; ++j) {
      const int r = mt * 16 + lhi * 4 + j;
      C[(size_t)r * N + c] = acc[nn][j] + bb;
    }
  }
}

// ---------------- encoder kernel: 64 blocks (32 per GRU), 2 active waves each ----
__global__ __launch_bounds__(256, 1) void k_enc(
    char* __restrict__ ws, const float* __restrict__ enc_bh,
    const float* __restrict__ aff_bh)
{
  using namespace L;
  const int tid = threadIdx.x, blk = blockIdx.x;
  const int wave = tid >> 6, lane = tid & 63;
  const int l15 = lane & 15, lhi = lane >> 4;
  const int g = blk >> 5;
  const bool act = wave < 2;
  int* flags = (int*)(ws + o_flags);
  int* slotE = flags + 128 + g * 64;
  const u16* Wh = (const u16*)(ws + (g ? o_Wha : o_Whe));
  const float* gi = (const float*)(ws + (g ? o_giA : o_giE));
  const float* bh = g ? aff_bh : enc_bh;
  u16* hbuf = (u16*)(ws + (g ? o_haff : o_henc));
  u16* cat = (u16*)(ws + o_cat);
  u16* Kb = (u16*)(ws + o_Kbuf);

  const int wid = (blk & 31) * 2 + (wave & 1);     // 0..63 when act
  const int btile = wid >> 5, ctile = wid & 31;
  const int bl = btile * 16 + l15;
  const int c0 = ctile * 16 + lhi * 4;
  const u16* wr0 = Wh + (size_t)(ctile * 16 + l15) * 512 + lhi * 8;
  const u16* wr1 = wr0 + (size_t)512 * 512;
  const u16* wr2 = wr1 + (size_t)512 * 512;
  f4 bhr4 = {0.f, 0.f, 0.f, 0.f}, bhz4 = bhr4, bhn4 = bhr4;
  if (act) {
    bhr4 = *(const f4*)(bh + c0);
    bhz4 = *(const f4*)(bh + 512 + c0);
    bhn4 = *(const f4*)(bh + 1024 + c0);
  }
  for (int s = 0; s < 60; ++s) {
    const u16* hin = hbuf + (s & 1) * (32 * 512);
    u16* hout = hbuf + ((s & 1) ^ 1) * (32 * 512);
    if (act) {
      const u16* brow = hin + bl * 512 + lhi * 8;
      u64 flo[16], fhi[16];
#pragma unroll
      for (int kk = 0; kk < 16; ++kk) {        // batched: one exposed latency
        flo[kk] = ldA64(brow + kk * 32);
        fhi[kk] = ldA64(brow + kk * 32 + 4);
      }
      const u64 hq = ldA64(hin + bl * 512 + c0);
      f4 ar = {0.f, 0.f, 0.f, 0.f}, az = ar, an = ar;
#pragma unroll
      for (int kk = 0; kk < 16; ++kk) {
        const bf8 hf = pk_frag(flo[kk], fhi[kk]);
        ar = MFMA(*(const bf8*)(wr0 + kk * 32), hf, ar);
        az = MFMA(*(const bf8*)(wr1 + kk * 32), hf, az);
        an = MFMA(*(const bf8*)(wr2 + kk * 32), hf, an);
      }
      const float* gr = gi + (size_t)(s * 32 + bl) * 1536;
      const f4 g0 = *(const f4*)(gr + c0);
      const f4 g1 = *(const f4*)(gr + 512 + c0);
      const f4 g2 = *(const f4*)(gr + 1024 + c0);
      u64 pk = 0;
#pragma unroll
      for (int j = 0; j < 4; ++j) {
        const float r = sigmoid_(g0[j] + ar[j] + bhr4[j]);
        const float z = sigmoid_(g1[j] + az[j] + bhz4[j]);
        const float n = tanh_(g2[j] + r * (an[j] + bhn4[j]));
        const float hold = bf2f((u16)(hq >> (16 * j)));
        pk |= (u64)f2bf((1.f - z) * n + z * hold) << (16 * j);
      }
      stA64(hout + bl * 512 + c0, pk);
      if (g) *(u64*)(Kb + (size_t)(s * 32 + bl) * 512 + c0) = pk;  // next kernel
      if (s == 59) *(u64*)(cat + bl * 1024 + g * 512 + c0) = pk;   // next kernel
    }
    wait_vm0();
    __syncthreads();
    if (tid == 0) stA32(&slotE[blk & 31], s + 1);   // slot write, no RMW
    if (wave == 2) wait_slots(slotE, 32, s + 1);    // idle wave polls
    __syncthreads();
  }
}

// ---------------- mid kernel: state0 | gi_static | KA (no sync needed) ----------
__global__ __launch_bounds__(256) void k_mid(char* __restrict__ ws,
                                             const float* __restrict__ bp)
{
  using namespace L;
  const int tid = threadIdx.x, blk = blockIdx.x;
  const int wave = tid >> 6, lane = tid & 63;
  const int l15 = lane & 15, lhi = lane >> 4;
  u16* xb = (u16*)(ws + o_xbuf);
  u16* cat = (u16*)(ws + o_cat);
  u16* Kb = (u16*)(ws + o_Kbuf);

  if (blk < 16) {  // state0 = tanh(cat @ Wp^T + bp) -> xbuf[0]; zero attn half
    const u16* Wp_ = (const u16*)(ws + o_Wp);
    const int wid = blk * 4 + wave;
    const int btile = wid >> 5, ctile = wid & 31;
    const int bl = btile * 16 + l15;
    const int c0 = ctile * 16 + lhi * 4;
    const u16* arow = Wp_ + (size_t)(ctile * 16 + l15) * 1024 + lhi * 8;
    const u16* brow = cat + bl * 1024 + lhi * 8;
    f4 acc = {0.f, 0.f, 0.f, 0.f};
    for (int k = 0; k < 1024; k += 32)
      acc = MFMA(*(const bf8*)(arow + k), *(const bf8*)(brow + k), acc);
    const f4 bp4 = *(const f4*)(bp + c0);
    u64 pk = 0;
#pragma unroll
    for (int j = 0; j < 4; ++j)
      pk |= (u64)f2bf(tanh_(acc[j] + bp4[j])) << (16 * j);
    *(u64*)(xb + bl * 1024 + 512 + c0) = pk;
    *(u64*)(xb + bl * 1024 + c0) = 0;          // init attn = 0
  } else if (blk < 32) {  // gi_static = ctx_aff @ Wd_aff^T + bcomb
    const u16* WdA = (const u16*)(ws + o_WdA);
    const float* bco = (const float*)(ws + o_bcomb);
    float* gst = (float*)(ws + o_gistat);
    const int wid = (blk - 16) * 4 + wave;
    const int btile = wid >> 5, ctb = wid & 31;
    const int bl = btile * 16 + l15;
    const int c0 = ctb * 16 + lhi * 4;
    const u16* brow = cat + bl * 1024 + 512 + lhi * 8;
    const u16* a0p = WdA + (size_t)(ctb * 16 + l15) * 512 + lhi * 8;
    const u16* a1p = a0p + (size_t)512 * 512;
    const u16* a2p = a1p + (size_t)512 * 512;
    f4 a0 = {0.f, 0.f, 0.f, 0.f}, a1 = a0, a2 = a0;
    for (int k = 0; k < 512; k += 32) {
      const bf8 bfr = *(const bf8*)(brow + k);
      a0 = MFMA(*(const bf8*)(a0p + k), bfr, a0);
      a1 = MFMA(*(const bf8*)(a1p + k), bfr, a1);
      a2 = MFMA(*(const bf8*)(a2p + k), bfr, a2);
    }
    const f4 v0 = *(const f4*)(bco + c0);
    const f4 v1 = *(const f4*)(bco + 512 + c0);
    const f4 v2 = *(const f4*)(bco + 1024 + c0);
    *(f4*)(gst + bl * 1536 + c0) = a0 + v0;
    *(f4*)(gst + bl * 1536 + 512 + c0) = a1 + v1;
    *(f4*)(gst + bl * 1536 + 1024 + c0) = a2 + v2;
  } else {  // KA = K @ Wa^T
    const u16* Wa_ = (const u16*)(ws + o_Wa);
    u16* KAp = (u16*)(ws + o_KA);
    const int widK = (blk - 32) * 4 + wave;
    for (int task = widK; task < 3840; task += 192) {
      const int mt = task >> 5, ct = task & 31;
      const int m = mt * 16 + l15;
      const int c0 = ct * 16 + lhi * 4;
      const u16* arow = Wa_ + (size_t)(ct * 16 + l15) * 512 + lhi * 8;
      const u16* brow = Kb + (size_t)m * 512 + lhi * 8;
      f4 acc = {0.f, 0.f, 0.f, 0.f};
      for (int k = 0; k < 512; k += 32)
        acc = MFMA(*(const bf8*)(arow + k), *(const bf8*)(brow + k), acc);
      u64 pk = 0;
#pragma unroll
      for (int j = 0; j < 4; ++j) pk |= (u64)f2bf(acc[j]) << (16 * j);
      *(u64*)(KAp + (size_t)m * 512 + c0) = pk;
    }
  }
}

// ---------------- decoder: A=32 blocks (round-6 proven) + B=32 blocks ---------
// B-role: one 512-thread block per batch; Kb rows staged in dynamic LDS once;
// scores (ILP dot from L2 KA), softmax, ctx (LDS), attn via MFMA vs WcB.
__global__ __launch_bounds__(512, 1) void k_dec(
    char* __restrict__ ws, float* __restrict__ out,
    const float* __restrict__ dec_bh, const float* __restrict__ bc)
{
  using namespace L;
  extern __shared__ char dls[];
  const int tid = threadIdx.x, blk = blockIdx.x;
  const int wave = tid >> 6, lane = tid & 63;
  const int l15 = lane & 15, lhi = lane >> 4;
  int* flags = (int*)(ws + o_flags);
  int* slotA = flags;        // 32
  int* slotB = flags + 64;   // 32
  u16* xb = (u16*)(ws + o_xbuf);
  u16* outs = (u16*)(ws + o_outsB);

  if (blk < 32) {
    // A-role: h_t = GRU from [attn_{t-1} ; h_{t-1}] via Wd2 (K=1024), n-gate split.
    // stage 1 (gated on A slots): h-half loads + h-half MFMAs — overlaps B's work.
    // stage 2 (gated on B slots): attn-half loads + MFMAs + gates.
    const bool act = wave < 2;
    const u16* Wd2 = (const u16*)(ws + o_Wd2);
    const float* gst = (const float*)(ws + o_gistat);
    const float* gD = (const float*)(ws + o_giD);
    const int wid = (blk & 31) * 2 + (wave & 1);
    const int btile = wid >> 5, ctile = wid & 31;
    const int bl = btile * 16 + l15;
    const int c0 = ctile * 16 + lhi * 4;
    const u16* wr = Wd2 + (size_t)(ctile * 16 + l15) * 1024 + lhi * 8;
    const u16* wz = wr + (size_t)512 * 1024;
    const u16* wn = wz + (size_t)512 * 1024;
    f4 bhr4 = {0.f, 0.f, 0.f, 0.f}, bhz4 = bhr4, bhn4 = bhr4;
    f4 s0 = bhr4, s1 = bhr4, s2 = bhr4;
    if (act) {
      bhr4 = *(const f4*)(dec_bh + c0);
      bhz4 = *(const f4*)(dec_bh + 512 + c0);
      bhn4 = *(const f4*)(dec_bh + 1024 + c0);
      s0 = *(const f4*)(gst + bl * 1536 + c0);
      s1 = *(const f4*)(gst + bl * 1536 + 512 + c0);
      s2 = *(const f4*)(gst + bl * 1536 + 1024 + c0);
    }
    for (int t = 0; t < 59; ++t) {
      const u16* xin = xb + (t & 1) * (32 * 1024);
      u16* xout = xb + ((t & 1) ^ 1) * (32 * 1024);
      const u16* brow = xin + bl * 1024 + lhi * 8;
      f4 ar = {0.f, 0.f, 0.f, 0.f}, az = ar, anx = ar, anh = ar;
      u64 hq = 0;
      f4 d0 = ar, d1 = ar, d2 = ar;
      // ---- stage 1: needs h(t-1) = all A slots >= t ----
      if (t) {
        if (wave == 2) wait_slots(slotA, 32, t);
        __syncthreads();
      }
      if (act) {
        u64 flo[16], fhi[16];
#pragma unroll
        for (int kk = 0; kk < 16; ++kk) {
          flo[kk] = ldA64(brow + (16 + kk) * 32);
          fhi[kk] = ldA64(brow + (16 + kk) * 32 + 4);
        }
        hq = ldA64(xin + bl * 1024 + 512 + c0);
        const float* g2p = gD + (size_t)(t * 32 + bl) * 1536;   // static prefetch
        d0 = *(const f4*)(g2p + c0);
        d1 = *(const f4*)(g2p + 512 + c0);
        d2 = *(const f4*)(g2p + 1024 + c0);
#pragma unroll
        for (int kk = 0; kk < 16; ++kk) {
          const bf8 xf = pk_frag(flo[kk], fhi[kk]);
          ar = MFMA(*(const bf8*)(wr + (16 + kk) * 32), xf, ar);
          az = MFMA(*(const bf8*)(wz + (16 + kk) * 32), xf, az);
          anh = MFMA(*(const bf8*)(wn + (16 + kk) * 32), xf, anh);
        }
      }
      // ---- stage 2: needs attn(t-1) = all B slots >= t ----
      if (t) {
        if (wave == 2) wait_slots(slotB, 32, t);
        __syncthreads();
      }
      if (act) {
        u64 glo[16], ghi[16];
#pragma unroll
        for (int kk = 0; kk < 16; ++kk) {
          glo[kk] = ldA64(brow + kk * 32);
          ghi[kk] = ldA64(brow + kk * 32 + 4);
        }
#pragma unroll
        for (int kk = 0; kk < 16; ++kk) {
          const bf8 xf = pk_frag(glo[kk], ghi[kk]);
          ar = MFMA(*(const bf8*)(wr + kk * 32), xf, ar);
          az = MFMA(*(const bf8*)(wz + kk * 32), xf, az);
          anx = MFMA(*(const bf8*)(wn + kk * 32), xf, anx);
        }
        u64 pk = 0;
#pragma unroll
        for (int j = 0; j < 4; ++j) {
          const float r = sigmoid_(s0[j] + d0[j] + ar[j] + bhr4[j]);
          const float z = sigmoid_(s1[j] + d1[j] + az[j] + bhz4[j]);
          const float n = tanh_(s2[j] + d2[j] + anx[j] + r * (anh[j] + bhn4[j]));
          const float hold = bf2f((u16)(hq >> (16 * j)));
          pk |= (u64)f2bf((1.f - z) * n + z * hold) << (16 * j);
        }
        stA64(xout + bl * 1024 + 512 + c0, pk);
        *(u64*)(outs + (size_t)(bl * 59 + t) * 1024 + c0) = pk;  // next kernel
      }
      wait_vm0();
      __syncthreads();
      if (tid == 0) stA32(&slotA[blk], t + 1);   // slot write, no RMW
    }
  } else {
    // ---- B-role: one block per batch ----
    const int b = blk - 32;
    u16* Kbl = (u16*)dls;                    // [60][512] bf16 (60KB)
    float* hsm = (float*)(dls + 61440);      // 512 f32
    u16* cxb = (u16*)(dls + 63488);          // 512 bf16
    float* scb = (float*)(dls + 64512);      // 64 f32
    float* wsb = (float*)(dls + 64768);      // 64 f32
    const u16* KAp = (const u16*)(ws + o_KA);
    const u16* Kb = (const u16*)(ws + o_Kbuf);
    const u16* WcB = (const u16*)(ws + o_WcB);
    // stage Kb rows for batch b into LDS (once)
    for (int i = tid; i < 7680; i += 512) {
      const int s = i >> 7, q = i & 127;
      ((u64*)Kbl)[i] = *(const u64*)(Kb + (size_t)(s * 32 + b) * 512 + q * 8);
    }
    f4 bcv[4];
#pragma unroll
    for (int ci = 0; ci < 4; ++ci) bcv[ci] = (f4){0.f, 0.f, 0.f, 0.f};
    if (l15 == 0) {
#pragma unroll
      for (int ci = 0; ci < 4; ++ci)
        bcv[ci] = *(const f4*)(bc + (wave + ci * 8) * 16 + lhi * 4);
    }
    __syncthreads();

    const bf8 zf = {0, 0, 0, 0, 0, 0, 0, 0};
    for (int t = 0; t < 59; ++t) {
      if (wave == 0) wait_slots(slotA, 32, t + 1);
      __syncthreads();
      const u16* xcur = xb + ((t & 1) ^ 1) * (32 * 1024);
      if (tid < 128) {  // coherent-load h (written by A this step)
        const u64 hv = ldA64(xcur + b * 1024 + 512 + tid * 4);
        const uint32 w0 = (uint32)hv, w1 = (uint32)(hv >> 32);
        hsm[tid * 4 + 0] = bfLO(w0);
        hsm[tid * 4 + 1] = bfHI(w0);
        hsm[tid * 4 + 2] = bfLO(w1);
        hsm[tid * 4 + 3] = bfHI(w1);
      }
      __syncthreads();
      if (tid < 480) {  // scores[s] = h . KA[s,b,:]  (8 lanes per s)
        const int s = tid >> 3, q = tid & 7;
        const u16* kr = KAp + (size_t)(s * 32 + b) * 512 + q * 64;
        const float* hqp = &hsm[q * 64];
        float a0 = 0.f, a1 = 0.f;
#pragma unroll
        for (int i = 0; i < 64; i += 8) {
          const uint2 k4 = *(const uint2*)(kr + i);
          const uint2 k5 = *(const uint2*)(kr + i + 4);
          const float4 h4 = *(const float4*)(hqp + i);
          const float4 h5 = *(const float4*)(hqp + i + 4);
          a0 += h4.x * bfLO(k4.x) + h4.y * bfHI(k4.x)
              + h4.z * bfLO(k4.y) + h4.w * bfHI(k4.y);
          a1 += h5.x * bfLO(k5.x) + h5.y * bfHI(k5.x)
              + h5.z * bfLO(k5.y) + h5.w * bfHI(k5.y);
        }
        float a = a0 + a1;
        a += __shfl_xor(a, 1);
        a += __shfl_xor(a, 2);
        a += __shfl_xor(a, 4);
        if (q == 0) scb[s] = a;
      }
      __syncthreads();
      if (tid < 64) {  // softmax over 60 + weights output
        const float v = (tid < 60) ? scb[tid] : -1e30f;
        float m = v;
#pragma unroll
        for (int d = 1; d < 64; d <<= 1) m = fmaxf(m, __shfl_xor(m, d));
        const float e = (tid < 60) ? __expf(v - m) : 0.f;
        float sm = e;
#pragma unroll
        for (int d = 1; d < 64; d <<= 1) sm += __shfl_xor(sm, d);
        const float w = e / sm;
        if (tid < 60) {
          wsb[tid] = w;
          out[WOFF + (size_t)(b * 59 + t) * 60 + tid] = w;
        }
      }
      __syncthreads();
      {  // ctx[d] = sum_s w[s]*K[s,b,d]  from LDS
        float c0 = 0.f, c1 = 0.f, c2 = 0.f, c3 = 0.f;
#pragma unroll
        for (int s = 0; s < 60; s += 4) {
          c0 += wsb[s]     * bf2f(Kbl[s * 512 + tid]);
          c1 += wsb[s + 1] * bf2f(Kbl[(s + 1) * 512 + tid]);
          c2 += wsb[s + 2] * bf2f(Kbl[(s + 2) * 512 + tid]);
          c3 += wsb[s + 3] * bf2f(Kbl[(s + 3) * 512 + tid]);
        }
        cxb[tid] = f2bf((c0 + c1) + (c2 + c3));
      }
      __syncthreads();
      {  // attn = tanh(Wc @ ctx + bc) via MFMA (32 ctiles over 8 waves)
        bf8 cf[16];
#pragma unroll
        for (int kc = 0; kc < 16; ++kc)
          cf[kc] = (l15 == 0) ? *(const bf8*)&cxb[kc * 32 + lhi * 8] : zf;
        f4 ac[4];
#pragma unroll
        for (int ci = 0; ci < 4; ++ci) ac[ci] = (f4){0.f, 0.f, 0.f, 0.f};
#pragma unroll
        for (int ci = 0; ci < 4; ++ci) {
          const int ctile = wave + ci * 8;
          const u16* wrow = WcB + (size_t)(ctile * 16 + l15) * 512 + lhi * 8;
#pragma unroll
          for (int kc = 0; kc < 16; ++kc)
            ac[ci] = MFMA(*(const bf8*)(wrow + kc * 32), cf[kc], ac[ci]);
        }
        u16* xout = xb + ((t & 1) ^ 1) * (32 * 1024);
        if (l15 == 0) {
#pragma unroll
          for (int ci = 0; ci < 4; ++ci) {
            const int c0 = (wave + ci * 8) * 16 + lhi * 4;
            u64 pk = 0;
#pragma unroll
            for (int j = 0; j < 4; ++j)
              pk |= (u64)f2bf(tanh_(ac[ci][j] + bcv[ci][j])) << (16 * j);
            stA64(xout + b * 1024 + c0, pk);
            *(u64*)(outs + (size_t)(b * 59 + t) * 1024 + 512 + c0) = pk;
          }
        }
      }
      wait_vm0();
      __syncthreads();
      if (tid == 0) stA32(&slotB[b], t + 1);   // slot write, no RMW
    }
  }
}

// ---------------- vocab GEMM v2: LDS-staged, double-buffered, exp+rowsum ------
__global__ __launch_bounds__(512, 2) void k_vocab2(
    const u16* __restrict__ A, const u16* __restrict__ Bm,
    const float* __restrict__ bvv, float* __restrict__ out,
    float* __restrict__ rowsum)
{
  __shared__ u16 As[2][128][40];
  __shared__ u16 Bs[2][256][40];
  const int tid = threadIdx.x;
  const int bid = blockIdx.x;
  const int xcd = bid & 7, sub = bid >> 3;
  const int wgid = (xcd < 4 ? xcd * 368 : 4 * 368 + (xcd - 4) * 367) + sub;
  const int mtile = wgid % 15, ntile = wgid / 15;
  const int rbase = mtile * 128, cbase = ntile * 256;

  const int wave = tid >> 6, lane = tid & 63;
  const int l15 = lane & 15, lhi = lane >> 4;
  const int m0 = (wave >> 2) * 64, n0 = (wave & 3) * 64;

  const int sar = tid >> 2, sak = (tid & 3) * 8;
  const u16* gA = A + (size_t)(rbase + sar) * 1024 + sak;
  const u16* gB0 = Bm + (size_t)(cbase + sar) * 1024 + sak;
  const u16* gB1 = Bm + (size_t)(cbase + 128 + sar) * 1024 + sak;

  f4 acc[4][4];
#pragma unroll
  for (int mi = 0; mi < 4; ++mi)
#pragma unroll
    for (int ni = 0; ni < 4; ++ni) acc[mi][ni] = (f4){0.f, 0.f, 0.f, 0.f};

  uint4 ra, rb0, rb1;
  ra = *(const uint4*)(gA);
  rb0 = *(const uint4*)(gB0);
  rb1 = *(const uint4*)(gB1);
  *(uint4*)&As[0][sar][sak] = ra;
  *(uint4*)&Bs[0][sar][sak] = rb0;
  *(uint4*)&Bs[0][128 + sar][sak] = rb1;
  __syncthreads();

  int cur = 0;
#pragma unroll 1
  for (int t = 0; t < 32; ++t) {
    if (t < 31) {
      const int k0 = (t + 1) * 32;
      ra = *(const uint4*)(gA + k0);
      rb0 = *(const uint4*)(gB0 + k0);
      rb1 = *(const uint4*)(gB1 + k0);
    }
    bf8 af[4], bfr[4];
#pragma unroll
    for (int mi = 0; mi < 4; ++mi)
      af[mi] = *(const bf8*)&As[cur][m0 + mi * 16 + l15][lhi * 8];
#pragma unroll
    for (int ni = 0; ni < 4; ++ni)
      bfr[ni] = *(const bf8*)&Bs[cur][n0 + ni * 16 + l15][lhi * 8];
#pragma unroll
    for (int mi = 0; mi < 4; ++mi)
#pragma unroll
      for (int ni = 0; ni < 4; ++ni)
        acc[mi][ni] = MFMA(af[mi], bfr[ni], acc[mi][ni]);
    if (t < 31) {
      __syncthreads();
      *(uint4*)&As[cur ^ 1][sar][sak] = ra;
      *(uint4*)&Bs[cur ^ 1][sar][sak] = rb0;
      *(uint4*)&Bs[cur ^ 1][128 + sar][sak] = rb1;
      __syncthreads();
      cur ^= 1;
    }
  }

#pragma unroll
  for (int mi = 0; mi < 4; ++mi) {
    float rs[4] = {0.f, 0.f, 0.f, 0.f};
#pragma unroll
    for (int ni = 0; ni < 4; ++ni) {
      const int c = cbase + n0 + ni * 16 + l15;
      if (c < 50000) {
        const float bb = bvv[c];
#pragma unroll
        for (int j = 0; j < 4; ++j) {
          const int r = rbase + m0 + mi * 16 + lhi * 4 + j;
          if (r < 1888) {
            const float e = __expf(acc[mi][ni][j] + bb);
            out[(size_t)r * 50000 + c] = e;
            rs[j] += e;
          }
        }
      }
    }
#pragma unroll
    for (int j = 0; j < 4; ++j) {
#pragma unroll
      for (int d = 1; d < 16; d <<= 1) rs[j] += __shfl_xor(rs[j], d);
    }
    if (l15 == 0) {
#pragma unroll
      for (int j = 0; j < 4; ++j) {
        const int r = rbase + m0 + mi * 16 + lhi * 4 + j;
        if (r < 1888) atomicAdd(&rowsum[r], rs[j]);
      }
    }
  }
}

// ---------------- vocab GEMM fallback (no bf16 Wv copy) -----------------------
__global__ __launch_bounds__(512) void k_vocab0(
    const u16* __restrict__ A, const float* __restrict__ WvF,
    const float* __restrict__ bv, float* __restrict__ out,
    float* __restrict__ rowsum)
{
  const int bid = blockIdx.x;
  const int x = bid & 7, jj = bid >> 3;
  const int mtile = jj % 15, nseq = jj / 15;
  const int ntile = nseq * 8 + x;
  if (ntile >= 196) return;
  const int w = threadIdx.x >> 6, lane = threadIdx.x & 63;
  const int l15 = lane & 15, lhi = lane >> 4;
  const int rbase = mtile * 128 + w * 16;
  const u16* arow = A + (size_t)(rbase + l15) * 1024 + lhi * 8;
  const int cbase = ntile * 256;
  f4 acc[16];
#pragma unroll
  for (int nn = 0; nn < 16; ++nn) acc[nn] = (f4){0.f, 0.f, 0.f, 0.f};
  for (int k = 0; k < 1024; k += 32) {
    const bf8 a = *(const bf8*)(arow + k);
#pragma unroll
    for (int nn = 0; nn < 16; ++nn) {
      const int cs = cbase + nn * 16;
      bf8 bfr = {0, 0, 0, 0, 0, 0, 0, 0};
      if (cs < 50000) {
        const float* p = WvF + (size_t)(cs + l15) * 1024 + k + lhi * 8;
        const float4 f0 = *(const float4*)p;
        const float4 f1 = *(const float4*)(p + 4);
        bfr[0] = (short)(__float_as_uint(f0.x) >> 16);
        bfr[1] = (short)(__float_as_uint(f0.y) >> 16);
        bfr[2] = (short)(__float_as_uint(f0.z) >> 16);
        bfr[3] = (short)(__float_as_uint(f0.w) >> 16);
        bfr[4] = (short)(__float_as_uint(f1.x) >> 16);
        bfr[5] = (short)(__float_as_uint(f1.y) >> 16);
        bfr[6] = (short)(__float_as_uint(f1.z) >> 16);
        bfr[7] = (short)(__float_as_uint(f1.w) >> 16);
      }
      acc[nn] = MFMA(a, bfr, acc[nn]);
    }
  }
  float rsv[4] = {0.f, 0.f, 0.f, 0.f};
#pragma unroll
  for (int nn = 0; nn < 16; ++nn) {
    const int cs = cbase + nn * 16;
    if (cs >= 50000) continue;
    const int c = cs + l15;
    const float bb = bv[c];
#pragma unroll
    for (int j = 0; j < 4; ++j) {
      const int r = rbase + lhi * 4 + j;
      if (r < 1888) {
        const float e = __expf(acc[nn][j] + bb);
        out[(size_t)r * 50000 + c] = e;
        rsv[j] += e;
      }
    }
  }
#pragma unroll
  for (int j = 0; j < 4; ++j) {
#pragma unroll
    for (int d = 1; d < 16; d <<= 1) rsv[j] += __shfl_xor(rsv[j], d);
  }
  if (l15 == 0) {
#pragma unroll
    for (int j = 0; j < 4; ++j) {
      const int r = rbase + lhi * 4 + j;
      if (r < 1888) atomicAdd(&rowsum[r], rsv[j]);
    }
  }
}

// ---------------- rowsum -> 1/rowsum ----------------
__global__ void k_invrow(float* rs)
{
  const int i = blockIdx.x * 256 + threadIdx.x;
  if (i < 1920) {
    const float s = rs[i];
    rs[i] = (s > 0.f) ? 1.f / s : 0.f;
  }
}

// ---------------- scale exp values by 1/rowsum ----------------
__global__ __launch_bounds__(256) void k_scale(float* __restrict__ out,
                                               const float* __restrict__ inv)
{
  const int bid = blockIdx.x;
  const int r = bid / 49, ch = bid - r * 49;
  const int c = ch * 1024 + threadIdx.x * 4;
  if (c < 50000) {
    const float s = inv[r];
    float4* p = (float4*)(out + (size_t)r * 50000 + c);
    float4 v = *p;
    v.x *= s; v.y *= s; v.z *= s; v.w *= s;
    *p = v;
  }
}

extern "C" void kernel_launch(void* const* d_in, const int* in_sizes, int n_in,
                              void* d_out, int out_size, void* d_ws, size_t ws_size,
                              hipStream_t stream) {
  const int* posts = (const int*)d_in[0];
  const int* resp = (const int*)d_in[1];
  const float* emb = (const float*)d_in[3];
  const float* aemb = (const float*)d_in[4];
  const float* encWi = (const float*)d_in[5];
  const float* encWh = (const float*)d_in[6];
  const float* enc_bi = (const float*)d_in[7];
  const float* enc_bh = (const float*)d_in[8];
  const float* affWi = (const float*)d_in[9];
  const float* affWh = (const float*)d_in[10];
  const float* aff_bi = (const float*)d_in[11];
  const float* aff_bh = (const float*)d_in[12];
  const float* Wp = (const float*)d_in[13];
  const float* bp = (const float*)d_in[14];
  const float* Wl = (const float*)d_in[15];
  const float* bl = (const float*)d_in[16];
  const float* dWi = (const float*)d_in[17];
  const float* dWh = (const float*)d_in[18];
  const float* dbi = (const float*)d_in[19];
  const float* dbh = (const float*)d_in[20];
  const float* Wa = (const float*)d_in[21];
  const float* Wc = (const float*)d_in[22];
  const float* bc = (const float*)d_in[23];
  const float* Wv = (const float*)d_in[24];
  const float* bv = (const float*)d_in[25];
  char* ws = (char*)d_ws;
  float* out = (float*)d_out;
  const bool useWvB = ws_size >= L::WS_FULL;

  kp_gather<<<4760, 256, 0, stream>>>(posts, resp, emb, aemb, ws);
  kp_wconv<<<19500, 256, 0, stream>>>(encWi, affWi, encWh, affWh, dWi, Wl, Wa, Wp, Wc, ws);
  kp_bcomb<<<6, 256, 0, stream>>>(dWi, bl, dbi, ws);
  if (useWvB) kp_wv<<<50176, 256, 0, stream>>>(Wv, ws);

  // Wcomb = dec_Wi @ Wl  -> f32 [1536][1328]
  k_gemm_nt<<<dim3(96, 6), 256, 0, stream>>>(
      (const u16*)(ws + L::o_decWi), (const u16*)(ws + L::o_WlT),
      (float*)(ws + L::o_Wcomb), nullptr, 1536, 1328, 512);
  kp_pack2<<<11136, 256, 0, stream>>>((const float*)(ws + L::o_Wcomb), dWh, ws);

  // input-gate precomputes
  k_gemm_nt<<<dim3(120, 6), 256, 0, stream>>>(
      (const u16*)(ws + L::o_embP), (const u16*)(ws + L::o_encWi),
      (float*)(ws + L::o_giE), enc_bi, 1920, 1536, 320);
  k_gemm_nt<<<dim3(120, 6), 256, 0, stream>>>(
      (const u16*)(ws + L::o_embA), (const u16*)(ws + L::o_affWi),
      (float*)(ws + L::o_giA), aff_bi, 1920, 1536, 320);
  k_gemm_nt<<<dim3(118, 6), 256, 0, stream>>>(
      (const u16*)(ws + L::o_embD), (const u16*)(ws + L::o_WdE),
      (float*)(ws + L::o_giD), nullptr, 1888, 1536, 320);

  k_enc<<<64, 256, 0, stream>>>(ws, enc_bh, aff_bh);
  k_mid<<<80, 256, 0, stream>>>(ws, bp);
  k_dec<<<64, 512, 65024, stream>>>(ws, out, dbh, bc);

  if (useWvB)
    k_vocab2<<<2940, 512, 0, stream>>>(
        (const u16*)(ws + L::o_outsB), (const u16*)(ws + L::o_WvB),
        bv, out, (float*)(ws + L::o_rowsum));
  else
    k_vocab0<<<2944, 512, 0, stream>>>(
        (const u16*)(ws + L::o_outsB), Wv, bv, out, (float*)(ws + L::o_rowsum));

  k_invrow<<<8, 256, 0, stream>>>((float*)(ws + L::o_rowsum));
  k_scale<<<92512, 256, 0, stream>>>(out, (const float*)(ws + L::o_rowsum));
}

// Round 9
// 2859.454 us; speedup vs baseline: 4.7671x; 1.1060x over previous
//
#include <hip/hip_runtime.h>

typedef unsigned int uint32;
typedef unsigned short u16;
typedef unsigned long long u64;
typedef __attribute__((ext_vector_type(8))) short bf8;   // 8 x bf16 (4 VGPRs)
typedef __attribute__((ext_vector_type(4))) float f4;    // 4 x f32
typedef __attribute__((ext_vector_type(4))) uint32 u32x4;

#define DEV static __device__ __forceinline__

DEV f4 MFMA(bf8 a, bf8 b, f4 c) {
  return __builtin_amdgcn_mfma_f32_16x16x32_bf16(a, b, c, 0, 0, 0);
}
DEV u16 f2bf(float f) {
  uint32 u = __float_as_uint(f);
  return (u16)((u + 0x7FFFu + ((u >> 16) & 1u)) >> 16);
}
DEV float bf2f(u16 h) { return __uint_as_float(((uint32)h) << 16); }
DEV float bfLO(uint32 u) { return __uint_as_float(u << 16); }
DEV float bfHI(uint32 u) { return __uint_as_float(u & 0xFFFF0000u); }
DEV float sigmoid_(float x) { return 1.f / (1.f + __expf(-x)); }
DEV float tanh_(float x) {
  float cx = fminf(fmaxf(x, -15.f), 15.f);
  float e = __expf(2.f * cx);
  return (e - 1.f) / (e + 1.f);
}

// ---- device-coherent (agent-scope, relaxed) data movement; compiler-tracked ----
DEV u64 ldA64(const void* p) {
  return __hip_atomic_load((u64*)p, __ATOMIC_RELAXED, __HIP_MEMORY_SCOPE_AGENT);
}
DEV void stA64(void* p, u64 v) {
  __hip_atomic_store((u64*)p, v, __ATOMIC_RELAXED, __HIP_MEMORY_SCOPE_AGENT);
}
DEV void stA32(int* p, int v) {
  __hip_atomic_store(p, v, __ATOMIC_RELAXED, __HIP_MEMORY_SCOPE_AGENT);
}
DEV bf8 pk_frag(u64 lo, u64 hi) {
  u32x4 v = {(uint32)lo, (uint32)(lo >> 32), (uint32)hi, (uint32)(hi >> 32)};
  return __builtin_bit_cast(bf8, v);
}

// ---- sync primitives ----
DEV void wait_vm0() { asm volatile("s_waitcnt vmcnt(0)" ::: "memory"); }
// slot-based barrier: producers WRITE slot[i]=tgt (no RMW); one wave polls all
// slots with a coalesced lane-load + ballot. Call from a full wave.
DEV void wait_slots(const int* slots, int n, int tgt) {
  const int lane = threadIdx.x & 63;
  for (int i = 0; i < (1 << 21); ++i) {
    int v = 0x7fffffff;
    if (lane < n)
      v = __hip_atomic_load((int*)(slots + lane), __ATOMIC_RELAXED,
                            __HIP_MEMORY_SCOPE_AGENT);
    if (__all(v >= tgt)) return;
    __builtin_amdgcn_s_sleep(1);
  }
}

namespace L {
// sizes: B=32,S=60,T=59,V=50000,E=300(pad320),H=512,3H=1536
constexpr size_t o_flags  = 0;          // 1024 int
constexpr size_t o_rowsum = 4096;       // 1920 f32
constexpr size_t o_bcomb  = 11776;      // 1536 f32
constexpr size_t o_gistat = 17920;      // 32x1536 f32
constexpr size_t o_xbuf   = 214528;     // 2x32x1024 bf16  (attn | h)
constexpr size_t o_henc   = 345600;     // 2x32x512 bf16
constexpr size_t o_haff   = 411136;     // 2x32x512 bf16
constexpr size_t o_cat    = 476672;     // 32x1024 bf16 (state_enc | state_aff)
constexpr size_t o_Kbuf   = 542208;     // 1920x512 bf16 (row = s*32+b)
constexpr size_t o_KA     = 2508288;    // 1920x512 bf16
constexpr size_t o_embP   = 4474368;    // 1920x320 bf16
constexpr size_t o_embA   = 5703168;    // 1920x320 bf16
constexpr size_t o_embD   = 6931968;    // 1888x320 bf16
constexpr size_t o_encWi  = 8140288;    // 1536x320 bf16
constexpr size_t o_affWi  = 9123328;    // 1536x320 bf16
constexpr size_t o_Whe    = 10106368;   // 1536x512 bf16
constexpr size_t o_Wha    = 11679232;   // 1536x512 bf16
constexpr size_t o_decWi  = 13252096;   // 1536x512 bf16
constexpr size_t o_WlT    = 14824960;   // 1328x512 bf16
constexpr size_t o_Wa     = 16184832;   // 512x512 bf16
constexpr size_t o_Wp     = 16709120;   // 512x1024 bf16
constexpr size_t o_wq     = 17757696;   // 32768 uint4 (packed Wc^T pairs)
constexpr size_t o_Wcomb  = 18281984;   // 1536x1328 f32
constexpr size_t o_WdE    = 26441216;   // 1536x320 bf16
constexpr size_t o_WdA    = 27424256;   // 1536x512 bf16
constexpr size_t o_Wd2    = 28997120;   // 1536x1024 bf16 (Wcomb_attn | dec_Wh)
constexpr size_t o_giE    = 32142848;   // 1920x1536 f32
constexpr size_t o_giA    = 43939328;   // 1920x1536 f32
constexpr size_t o_giD    = 55735808;   // 1888x1536 f32
constexpr size_t o_outsB  = 67335680;   // 1920x1024 bf16 (row = t*32+b : h|attn)
constexpr size_t o_WvB    = 71267840;   // 50176x1024 bf16 (optional)
constexpr size_t WS_FULL  = 174028288;
constexpr size_t WOFF = 94400000;       // weights output offset (floats)
// slots (ints): [0..31] dec A; [64..127] dec B; [128..159] enc g0; [192..223] enc g1
}

// ---------------- prep: embedding gathers -> bf16, padded K=320 ----------------
__global__ __launch_bounds__(256) void kp_gather(
    const int* __restrict__ posts, const int* __restrict__ resp,
    const float* __restrict__ emb, const float* __restrict__ aemb, char* ws)
{
  using namespace L;
  const int gid = blockIdx.x * 256 + threadIdx.x;
  const int r = gid / 320, e = gid - r * 320;
  u16* embP = (u16*)(ws + o_embP);
  u16* embA = (u16*)(ws + o_embA);
  u16* embD = (u16*)(ws + o_embD);
  if (r < 1920) {
    const int b = r & 31, s = r >> 5;
    const int tok = posts[b * 60 + s];
    embP[r * 320 + e] = f2bf(e < 300 ? emb[(size_t)tok * 300 + e] : 0.f);
    embA[r * 320 + e] = f2bf(e < 300 ? aemb[(size_t)tok * 300 + e] : 0.f);
  } else if (r < 3808) {
    const int r2 = r - 1920;
    const int b = r2 & 31, t = r2 >> 5;
    const int tok = resp[b * 60 + t];
    embD[r2 * 320 + e] = f2bf(e < 300 ? emb[(size_t)tok * 300 + e] : 0.f);
  }
}

// ---------------- prep: weight conversions / transposes / zeroing ----------------
__global__ __launch_bounds__(256) void kp_wconv(
    const float* __restrict__ encWi, const float* __restrict__ affWi,
    const float* __restrict__ encWh, const float* __restrict__ affWh,
    const float* __restrict__ dWi, const float* __restrict__ Wl,
    const float* __restrict__ Wa, const float* __restrict__ Wp,
    const float* __restrict__ Wc, char* ws)
{
  using namespace L;
  long gid = (long)blockIdx.x * 256 + threadIdx.x;
  if (gid < 983040) {  // enc_Wi / aff_Wi -> [1536][320] bf16 (pad)
    const int g = gid >= 491520;
    const long u = gid - (g ? 491520 : 0);
    const int n = (int)(u / 320), e = (int)(u - (long)n * 320);
    const float* src = g ? affWi : encWi;
    u16* dst = (u16*)(ws + (g ? o_affWi : o_encWi));
    dst[u] = f2bf(e < 300 ? src[(size_t)n * 300 + e] : 0.f);
    return;
  }
  gid -= 983040;
  if (gid < 2359296) {  // enc_Wh / aff_Wh / dec_Wi -> bf16 direct
    const int g = (int)(gid / 786432);
    const long u = gid - (long)g * 786432;
    const float* src = g == 0 ? encWh : (g == 1 ? affWh : dWi);
    u16* dst = (u16*)(ws + (g == 0 ? o_Whe : (g == 1 ? o_Wha : o_decWi)));
    dst[u] = f2bf(src[u]);
    return;
  }
  gid -= 2359296;
  if (gid < 679936) {  // Wl^T -> [1328][512] bf16 (pad rows)
    const int j = (int)(gid >> 9), k = (int)(gid & 511);
    ((u16*)(ws + o_WlT))[gid] = f2bf(j < 1324 ? Wl[(size_t)k * 1324 + j] : 0.f);
    return;
  }
  gid -= 679936;
  if (gid < 262144) { ((u16*)(ws + o_Wa))[gid] = f2bf(Wa[gid]); return; }
  gid -= 262144;
  if (gid < 524288) { ((u16*)(ws + o_Wp))[gid] = f2bf(Wp[gid]); return; }
  gid -= 524288;
  if (gid < 131072) {  // packed Wc^T pairs: u32 idx = (g4*512+j)*4+q ; d0 = g4*8+q*2
    const int q = (int)(gid & 3), j = (int)((gid >> 2) & 511), g4 = (int)(gid >> 11);
    const int d0 = g4 * 8 + q * 2;
    const uint32 lo = f2bf(Wc[(size_t)j * 512 + d0]);
    const uint32 hi = f2bf(Wc[(size_t)j * 512 + d0 + 1]);
    ((uint32*)(ws + o_wq))[gid] = lo | (hi << 16);
    return;
  }
  gid -= 131072;
  if (gid < 2944) {  // zero flags + rowsum
    if (gid < 1024) ((uint32*)(ws + o_flags))[gid] = 0;
    else ((uint32*)(ws + o_rowsum))[gid - 1024] = 0;
    return;
  }
  gid -= 2944;
  if (gid < 49152) {  // zero: outsB pad rows, henc, haff (u32 words)
    if (gid < 16384) ((uint32*)(ws + o_outsB + (size_t)1888 * 1024 * 2))[gid] = 0;
    else if (gid < 32768) ((uint32*)(ws + o_henc))[gid - 16384] = 0;
    else ((uint32*)(ws + o_haff))[gid - 32768] = 0;
  }
}

// ---------------- prep: bcomb = dec_Wi @ bl + dec_bi ----------------
__global__ __launch_bounds__(256) void kp_bcomb(
    const float* __restrict__ dWi, const float* __restrict__ bl,
    const float* __restrict__ dbi, char* ws)
{
  const int i = blockIdx.x * 256 + threadIdx.x;
  if (i >= 1536) return;
  float a = dbi[i];
  for (int k = 0; k < 512; ++k) a += dWi[(size_t)i * 512 + k] * bl[k];
  ((float*)(ws + L::o_bcomb))[i] = a;
}

// ---------------- prep: split Wcomb into bf16 pieces ----------------
__global__ __launch_bounds__(256) void kp_pack2(
    const float* __restrict__ Wcomb, const float* __restrict__ dWh, char* ws)
{
  using namespace L;
  long gid = (long)blockIdx.x * 256 + threadIdx.x;
  if (gid < 491520) {  // Wd_emb [1536][320] <- Wcomb[:,0:300]
    const int n = (int)(gid / 320), e = (int)(gid - (long)n * 320);
    ((u16*)(ws + o_WdE))[gid] = f2bf(e < 300 ? Wcomb[(size_t)n * 1328 + e] : 0.f);
    return;
  }
  gid -= 491520;
  if (gid < 786432) {  // Wd_aff [1536][512] <- Wcomb[:,300:812]
    const int n = (int)(gid >> 9), k = (int)(gid & 511);
    ((u16*)(ws + o_WdA))[gid] = f2bf(Wcomb[(size_t)n * 1328 + 300 + k]);
    return;
  }
  gid -= 786432;
  if (gid < 1572864) {  // Wd2 [1536][1024] = [Wcomb[:,812:1324] | dec_Wh]
    const int n = (int)(gid >> 10), k = (int)(gid & 1023);
    const float v = (k < 512) ? Wcomb[(size_t)n * 1328 + 812 + k]
                              : dWh[(size_t)n * 512 + (k - 512)];
    ((u16*)(ws + o_Wd2))[gid] = f2bf(v);
  }
}

// ---------------- generic MFMA GEMM: C[M][N] = A[M][Kp] * B[N][Kp]^T (+bias) ----------------
__global__ __launch_bounds__(256) void k_gemm_nt(
    const u16* __restrict__ A, const u16* __restrict__ Bm,
    float* __restrict__ C, const float* __restrict__ bias,
    const int M, const int N, const int Kp)
{
  const int mt = blockIdx.x, cb = blockIdx.y;
  const int w = threadIdx.x >> 6, lane = threadIdx.x & 63;
  const int l15 = lane & 15, lhi = lane >> 4;
  const u16* arow = A + (size_t)(mt * 16 + l15) * Kp + lhi * 8;
  const int c0 = cb * 256 + w * 64;
  f4 acc[4];
#pragma unroll
  for (int nn = 0; nn < 4; ++nn) acc[nn] = (f4){0.f, 0.f, 0.f, 0.f};
  for (int k = 0; k < Kp; k += 32) {
    const bf8 a = *(const bf8*)(arow + k);
#pragma unroll
    for (int nn = 0; nn < 4; ++nn) {
      const int cs = c0 + nn * 16;
      if (cs < N) {
        const bf8 b = *(const bf8*)(Bm + (size_t)(cs + l15) * Kp + k + lhi * 8);
        acc[nn] = MFMA(a, b, acc[nn]);
      }
    }
  }
#pragma unroll
  for (int nn = 0; nn < 4; ++nn) {
    const int cs = c0 + nn * 16;
    if (cs >= N) continue;
    const int c = cs + l15;
    const float bb = bias ? bias[c] : 0.f;
#pragma unroll
    for (int j = 0; j < 4; ++j) {
      const int r = mt * 16 + lhi * 4 + j;
      C[(size_t)r * N + c] = acc[nn][j] + bb;
    }
  }
}

// -------- encoder + fused bulk: blk<64 enc; blk<772 giD gemm; else Wv->bf16 ----
__global__ __launch_bounds__(256) void k_encplus(
    char* __restrict__ ws, const float* __restrict__ enc_bh,
    const float* __restrict__ aff_bh, const float* __restrict__ Wv)
{
  using namespace L;
  const int tid = threadIdx.x, blk = blockIdx.x;
  const int wave = tid >> 6, lane = tid & 63;
  const int l15 = lane & 15, lhi = lane >> 4;

  if (blk < 64) {
    // ===== encoder role (round-6 proven): 32 blocks per GRU, 2 active waves =====
    const int g = blk >> 5;
    const bool act = wave < 2;
    int* flags = (int*)(ws + o_flags);
    int* slotE = flags + 128 + g * 64;
    const u16* Wh = (const u16*)(ws + (g ? o_Wha : o_Whe));
    const float* gi = (const float*)(ws + (g ? o_giA : o_giE));
    const float* bh = g ? aff_bh : enc_bh;
    u16* hbuf = (u16*)(ws + (g ? o_haff : o_henc));
    u16* cat = (u16*)(ws + o_cat);
    u16* Kb = (u16*)(ws + o_Kbuf);

    const int wid = (blk & 31) * 2 + (wave & 1);     // 0..63 when act
    const int btile = wid >> 5, ctile = wid & 31;
    const int bl = btile * 16 + l15;
    const int c0 = ctile * 16 + lhi * 4;
    const u16* wr0 = Wh + (size_t)(ctile * 16 + l15) * 512 + lhi * 8;
    const u16* wr1 = wr0 + (size_t)512 * 512;
    const u16* wr2 = wr1 + (size_t)512 * 512;
    f4 bhr4 = {0.f, 0.f, 0.f, 0.f}, bhz4 = bhr4, bhn4 = bhr4;
    if (act) {
      bhr4 = *(const f4*)(bh + c0);
      bhz4 = *(const f4*)(bh + 512 + c0);
      bhn4 = *(const f4*)(bh + 1024 + c0);
    }
    for (int s = 0; s < 60; ++s) {
      const u16* hin = hbuf + (s & 1) * (32 * 512);
      u16* hout = hbuf + ((s & 1) ^ 1) * (32 * 512);
      if (act) {
        const u16* brow = hin + bl * 512 + lhi * 8;
        u64 flo[16], fhi[16];
#pragma unroll
        for (int kk = 0; kk < 16; ++kk) {      // batched: one exposed latency
          flo[kk] = ldA64(brow + kk * 32);
          fhi[kk] = ldA64(brow + kk * 32 + 4);
        }
        const u64 hq = ldA64(hin + bl * 512 + c0);
        f4 ar = {0.f, 0.f, 0.f, 0.f}, az = ar, an = ar;
#pragma unroll
        for (int kk = 0; kk < 16; ++kk) {
          const bf8 hf = pk_frag(flo[kk], fhi[kk]);
          ar = MFMA(*(const bf8*)(wr0 + kk * 32), hf, ar);
          az = MFMA(*(const bf8*)(wr1 + kk * 32), hf, az);
          an = MFMA(*(const bf8*)(wr2 + kk * 32), hf, an);
        }
        const float* gr = gi + (size_t)(s * 32 + bl) * 1536;
        const f4 g0 = *(const f4*)(gr + c0);
        const f4 g1 = *(const f4*)(gr + 512 + c0);
        const f4 g2 = *(const f4*)(gr + 1024 + c0);
        u64 pk = 0;
#pragma unroll
        for (int j = 0; j < 4; ++j) {
          const float r = sigmoid_(g0[j] + ar[j] + bhr4[j]);
          const float z = sigmoid_(g1[j] + az[j] + bhz4[j]);
          const float n = tanh_(g2[j] + r * (an[j] + bhn4[j]));
          const float hold = bf2f((u16)(hq >> (16 * j)));
          pk |= (u64)f2bf((1.f - z) * n + z * hold) << (16 * j);
        }
        stA64(hout + bl * 512 + c0, pk);
        if (g) *(u64*)(Kb + (size_t)(s * 32 + bl) * 512 + c0) = pk;  // next kernel
        if (s == 59) *(u64*)(cat + bl * 1024 + g * 512 + c0) = pk;   // next kernel
      }
      wait_vm0();
      __syncthreads();
      if (tid == 0) stA32(&slotE[blk & 31], s + 1);   // slot write, no RMW
      if (wave == 2) wait_slots(slotE, 32, s + 1);    // idle wave polls
      __syncthreads();
    }
  } else if (blk < 772) {
    // ===== giD = embD @ WdE^T  (fused; consumed by next-next kernel) =====
    const int bb = blk - 64;
    const int mt = bb % 118, cb = bb / 118;
    const u16* A = (const u16*)(ws + o_embD);
    const u16* Bm = (const u16*)(ws + o_WdE);
    float* C = (float*)(ws + o_giD);
    const int Kp = 320, N = 1536;
    const int w = wave;
    const u16* arow = A + (size_t)(mt * 16 + l15) * Kp + lhi * 8;
    const int c0 = cb * 256 + w * 64;
    f4 acc[4];
#pragma unroll
    for (int nn = 0; nn < 4; ++nn) acc[nn] = (f4){0.f, 0.f, 0.f, 0.f};
    for (int k = 0; k < Kp; k += 32) {
      const bf8 a = *(const bf8*)(arow + k);
#pragma unroll
      for (int nn = 0; nn < 4; ++nn) {
        const bf8 b = *(const bf8*)(Bm + (size_t)(c0 + nn * 16 + l15) * Kp + k + lhi * 8);
        acc[nn] = MFMA(a, b, acc[nn]);
      }
    }
#pragma unroll
    for (int nn = 0; nn < 4; ++nn) {
      const int c = c0 + nn * 16 + l15;
#pragma unroll
      for (int j = 0; j < 4; ++j)
        C[(size_t)(mt * 16 + lhi * 4 + j) * N + c] = acc[nn][j];
    }
  } else {
    // ===== Wv -> bf16 (padded rows) fused =====
    const long gid = (long)(blk - 772) * 256 + tid;
    const int r = (int)(gid >> 8), q = (int)(gid & 255);
    u16* WvB = (u16*)(ws + o_WvB);
    uint2 o;
    if (r < 50000) {
      const float4 f = *(const float4*)(Wv + (size_t)r * 1024 + q * 4);
      o.x = (uint32)f2bf(f.x) | ((uint32)f2bf(f.y) << 16);
      o.y = (uint32)f2bf(f.z) | ((uint32)f2bf(f.w) << 16);
    } else { o.x = 0u; o.y = 0u; }
    if (r < 50176) *(uint2*)(WvB + (size_t)r * 1024 + q * 4) = o;
  }
}

// ---------------- mid kernel: state0 | gi_static | KA (no sync needed) ----------
__global__ __launch_bounds__(256) void k_mid(char* __restrict__ ws,
                                             const float* __restrict__ bp)
{
  using namespace L;
  const int tid = threadIdx.x, blk = blockIdx.x;
  const int wave = tid >> 6, lane = tid & 63;
  const int l15 = lane & 15, lhi = lane >> 4;
  u16* xb = (u16*)(ws + o_xbuf);
  u16* cat = (u16*)(ws + o_cat);
  u16* Kb = (u16*)(ws + o_Kbuf);

  if (blk < 16) {  // state0 = tanh(cat @ Wp^T + bp) -> xbuf[0]; zero attn half
    const u16* Wp_ = (const u16*)(ws + o_Wp);
    const int wid = blk * 4 + wave;
    const int btile = wid >> 5, ctile = wid & 31;
    const int bl = btile * 16 + l15;
    const int c0 = ctile * 16 + lhi * 4;
    const u16* arow = Wp_ + (size_t)(ctile * 16 + l15) * 1024 + lhi * 8;
    const u16* brow = cat + bl * 1024 + lhi * 8;
    f4 acc = {0.f, 0.f, 0.f, 0.f};
    for (int k = 0; k < 1024; k += 32)
      acc = MFMA(*(const bf8*)(arow + k), *(const bf8*)(brow + k), acc);
    const f4 bp4 = *(const f4*)(bp + c0);
    u64 pk = 0;
#pragma unroll
    for (int j = 0; j < 4; ++j)
      pk |= (u64)f2bf(tanh_(acc[j] + bp4[j])) << (16 * j);
    *(u64*)(xb + bl * 1024 + 512 + c0) = pk;
    *(u64*)(xb + bl * 1024 + c0) = 0;          // init attn = 0
  } else if (blk < 32) {  // gi_static = ctx_aff @ Wd_aff^T + bcomb
    const u16* WdA = (const u16*)(ws + o_WdA);
    const float* bco = (const float*)(ws + o_bcomb);
    float* gst = (float*)(ws + o_gistat);
    const int wid = (blk - 16) * 4 + wave;
    const int btile = wid >> 5, ctb = wid & 31;
    const int bl = btile * 16 + l15;
    const int c0 = ctb * 16 + lhi * 4;
    const u16* brow = cat + bl * 1024 + 512 + lhi * 8;
    const u16* a0p = WdA + (size_t)(ctb * 16 + l15) * 512 + lhi * 8;
    const u16* a1p = a0p + (size_t)512 * 512;
    const u16* a2p = a1p + (size_t)512 * 512;
    f4 a0 = {0.f, 0.f, 0.f, 0.f}, a1 = a0, a2 = a0;
    for (int k = 0; k < 512; k += 32) {
      const bf8 bfr = *(const bf8*)(brow + k);
      a0 = MFMA(*(const bf8*)(a0p + k), bfr, a0);
      a1 = MFMA(*(const bf8*)(a1p + k), bfr, a1);
      a2 = MFMA(*(const bf8*)(a2p + k), bfr, a2);
    }
    const f4 v0 = *(const f4*)(bco + c0);
    const f4 v1 = *(const f4*)(bco + 512 + c0);
    const f4 v2 = *(const f4*)(bco + 1024 + c0);
    *(f4*)(gst + bl * 1536 + c0) = a0 + v0;
    *(f4*)(gst + bl * 1536 + 512 + c0) = a1 + v1;
    *(f4*)(gst + bl * 1536 + 1024 + c0) = a2 + v2;
  } else {  // KA = K @ Wa^T
    const u16* Wa_ = (const u16*)(ws + o_Wa);
    u16* KAp = (u16*)(ws + o_KA);
    const int widK = (blk - 32) * 4 + wave;
    for (int task = widK; task < 3840; task += 192) {
      const int mt = task >> 5, ct = task & 31;
      const int m = mt * 16 + l15;
      const int c0 = ct * 16 + lhi * 4;
      const u16* arow = Wa_ + (size_t)(ct * 16 + l15) * 512 + lhi * 8;
      const u16* brow = Kb + (size_t)m * 512 + lhi * 8;
      f4 acc = {0.f, 0.f, 0.f, 0.f};
      for (int k = 0; k < 512; k += 32)
        acc = MFMA(*(const bf8*)(arow + k), *(const bf8*)(brow + k), acc);
      u64 pk = 0;
#pragma unroll
      for (int j = 0; j < 4; ++j) pk |= (u64)f2bf(acc[j]) << (16 * j);
      *(u64*)(KAp + (size_t)m * 512 + c0) = pk;
    }
  }
}

// ----- fused decoder + vocab GEMM: blk<96 dec (round-6 proven); else vocab ----
// outs rows are t-major (row = t*32+b), written agent-scope so vocab tiles can
// consume them in-flight, gated on slotB progress + one acquire fence.
__global__ __launch_bounds__(256, 1) void k_decvoc(
    char* __restrict__ ws, float* __restrict__ out,
    const float* __restrict__ dec_bh, const float* __restrict__ bc,
    const float* __restrict__ bv)
{
  using namespace L;
  const int tid = threadIdx.x, blk = blockIdx.x;
  const int wave = tid >> 6, lane = tid & 63;
  const int l15 = lane & 15, lhi = lane >> 4;
  int* flags = (int*)(ws + o_flags);
  int* slotA = flags;        // 32
  int* slotB = flags + 64;   // 64

  __shared__ float hsm[512];
  __shared__ float ctxs[512];
  __shared__ float scb[64];
  __shared__ float wsb[64];
  __shared__ u16 attn_sm[256];
  __shared__ u16 vAs[2][128][40];
  __shared__ u16 vBs[2][128][40];

  u16* xb = (u16*)(ws + o_xbuf);
  u16* outs = (u16*)(ws + o_outsB);

  if (blk < 32) {
    // A-role: h_t = GRU from [attn_{t-1} ; h_{t-1}] via Wd2 (K=1024), n-gate split.
    const bool act = wave < 2;
    const u16* Wd2 = (const u16*)(ws + o_Wd2);
    const float* gst = (const float*)(ws + o_gistat);
    const float* gD = (const float*)(ws + o_giD);
    const int wid = (blk & 31) * 2 + (wave & 1);
    const int btile = wid >> 5, ctile = wid & 31;
    const int bl = btile * 16 + l15;
    const int c0 = ctile * 16 + lhi * 4;
    const u16* wr = Wd2 + (size_t)(ctile * 16 + l15) * 1024 + lhi * 8;
    const u16* wz = wr + (size_t)512 * 1024;
    const u16* wn = wz + (size_t)512 * 1024;
    f4 bhr4 = {0.f, 0.f, 0.f, 0.f}, bhz4 = bhr4, bhn4 = bhr4;
    f4 s0 = bhr4, s1 = bhr4, s2 = bhr4;
    if (act) {
      bhr4 = *(const f4*)(dec_bh + c0);
      bhz4 = *(const f4*)(dec_bh + 512 + c0);
      bhn4 = *(const f4*)(dec_bh + 1024 + c0);
      s0 = *(const f4*)(gst + bl * 1536 + c0);
      s1 = *(const f4*)(gst + bl * 1536 + 512 + c0);
      s2 = *(const f4*)(gst + bl * 1536 + 1024 + c0);
    }
    for (int t = 0; t < 59; ++t) {
      const u16* xin = xb + (t & 1) * (32 * 1024);
      u16* xout = xb + ((t & 1) ^ 1) * (32 * 1024);
      const u16* brow = xin + bl * 1024 + lhi * 8;
      f4 ar = {0.f, 0.f, 0.f, 0.f}, az = ar, anx = ar, anh = ar;
      u64 hq = 0;
      f4 d0 = ar, d1 = ar, d2 = ar;
      // ---- stage 1: needs h(t-1) = all A slots >= t ----
      if (t) {
        if (wave == 2) wait_slots(slotA, 32, t);
        __syncthreads();
      }
      if (act) {
        u64 flo[16], fhi[16];
#pragma unroll
        for (int kk = 0; kk < 16; ++kk) {
          flo[kk] = ldA64(brow + (16 + kk) * 32);
          fhi[kk] = ldA64(brow + (16 + kk) * 32 + 4);
        }
        hq = ldA64(xin + bl * 1024 + 512 + c0);
        const float* g2p = gD + (size_t)(t * 32 + bl) * 1536;   // static prefetch
        d0 = *(const f4*)(g2p + c0);
        d1 = *(const f4*)(g2p + 512 + c0);
        d2 = *(const f4*)(g2p + 1024 + c0);
#pragma unroll
        for (int kk = 0; kk < 16; ++kk) {
          const bf8 xf = pk_frag(flo[kk], fhi[kk]);
          ar = MFMA(*(const bf8*)(wr + (16 + kk) * 32), xf, ar);
          az = MFMA(*(const bf8*)(wz + (16 + kk) * 32), xf, az);
          anh = MFMA(*(const bf8*)(wn + (16 + kk) * 32), xf, anh);
        }
      }
      // ---- stage 2: needs attn(t-1) = all B slots >= t ----
      if (t) {
        if (wave == 2) wait_slots(slotB, 64, t);
        __syncthreads();
      }
      if (act) {
        u64 glo[16], ghi[16];
#pragma unroll
        for (int kk = 0; kk < 16; ++kk) {
          glo[kk] = ldA64(brow + kk * 32);
          ghi[kk] = ldA64(brow + kk * 32 + 4);
        }
#pragma unroll
        for (int kk = 0; kk < 16; ++kk) {
          const bf8 xf = pk_frag(glo[kk], ghi[kk]);
          ar = MFMA(*(const bf8*)(wr + kk * 32), xf, ar);
          az = MFMA(*(const bf8*)(wz + kk * 32), xf, az);
          anx = MFMA(*(const bf8*)(wn + kk * 32), xf, anx);
        }
        u64 pk = 0;
#pragma unroll
        for (int j = 0; j < 4; ++j) {
          const float r = sigmoid_(s0[j] + d0[j] + ar[j] + bhr4[j]);
          const float z = sigmoid_(s1[j] + d1[j] + az[j] + bhz4[j]);
          const float n = tanh_(s2[j] + d2[j] + anx[j] + r * (anh[j] + bhn4[j]));
          const float hold = bf2f((u16)(hq >> (16 * j)));
          pk |= (u64)f2bf((1.f - z) * n + z * hold) << (16 * j);
        }
        stA64(xout + bl * 1024 + 512 + c0, pk);
        stA64(outs + (size_t)(t * 32 + bl) * 1024 + c0, pk);  // t-major, visible
      }
      wait_vm0();
      __syncthreads();
      if (tid == 0) stA32(&slotA[blk], t + 1);   // slot write, no RMW
    }
  } else if (blk < 96) {
    // B-role: 2 blocks per batch element: scores -> softmax -> ctx -> attn
    const int idx = blk - 32;
    const int b = idx >> 1, half = idx & 1;
    const u16* KAp = (const u16*)(ws + o_KA);
    const u16* Kb = (const u16*)(ws + o_Kbuf);
    const uint4* wq = (const uint4*)(ws + o_wq);
    for (int t = 0; t < 59; ++t) {
      if (wave == 0) wait_slots(slotA, 32, t + 1);
      __syncthreads();
      const u16* xcur = xb + ((t & 1) ^ 1) * (32 * 1024);
      if (tid < 128) {  // coherent-load h (written by A this step)
        const u64 hv = ldA64(xcur + b * 1024 + 512 + tid * 4);
        const uint32 w0 = (uint32)hv, w1 = (uint32)(hv >> 32);
        hsm[tid * 4 + 0] = bfLO(w0);
        hsm[tid * 4 + 1] = bfHI(w0);
        hsm[tid * 4 + 2] = bfLO(w1);
        hsm[tid * 4 + 3] = bfHI(w1);
      }
      __syncthreads();
      if (tid < 240) {  // scores[s] = h . KA[s,b,:]   (2 accumulator chains)
        const int s = tid >> 2, q = tid & 3;
        const u16* kr = KAp + (size_t)(s * 32 + b) * 512 + q * 128;
        const float* hq = &hsm[q * 128];
        float acc0 = 0.f, acc1 = 0.f;
#pragma unroll 4
        for (int i = 0; i < 128; i += 8) {
          const uint2 k4 = *(const uint2*)(kr + i);
          const uint2 k5 = *(const uint2*)(kr + i + 4);
          const float4 h4 = *(const float4*)(hq + i);
          const float4 h5 = *(const float4*)(hq + i + 4);
          acc0 += h4.x * bfLO(k4.x) + h4.y * bfHI(k4.x)
                + h4.z * bfLO(k4.y) + h4.w * bfHI(k4.y);
          acc1 += h5.x * bfLO(k5.x) + h5.y * bfHI(k5.x)
                + h5.z * bfLO(k5.y) + h5.w * bfHI(k5.y);
        }
        float acc = acc0 + acc1;
        acc += __shfl_xor(acc, 1);
        acc += __shfl_xor(acc, 2);
        if ((tid & 3) == 0) scb[s] = acc;
      }
      __syncthreads();
      if (tid < 64) {  // softmax over 60
        const float v = (tid < 60) ? scb[tid] : -1e30f;
        float m = v;
#pragma unroll
        for (int d = 1; d < 64; d <<= 1) m = fmaxf(m, __shfl_xor(m, d));
        const float e = (tid < 60) ? __expf(v - m) : 0.f;
        float sm = e;
#pragma unroll
        for (int d = 1; d < 64; d <<= 1) sm += __shfl_xor(sm, d);
        const float w = e / sm;
        if (tid < 60) {
          wsb[tid] = w;
          if (half == 0) out[WOFF + (size_t)(b * 59 + t) * 60 + tid] = w;
        }
      }
      __syncthreads();
      {  // ctx = sum_s w[s] * K[s,b,:]  (4 accumulator chains)
        float c0a = 0.f, c0b = 0.f, c1a = 0.f, c1b = 0.f;
#pragma unroll 2
        for (int s = 0; s < 60; s += 2) {
          const float w0 = wsb[s], w1 = wsb[s + 1];
          const u16* kr0 = Kb + (size_t)(s * 32 + b) * 512;
          const u16* kr1 = Kb + (size_t)((s + 1) * 32 + b) * 512;
          c0a += w0 * bf2f(kr0[tid]);
          c1a += w0 * bf2f(kr0[tid + 256]);
          c0b += w1 * bf2f(kr1[tid]);
          c1b += w1 * bf2f(kr1[tid + 256]);
        }
        ctxs[tid] = c0a + c0b;
        ctxs[tid + 256] = c1a + c1b;
      }
      __syncthreads();
      const int jj = half * 256 + tid;  // attn[jj] = tanh(bc + ctx . Wc[jj,:])
      float faa[4] = {0.f, 0.f, 0.f, 0.f};
      float fbb[4] = {0.f, 0.f, 0.f, 0.f};
#pragma unroll 4
      for (int g4 = 0; g4 < 64; ++g4) {
        const uint4 wv4 = wq[g4 * 512 + jj];
        const float4 ca = *(const float4*)&ctxs[g4 * 8];
        const float4 cb2 = *(const float4*)&ctxs[g4 * 8 + 4];
        faa[g4 & 3] += ca.x * bfLO(wv4.x) + ca.y * bfHI(wv4.x)
                     + ca.z * bfLO(wv4.y) + ca.w * bfHI(wv4.y);
        fbb[g4 & 3] += cb2.x * bfLO(wv4.z) + cb2.y * bfHI(wv4.z)
                     + cb2.z * bfLO(wv4.w) + cb2.w * bfHI(wv4.w);
      }
      const float fa = bc[jj] + faa[0] + faa[1] + faa[2] + faa[3]
                     + fbb[0] + fbb[1] + fbb[2] + fbb[3];
      attn_sm[tid] = f2bf(tanh_(fa));
      __syncthreads();
      if (tid < 64) {  // pack 4 attn values -> coherent u64 store
        u16* xout = xb + ((t & 1) ^ 1) * (32 * 1024);
        const u64 pk = (u64)attn_sm[tid * 4] | ((u64)attn_sm[tid * 4 + 1] << 16)
                     | ((u64)attn_sm[tid * 4 + 2] << 32) | ((u64)attn_sm[tid * 4 + 3] << 48);
        const int cc = half * 256 + tid * 4;
        stA64(xout + b * 1024 + cc, pk);
        stA64(outs + (size_t)(t * 32 + b) * 1024 + 512 + cc, pk);  // t-major
      }
      wait_vm0();
      __syncthreads();
      if (tid == 0) stA32(&slotB[idx], t + 1);   // slot write, no RMW
    }
  } else {
    // ===== vocab role: 128x128 tile, gated on decoder progress =====
    const int vb = blk - 96;
    const int mtile = vb / 392, ntile = vb % 392;   // mtile-major: early t first
    const int rbase = mtile * 128, cbase = ntile * 128;
    const int tgt = (4 * mtile + 4 < 59) ? (4 * mtile + 4) : 59;
    if (wave == 0) {
      wait_slots(slotB, 64, tgt);
      __builtin_amdgcn_fence(__ATOMIC_ACQUIRE, "agent");  // invalidate stale L1/L2
    }
    __syncthreads();

    const u16* A = outs;                     // t-major rows
    const u16* Bm = (const u16*)(ws + o_WvB);
    float* rowsum = (float*)(ws + o_rowsum);
    const int m0 = (wave >> 1) * 64, n0 = (wave & 1) * 64;
    const int sr0 = tid >> 2, sk = (tid & 3) * 8;  // + row 64 offset for 2nd load

    f4 acc[4][4];
#pragma unroll
    for (int mi = 0; mi < 4; ++mi)
#pragma unroll
      for (int ni = 0; ni < 4; ++ni) acc[mi][ni] = (f4){0.f, 0.f, 0.f, 0.f};

    const u16* gA0 = A + (size_t)(rbase + sr0) * 1024 + sk;
    const u16* gA1 = A + (size_t)(rbase + 64 + sr0) * 1024 + sk;
    const u16* gB0 = Bm + (size_t)(cbase + sr0) * 1024 + sk;
    const u16* gB1 = Bm + (size_t)(cbase + 64 + sr0) * 1024 + sk;

    uint4 a0 = *(const uint4*)(gA0), a1 = *(const uint4*)(gA1);
    uint4 b0 = *(const uint4*)(gB0), b1 = *(const uint4*)(gB1);
    *(uint4*)&vAs[0][sr0][sk] = a0;
    *(uint4*)&vAs[0][64 + sr0][sk] = a1;
    *(uint4*)&vBs[0][sr0][sk] = b0;
    *(uint4*)&vBs[0][64 + sr0][sk] = b1;
    __syncthreads();

    int cur = 0;
#pragma unroll 1
    for (int kt = 0; kt < 32; ++kt) {
      if (kt < 31) {
        const int k0 = (kt + 1) * 32;
        a0 = *(const uint4*)(gA0 + k0);
        a1 = *(const uint4*)(gA1 + k0);
        b0 = *(const uint4*)(gB0 + k0);
        b1 = *(const uint4*)(gB1 + k0);
      }
      bf8 af[4], bfr[4];
#pragma unroll
      for (int mi = 0; mi < 4; ++mi)
        af[mi] = *(const bf8*)&vAs[cur][m0 + mi * 16 + l15][lhi * 8];
#pragma unroll
      for (int ni = 0; ni < 4; ++ni)
        bfr[ni] = *(const bf8*)&vBs[cur][n0 + ni * 16 + l15][lhi * 8];
#pragma unroll
      for (int mi = 0; mi < 4; ++mi)
#pragma unroll
        for (int ni = 0; ni < 4; ++ni)
          acc[mi][ni] = MFMA(af[mi], bfr[ni], acc[mi][ni]);
      if (kt < 31) {
        __syncthreads();
        *(uint4*)&vAs[cur ^ 1][sr0][sk] = a0;
        *(uint4*)&vAs[cur ^ 1][64 + sr0][sk] = a1;
        *(uint4*)&vBs[cur ^ 1][sr0][sk] = b0;
        *(uint4*)&vBs[cur ^ 1][64 + sr0][sk] = b1;
        __syncthreads();
        cur ^= 1;
      }
    }

    // epilogue: exp + store (row mapped t-major -> b*59+t) + rowsum atomics
#pragma unroll
    for (int mi = 0; mi < 4; ++mi) {
      float rs[4] = {0.f, 0.f, 0.f, 0.f};
      int ro_[4]; bool rv[4];
#pragma unroll
      for (int j = 0; j < 4; ++j) {
        const int r = rbase + m0 + mi * 16 + lhi * 4 + j;
        const int tt = r >> 5, bb2 = r & 31;
        rv[j] = tt < 59;
        ro_[j] = bb2 * 59 + tt;
      }
#pragma unroll
      for (int ni = 0; ni < 4; ++ni) {
        const int c = cbase + n0 + ni * 16 + l15;
        if (c < 50000) {
          const float bb = bv[c];
#pragma unroll
          for (int j = 0; j < 4; ++j) {
            if (rv[j]) {
              const float e = __expf(acc[mi][ni][j] + bb);
              out[(size_t)ro_[j] * 50000 + c] = e;
              rs[j] += e;
            }
          }
        }
      }
#pragma unroll
      for (int j = 0; j < 4; ++j) {
#pragma unroll
        for (int d = 1; d < 16; d <<= 1) rs[j] += __shfl_xor(rs[j], d);
      }
      if (l15 == 0) {
#pragma unroll
        for (int j = 0; j < 4; ++j)
          if (rv[j]) atomicAdd(&rowsum[ro_[j]], rs[j]);
      }
    }
  }
}

// ---------------- vocab GEMM fallback (no bf16 Wv copy; t-major outs) ---------
__global__ __launch_bounds__(512) void k_vocab0(
    const u16* __restrict__ A, const float* __restrict__ WvF,
    const float* __restrict__ bv, float* __restrict__ out,
    float* __restrict__ rowsum)
{
  const int bid = blockIdx.x;
  const int x = bid & 7, jj = bid >> 3;
  const int mtile = jj % 15, nseq = jj / 15;
  const int ntile = nseq * 8 + x;
  if (ntile >= 196) return;
  const int w = threadIdx.x >> 6, lane = threadIdx.x & 63;
  const int l15 = lane & 15, lhi = lane >> 4;
  const int rbase = mtile * 128 + w * 16;
  const u16* arow = A + (size_t)(rbase + l15) * 1024 + lhi * 8;
  const int cbase = ntile * 256;
  f4 acc[16];
#pragma unroll
  for (int nn = 0; nn < 16; ++nn) acc[nn] = (f4){0.f, 0.f, 0.f, 0.f};
  for (int k = 0; k < 1024; k += 32) {
    const bf8 a = *(const bf8*)(arow + k);
#pragma unroll
    for (int nn = 0; nn < 16; ++nn) {
      const int cs = cbase + nn * 16;
      bf8 bfr = {0, 0, 0, 0, 0, 0, 0, 0};
      if (cs < 50000) {
        const float* p = WvF + (size_t)(cs + l15) * 1024 + k + lhi * 8;
        const float4 f0 = *(const float4*)p;
        const float4 f1 = *(const float4*)(p + 4);
        bfr[0] = (short)(__float_as_uint(f0.x) >> 16);
        bfr[1] = (short)(__float_as_uint(f0.y) >> 16);
        bfr[2] = (short)(__float_as_uint(f0.z) >> 16);
        bfr[3] = (short)(__float_as_uint(f0.w) >> 16);
        bfr[4] = (short)(__float_as_uint(f1.x) >> 16);
        bfr[5] = (short)(__float_as_uint(f1.y) >> 16);
        bfr[6] = (short)(__float_as_uint(f1.z) >> 16);
        bfr[7] = (short)(__float_as_uint(f1.w) >> 16);
      }
      acc[nn] = MFMA(a, bfr, acc[nn]);
    }
  }
#pragma unroll
  for (int j = 0; j < 4; ++j) {
    const int r = rbase + lhi * 4 + j;
    const int tt = r >> 5, bb2 = r & 31;
    if (tt >= 59) continue;
    const int ro = bb2 * 59 + tt;
    float rsv = 0.f;
#pragma unroll
    for (int nn = 0; nn < 16; ++nn) {
      const int cs = cbase + nn * 16;
      if (cs >= 50000) continue;
      const int c = cs + l15;
      const float e = __expf(acc[nn][j] + bv[c]);
      out[(size_t)ro * 50000 + c] = e;
      rsv += e;
    }
#pragma unroll
    for (int d = 1; d < 16; d <<= 1) rsv += __shfl_xor(rsv, d);
    if (l15 == 0) atomicAdd(&rowsum[ro], rsv);
  }
}

// ---------------- rowsum -> 1/rowsum ----------------
__global__ void k_invrow(float* rs)
{
  const int i = blockIdx.x * 256 + threadIdx.x;
  if (i < 1920) {
    const float s = rs[i];
    rs[i] = (s > 0.f) ? 1.f / s : 0.f;
  }
}

// ---------------- scale exp values by 1/rowsum ----------------
__global__ __launch_bounds__(256) void k_scale(float* __restrict__ out,
                                               const float* __restrict__ inv)
{
  const int bid = blockIdx.x;
  const int r = bid / 49, ch = bid - r * 49;
  const int c = ch * 1024 + threadIdx.x * 4;
  if (c < 50000) {
    const float s = inv[r];
    float4* p = (float4*)(out + (size_t)r * 50000 + c);
    float4 v = *p;
    v.x *= s; v.y *= s; v.z *= s; v.w *= s;
    *p = v;
  }
}

extern "C" void kernel_launch(void* const* d_in, const int* in_sizes, int n_in,
                              void* d_out, int out_size, void* d_ws, size_t ws_size,
                              hipStream_t stream) {
  const int* posts = (const int*)d_in[0];
  const int* resp = (const int*)d_in[1];
  const float* emb = (const float*)d_in[3];
  const float* aemb = (const float*)d_in[4];
  const float* encWi = (const float*)d_in[5];
  const float* encWh = (const float*)d_in[6];
  const float* enc_bi = (const float*)d_in[7];
  const float* enc_bh = (const float*)d_in[8];
  const float* affWi = (const float*)d_in[9];
  const float* affWh = (const float*)d_in[10];
  const float* aff_bi = (const float*)d_in[11];
  const float* aff_bh = (const float*)d_in[12];
  const float* Wp = (const float*)d_in[13];
  const float* bp = (const float*)d_in[14];
  const float* Wl = (const float*)d_in[15];
  const float* bl = (const float*)d_in[16];
  const float* dWi = (const float*)d_in[17];
  const float* dWh = (const float*)d_in[18];
  const float* dbi = (const float*)d_in[19];
  const float* dbh = (const float*)d_in[20];
  const float* Wa = (const float*)d_in[21];
  const float* Wc = (const float*)d_in[22];
  const float* bc = (const float*)d_in[23];
  const float* Wv = (const float*)d_in[24];
  const float* bv = (const float*)d_in[25];
  char* ws = (char*)d_ws;
  float* out = (float*)d_out;
  const bool useWvB = ws_size >= L::WS_FULL;

  kp_gather<<<4760, 256, 0, stream>>>(posts, resp, emb, aemb, ws);
  kp_wconv<<<19500, 256, 0, stream>>>(encWi, affWi, encWh, affWh, dWi, Wl, Wa, Wp, Wc, ws);
  kp_bcomb<<<6, 256, 0, stream>>>(dWi, bl, dbi, ws);

  // Wcomb = dec_Wi @ Wl  -> f32 [1536][1328]
  k_gemm_nt<<<dim3(96, 6), 256, 0, stream>>>(
      (const u16*)(ws + L::o_decWi), (const u16*)(ws + L::o_WlT),
      (float*)(ws + L::o_Wcomb), nullptr, 1536, 1328, 512);
  kp_pack2<<<11136, 256, 0, stream>>>((const float*)(ws + L::o_Wcomb), dWh, ws);

  // input-gate precomputes (giD is fused into k_encplus)
  k_gemm_nt<<<dim3(120, 6), 256, 0, stream>>>(
      (const u16*)(ws + L::o_embP), (const u16*)(ws + L::o_encWi),
      (float*)(ws + L::o_giE), enc_bi, 1920, 1536, 320);
  k_gemm_nt<<<dim3(120, 6), 256, 0, stream>>>(
      (const u16*)(ws + L::o_embA), (const u16*)(ws + L::o_affWi),
      (float*)(ws + L::o_giA), aff_bi, 1920, 1536, 320);

  // encoder chain + fused bulk (giD gemm + Wv->bf16 conversion)
  k_encplus<<<useWvB ? 50948 : 772, 256, 0, stream>>>(ws, enc_bh, aff_bh, Wv);
  k_mid<<<80, 256, 0, stream>>>(ws, bp);

  // decoder chain + fused, progress-gated vocab GEMM
  k_decvoc<<<useWvB ? 5976 : 96, 256, 0, stream>>>(ws, out, dbh, bc, bv);

  if (!useWvB)
    k_vocab0<<<2944, 512, 0, stream>>>(
        (const u16*)(ws + L::o_outsB), Wv, bv, out, (float*)(ws + L::o_rowsum));

  k_invrow<<<8, 256, 0, stream>>>((float*)(ws + L::o_rowsum));
  k_scale<<<92512, 256, 0, stream>>>(out, (const float*)(ws + L::o_rowsum));
}

// Round 10
// 2854.754 us; speedup vs baseline: 4.7750x; 1.0016x over previous
//
#include <hip/hip_runtime.h>

typedef unsigned int uint32;
typedef unsigned short u16;
typedef unsigned long long u64;
typedef __attribute__((ext_vector_type(8))) short bf8;   // 8 x bf16 (4 VGPRs)
typedef __attribute__((ext_vector_type(4))) float f4;    // 4 x f32
typedef __attribute__((ext_vector_type(4))) uint32 u32x4;

#define DEV static __device__ __forceinline__

DEV f4 MFMA(bf8 a, bf8 b, f4 c) {
  return __builtin_amdgcn_mfma_f32_16x16x32_bf16(a, b, c, 0, 0, 0);
}
DEV u16 f2bf(float f) {
  uint32 u = __float_as_uint(f);
  return (u16)((u + 0x7FFFu + ((u >> 16) & 1u)) >> 16);
}
DEV float bf2f(u16 h) { return __uint_as_float(((uint32)h) << 16); }
DEV float bfLO(uint32 u) { return __uint_as_float(u << 16); }
DEV float bfHI(uint32 u) { return __uint_as_float(u & 0xFFFF0000u); }
DEV float sigmoid_(float x) { return 1.f / (1.f + __expf(-x)); }
DEV float tanh_(float x) {
  float cx = fminf(fmaxf(x, -15.f), 15.f);
  float e = __expf(2.f * cx);
  return (e - 1.f) / (e + 1.f);
}

// ---- device-coherent (agent-scope, relaxed) data movement; compiler-tracked ----
DEV u64 ldA64(const void* p) {
  return __hip_atomic_load((u64*)p, __ATOMIC_RELAXED, __HIP_MEMORY_SCOPE_AGENT);
}
DEV void stA64(void* p, u64 v) {
  __hip_atomic_store((u64*)p, v, __ATOMIC_RELAXED, __HIP_MEMORY_SCOPE_AGENT);
}
DEV void stA32(int* p, int v) {
  __hip_atomic_store(p, v, __ATOMIC_RELAXED, __HIP_MEMORY_SCOPE_AGENT);
}
DEV bf8 pk_frag(u64 lo, u64 hi) {
  u32x4 v = {(uint32)lo, (uint32)(lo >> 32), (uint32)hi, (uint32)(hi >> 32)};
  return __builtin_bit_cast(bf8, v);
}

// ---- sync primitives ----
DEV void wait_vm0() { asm volatile("s_waitcnt vmcnt(0)" ::: "memory"); }
// slot-based barrier: producers WRITE slot[i]=tgt (no RMW); one wave polls all
// slots with a coalesced lane-load + ballot. Call from a full wave.
DEV void wait_slots(const int* slots, int n, int tgt) {
  const int lane = threadIdx.x & 63;
  for (int i = 0; i < (1 << 21); ++i) {
    int v = 0x7fffffff;
    if (lane < n)
      v = __hip_atomic_load((int*)(slots + lane), __ATOMIC_RELAXED,
                            __HIP_MEMORY_SCOPE_AGENT);
    if (__all(v >= tgt)) return;
    __builtin_amdgcn_s_sleep(1);
  }
}

namespace L {
// sizes: B=32,S=60,T=59,V=50000,E=300(pad320),H=512,3H=1536
constexpr size_t o_flags  = 0;          // 1024 int
constexpr size_t o_rowsum = 4096;       // 1920 f32
constexpr size_t o_bcomb  = 11776;      // 1536 f32
constexpr size_t o_gistat = 17920;      // 32x1536 f32
constexpr size_t o_xbuf   = 214528;     // 2x32x1024 bf16  (attn | h)
constexpr size_t o_henc   = 345600;     // 2x32x512 bf16
constexpr size_t o_haff   = 411136;     // 2x32x512 bf16
constexpr size_t o_cat    = 476672;     // 32x1024 bf16 (state_enc | state_aff)
constexpr size_t o_Kbuf   = 542208;     // 1920x512 bf16 (row = s*32+b)
constexpr size_t o_KA     = 2508288;    // 1920x512 bf16
constexpr size_t o_embP   = 4474368;    // 1920x320 bf16
constexpr size_t o_embA   = 5703168;    // 1920x320 bf16
constexpr size_t o_embD   = 6931968;    // 1888x320 bf16
constexpr size_t o_encWi  = 8140288;    // 1536x320 bf16
constexpr size_t o_affWi  = 9123328;    // 1536x320 bf16
constexpr size_t o_Whe    = 10106368;   // 1536x512 bf16
constexpr size_t o_Wha    = 11679232;   // 1536x512 bf16
constexpr size_t o_decWi  = 13252096;   // 1536x512 bf16
constexpr size_t o_WlT    = 14824960;   // 1328x512 bf16
constexpr size_t o_Wa     = 16184832;   // 512x512 bf16
constexpr size_t o_Wp     = 16709120;   // 512x1024 bf16
constexpr size_t o_wq     = 17757696;   // 32768 uint4 (packed Wc^T pairs)
constexpr size_t o_Wcomb  = 18281984;   // 1536x1328 f32
constexpr size_t o_WdE    = 26441216;   // 1536x320 bf16
constexpr size_t o_WdA    = 27424256;   // 1536x512 bf16
constexpr size_t o_Wd2    = 28997120;   // 1536x1024 bf16 (Wcomb_attn | dec_Wh)
constexpr size_t o_giE    = 32142848;   // 1920x1536 f32
constexpr size_t o_giA    = 43939328;   // 1920x1536 f32
constexpr size_t o_giD    = 55735808;   // 1888x1536 f32
constexpr size_t o_outsB  = 67335680;   // 1920x1024 bf16 (row = t*32+b : h|attn)
constexpr size_t o_WvB    = 71267840;   // 50176x1024 bf16 (optional)
constexpr size_t WS_FULL  = 174028288;
constexpr size_t WOFF = 94400000;       // weights output offset (floats)
// slots (ints): [0..31] dec A; [64..127] dec B; [128..159] enc g0; [192..223] enc g1
}

// ---------------- prep: embedding gathers -> bf16, padded K=320 ----------------
__global__ __launch_bounds__(256) void kp_gather(
    const int* __restrict__ posts, const int* __restrict__ resp,
    const float* __restrict__ emb, const float* __restrict__ aemb, char* ws)
{
  using namespace L;
  const int gid = blockIdx.x * 256 + threadIdx.x;
  const int r = gid / 320, e = gid - r * 320;
  u16* embP = (u16*)(ws + o_embP);
  u16* embA = (u16*)(ws + o_embA);
  u16* embD = (u16*)(ws + o_embD);
  if (r < 1920) {
    const int b = r & 31, s = r >> 5;
    const int tok = posts[b * 60 + s];
    embP[r * 320 + e] = f2bf(e < 300 ? emb[(size_t)tok * 300 + e] : 0.f);
    embA[r * 320 + e] = f2bf(e < 300 ? aemb[(size_t)tok * 300 + e] : 0.f);
  } else if (r < 3808) {
    const int r2 = r - 1920;
    const int b = r2 & 31, t = r2 >> 5;
    const int tok = resp[b * 60 + t];
    embD[r2 * 320 + e] = f2bf(e < 300 ? emb[(size_t)tok * 300 + e] : 0.f);
  }
}

// ---------------- prep: weight conversions / transposes / zeroing ----------------
__global__ __launch_bounds__(256) void kp_wconv(
    const float* __restrict__ encWi, const float* __restrict__ affWi,
    const float* __restrict__ encWh, const float* __restrict__ affWh,
    const float* __restrict__ dWi, const float* __restrict__ Wl,
    const float* __restrict__ Wa, const float* __restrict__ Wp,
    const float* __restrict__ Wc, char* ws)
{
  using namespace L;
  long gid = (long)blockIdx.x * 256 + threadIdx.x;
  if (gid < 983040) {  // enc_Wi / aff_Wi -> [1536][320] bf16 (pad)
    const int g = gid >= 491520;
    const long u = gid - (g ? 491520 : 0);
    const int n = (int)(u / 320), e = (int)(u - (long)n * 320);
    const float* src = g ? affWi : encWi;
    u16* dst = (u16*)(ws + (g ? o_affWi : o_encWi));
    dst[u] = f2bf(e < 300 ? src[(size_t)n * 300 + e] : 0.f);
    return;
  }
  gid -= 983040;
  if (gid < 2359296) {  // enc_Wh / aff_Wh / dec_Wi -> bf16 direct
    const int g = (int)(gid / 786432);
    const long u = gid - (long)g * 786432;
    const float* src = g == 0 ? encWh : (g == 1 ? affWh : dWi);
    u16* dst = (u16*)(ws + (g == 0 ? o_Whe : (g == 1 ? o_Wha : o_decWi)));
    dst[u] = f2bf(src[u]);
    return;
  }
  gid -= 2359296;
  if (gid < 679936) {  // Wl^T -> [1328][512] bf16 (pad rows)
    const int j = (int)(gid >> 9), k = (int)(gid & 511);
    ((u16*)(ws + o_WlT))[gid] = f2bf(j < 1324 ? Wl[(size_t)k * 1324 + j] : 0.f);
    return;
  }
  gid -= 679936;
  if (gid < 262144) { ((u16*)(ws + o_Wa))[gid] = f2bf(Wa[gid]); return; }
  gid -= 262144;
  if (gid < 524288) { ((u16*)(ws + o_Wp))[gid] = f2bf(Wp[gid]); return; }
  gid -= 524288;
  if (gid < 131072) {  // packed Wc^T pairs: u32 idx = (g4*512+j)*4+q ; d0 = g4*8+q*2
    const int q = (int)(gid & 3), j = (int)((gid >> 2) & 511), g4 = (int)(gid >> 11);
    const int d0 = g4 * 8 + q * 2;
    const uint32 lo = f2bf(Wc[(size_t)j * 512 + d0]);
    const uint32 hi = f2bf(Wc[(size_t)j * 512 + d0 + 1]);
    ((uint32*)(ws + o_wq))[gid] = lo | (hi << 16);
    return;
  }
  gid -= 131072;
  if (gid < 2944) {  // zero flags + rowsum
    if (gid < 1024) ((uint32*)(ws + o_flags))[gid] = 0;
    else ((uint32*)(ws + o_rowsum))[gid - 1024] = 0;
    return;
  }
  gid -= 2944;
  if (gid < 49152) {  // zero: outsB pad rows, henc, haff (u32 words)
    if (gid < 16384) ((uint32*)(ws + o_outsB + (size_t)1888 * 1024 * 2))[gid] = 0;
    else if (gid < 32768) ((uint32*)(ws + o_henc))[gid - 16384] = 0;
    else ((uint32*)(ws + o_haff))[gid - 32768] = 0;
  }
}

// ---------------- prep: bcomb = dec_Wi @ bl + dec_bi ----------------
__global__ __launch_bounds__(256) void kp_bcomb(
    const float* __restrict__ dWi, const float* __restrict__ bl,
    const float* __restrict__ dbi, char* ws)
{
  const int i = blockIdx.x * 256 + threadIdx.x;
  if (i >= 1536) return;
  float a = dbi[i];
  for (int k = 0; k < 512; ++k) a += dWi[(size_t)i * 512 + k] * bl[k];
  ((float*)(ws + L::o_bcomb))[i] = a;
}

// ---------------- prep: split Wcomb into bf16 pieces ----------------
__global__ __launch_bounds__(256) void kp_pack2(
    const float* __restrict__ Wcomb, const float* __restrict__ dWh, char* ws)
{
  using namespace L;
  long gid = (long)blockIdx.x * 256 + threadIdx.x;
  if (gid < 491520) {  // Wd_emb [1536][320] <- Wcomb[:,0:300]
    const int n = (int)(gid / 320), e = (int)(gid - (long)n * 320);
    ((u16*)(ws + o_WdE))[gid] = f2bf(e < 300 ? Wcomb[(size_t)n * 1328 + e] : 0.f);
    return;
  }
  gid -= 491520;
  if (gid < 786432) {  // Wd_aff [1536][512] <- Wcomb[:,300:812]
    const int n = (int)(gid >> 9), k = (int)(gid & 511);
    ((u16*)(ws + o_WdA))[gid] = f2bf(Wcomb[(size_t)n * 1328 + 300 + k]);
    return;
  }
  gid -= 786432;
  if (gid < 1572864) {  // Wd2 [1536][1024] = [Wcomb[:,812:1324] | dec_Wh]
    const int n = (int)(gid >> 10), k = (int)(gid & 1023);
    const float v = (k < 512) ? Wcomb[(size_t)n * 1328 + 812 + k]
                              : dWh[(size_t)n * 512 + (k - 512)];
    ((u16*)(ws + o_Wd2))[gid] = f2bf(v);
  }
}

// ---------------- generic MFMA GEMM: C[M][N] = A[M][Kp] * B[N][Kp]^T (+bias) ----------------
__global__ __launch_bounds__(256) void k_gemm_nt(
    const u16* __restrict__ A, const u16* __restrict__ Bm,
    float* __restrict__ C, const float* __restrict__ bias,
    const int M, const int N, const int Kp)
{
  const int mt = blockIdx.x, cb = blockIdx.y;
  const int w = threadIdx.x >> 6, lane = threadIdx.x & 63;
  const int l15 = lane & 15, lhi = lane >> 4;
  const u16* arow = A + (size_t)(mt * 16 + l15) * Kp + lhi * 8;
  const int c0 = cb * 256 + w * 64;
  f4 acc[4];
#pragma unroll
  for (int nn = 0; nn < 4; ++nn) acc[nn] = (f4){0.f, 0.f, 0.f, 0.f};
  for (int k = 0; k < Kp; k += 32) {
    const bf8 a = *(const bf8*)(arow + k);
#pragma unroll
    for (int nn = 0; nn < 4; ++nn) {
      const int cs = c0 + nn * 16;
      if (cs < N) {
        const bf8 b = *(const bf8*)(Bm + (size_t)(cs + l15) * Kp + k + lhi * 8);
        acc[nn] = MFMA(a, b, acc[nn]);
      }
    }
  }
#pragma unroll
  for (int nn = 0; nn < 4; ++nn) {
    const int cs = c0 + nn * 16;
    if (cs >= N) continue;
    const int c = cs + l15;
    const float bb = bias ? bias[c] : 0.f;
#pragma unroll
    for (int j = 0; j < 4; ++j) {
      const int r = mt * 16 + lhi * 4 + j;
      C[(size_t)r * N + c] = acc[nn][j] + bb;
    }
  }
}

// -------- encoder + fused bulk: blk<64 enc; blk<772 giD gemm; else Wv->bf16 ----
__global__ __launch_bounds__(256) void k_encplus(
    char* __restrict__ ws, const float* __restrict__ enc_bh,
    const float* __restrict__ aff_bh, const float* __restrict__ Wv)
{
  using namespace L;
  const int tid = threadIdx.x, blk = blockIdx.x;
  const int wave = tid >> 6, lane = tid & 63;
  const int l15 = lane & 15, lhi = lane >> 4;

  if (blk < 64) {
    // ===== encoder role (round-6 proven): 32 blocks per GRU, 2 active waves =====
    const int g = blk >> 5;
    const bool act = wave < 2;
    int* flags = (int*)(ws + o_flags);
    int* slotE = flags + 128 + g * 64;
    const u16* Wh = (const u16*)(ws + (g ? o_Wha : o_Whe));
    const float* gi = (const float*)(ws + (g ? o_giA : o_giE));
    const float* bh = g ? aff_bh : enc_bh;
    u16* hbuf = (u16*)(ws + (g ? o_haff : o_henc));
    u16* cat = (u16*)(ws + o_cat);
    u16* Kb = (u16*)(ws + o_Kbuf);

    const int wid = (blk & 31) * 2 + (wave & 1);     // 0..63 when act
    const int btile = wid >> 5, ctile = wid & 31;
    const int bl = btile * 16 + l15;
    const int c0 = ctile * 16 + lhi * 4;
    const u16* wr0 = Wh + (size_t)(ctile * 16 + l15) * 512 + lhi * 8;
    const u16* wr1 = wr0 + (size_t)512 * 512;
    const u16* wr2 = wr1 + (size_t)512 * 512;
    f4 bhr4 = {0.f, 0.f, 0.f, 0.f}, bhz4 = bhr4, bhn4 = bhr4;
    if (act) {
      bhr4 = *(const f4*)(bh + c0);
      bhz4 = *(const f4*)(bh + 512 + c0);
      bhn4 = *(const f4*)(bh + 1024 + c0);
    }
    for (int s = 0; s < 60; ++s) {
      const u16* hin = hbuf + (s & 1) * (32 * 512);
      u16* hout = hbuf + ((s & 1) ^ 1) * (32 * 512);
      if (act) {
        const u16* brow = hin + bl * 512 + lhi * 8;
        u64 flo[16], fhi[16];
#pragma unroll
        for (int kk = 0; kk < 16; ++kk) {      // batched: one exposed latency
          flo[kk] = ldA64(brow + kk * 32);
          fhi[kk] = ldA64(brow + kk * 32 + 4);
        }
        const u64 hq = ldA64(hin + bl * 512 + c0);
        f4 ar = {0.f, 0.f, 0.f, 0.f}, az = ar, an = ar;
#pragma unroll
        for (int kk = 0; kk < 16; ++kk) {
          const bf8 hf = pk_frag(flo[kk], fhi[kk]);
          ar = MFMA(*(const bf8*)(wr0 + kk * 32), hf, ar);
          az = MFMA(*(const bf8*)(wr1 + kk * 32), hf, az);
          an = MFMA(*(const bf8*)(wr2 + kk * 32), hf, an);
        }
        const float* gr = gi + (size_t)(s * 32 + bl) * 1536;
        const f4 g0 = *(const f4*)(gr + c0);
        const f4 g1 = *(const f4*)(gr + 512 + c0);
        const f4 g2 = *(const f4*)(gr + 1024 + c0);
        u64 pk = 0;
#pragma unroll
        for (int j = 0; j < 4; ++j) {
          const float r = sigmoid_(g0[j] + ar[j] + bhr4[j]);
          const float z = sigmoid_(g1[j] + az[j] + bhz4[j]);
          const float n = tanh_(g2[j] + r * (an[j] + bhn4[j]));
          const float hold = bf2f((u16)(hq >> (16 * j)));
          pk |= (u64)f2bf((1.f - z) * n + z * hold) << (16 * j);
        }
        stA64(hout + bl * 512 + c0, pk);
        if (g) *(u64*)(Kb + (size_t)(s * 32 + bl) * 512 + c0) = pk;  // next kernel
        if (s == 59) *(u64*)(cat + bl * 1024 + g * 512 + c0) = pk;   // next kernel
      }
      wait_vm0();
      __syncthreads();
      if (tid == 0) stA32(&slotE[blk & 31], s + 1);   // slot write, no RMW
      if (wave == 2) wait_slots(slotE, 32, s + 1);    // idle wave polls
      __syncthreads();
    }
  } else if (blk < 772) {
    // ===== giD = embD @ WdE^T  (fused; consumed by next-next kernel) =====
    const int bb = blk - 64;
    const int mt = bb % 118, cb = bb / 118;
    const u16* A = (const u16*)(ws + o_embD);
    const u16* Bm = (const u16*)(ws + o_WdE);
    float* C = (float*)(ws + o_giD);
    const int Kp = 320, N = 1536;
    const int w = wave;
    const u16* arow = A + (size_t)(mt * 16 + l15) * Kp + lhi * 8;
    const int c0 = cb * 256 + w * 64;
    f4 acc[4];
#pragma unroll
    for (int nn = 0; nn < 4; ++nn) acc[nn] = (f4){0.f, 0.f, 0.f, 0.f};
    for (int k = 0; k < Kp; k += 32) {
      const bf8 a = *(const bf8*)(arow + k);
#pragma unroll
      for (int nn = 0; nn < 4; ++nn) {
        const bf8 b = *(const bf8*)(Bm + (size_t)(c0 + nn * 16 + l15) * Kp + k + lhi * 8);
        acc[nn] = MFMA(a, b, acc[nn]);
      }
    }
#pragma unroll
    for (int nn = 0; nn < 4; ++nn) {
      const int c = c0 + nn * 16 + l15;
#pragma unroll
      for (int j = 0; j < 4; ++j)
        C[(size_t)(mt * 16 + lhi * 4 + j) * N + c] = acc[nn][j];
    }
  } else {
    // ===== Wv -> bf16 (padded rows) fused =====
    const long gid = (long)(blk - 772) * 256 + tid;
    const int r = (int)(gid >> 8), q = (int)(gid & 255);
    u16* WvB = (u16*)(ws + o_WvB);
    uint2 o;
    if (r < 50000) {
      const float4 f = *(const float4*)(Wv + (size_t)r * 1024 + q * 4);
      o.x = (uint32)f2bf(f.x) | ((uint32)f2bf(f.y) << 16);
      o.y = (uint32)f2bf(f.z) | ((uint32)f2bf(f.w) << 16);
    } else { o.x = 0u; o.y = 0u; }
    if (r < 50176) *(uint2*)(WvB + (size_t)r * 1024 + q * 4) = o;
  }
}

// ---------------- mid kernel: state0 | gi_static | KA (no sync needed) ----------
__global__ __launch_bounds__(256) void k_mid(char* __restrict__ ws,
                                             const float* __restrict__ bp)
{
  using namespace L;
  const int tid = threadIdx.x, blk = blockIdx.x;
  const int wave = tid >> 6, lane = tid & 63;
  const int l15 = lane & 15, lhi = lane >> 4;
  u16* xb = (u16*)(ws + o_xbuf);
  u16* cat = (u16*)(ws + o_cat);
  u16* Kb = (u16*)(ws + o_Kbuf);

  if (blk < 16) {  // state0 = tanh(cat @ Wp^T + bp) -> xbuf[0]; zero attn half
    const u16* Wp_ = (const u16*)(ws + o_Wp);
    const int wid = blk * 4 + wave;
    const int btile = wid >> 5, ctile = wid & 31;
    const int bl = btile * 16 + l15;
    const int c0 = ctile * 16 + lhi * 4;
    const u16* arow = Wp_ + (size_t)(ctile * 16 + l15) * 1024 + lhi * 8;
    const u16* brow = cat + bl * 1024 + lhi * 8;
    f4 acc = {0.f, 0.f, 0.f, 0.f};
    for (int k = 0; k < 1024; k += 32)
      acc = MFMA(*(const bf8*)(arow + k), *(const bf8*)(brow + k), acc);
    const f4 bp4 = *(const f4*)(bp + c0);
    u64 pk = 0;
#pragma unroll
    for (int j = 0; j < 4; ++j)
      pk |= (u64)f2bf(tanh_(acc[j] + bp4[j])) << (16 * j);
    *(u64*)(xb + bl * 1024 + 512 + c0) = pk;
    *(u64*)(xb + bl * 1024 + c0) = 0;          // init attn = 0
  } else if (blk < 32) {  // gi_static = ctx_aff @ Wd_aff^T + bcomb
    const u16* WdA = (const u16*)(ws + o_WdA);
    const float* bco = (const float*)(ws + o_bcomb);
    float* gst = (float*)(ws + o_gistat);
    const int wid = (blk - 16) * 4 + wave;
    const int btile = wid >> 5, ctb = wid & 31;
    const int bl = btile * 16 + l15;
    const int c0 = ctb * 16 + lhi * 4;
    const u16* brow = cat + bl * 1024 + 512 + lhi * 8;
    const u16* a0p = WdA + (size_t)(ctb * 16 + l15) * 512 + lhi * 8;
    const u16* a1p = a0p + (size_t)512 * 512;
    const u16* a2p = a1p + (size_t)512 * 512;
    f4 a0 = {0.f, 0.f, 0.f, 0.f}, a1 = a0, a2 = a0;
    for (int k = 0; k < 512; k += 32) {
      const bf8 bfr = *(const bf8*)(brow + k);
      a0 = MFMA(*(const bf8*)(a0p + k), bfr, a0);
      a1 = MFMA(*(const bf8*)(a1p + k), bfr, a1);
      a2 = MFMA(*(const bf8*)(a2p + k), bfr, a2);
    }
    const f4 v0 = *(const f4*)(bco + c0);
    const f4 v1 = *(const f4*)(bco + 512 + c0);
    const f4 v2 = *(const f4*)(bco + 1024 + c0);
    *(f4*)(gst + bl * 1536 + c0) = a0 + v0;
    *(f4*)(gst + bl * 1536 + 512 + c0) = a1 + v1;
    *(f4*)(gst + bl * 1536 + 1024 + c0) = a2 + v2;
  } else {  // KA = K @ Wa^T
    const u16* Wa_ = (const u16*)(ws + o_Wa);
    u16* KAp = (u16*)(ws + o_KA);
    const int widK = (blk - 32) * 4 + wave;
    for (int task = widK; task < 3840; task += 192) {
      const int mt = task >> 5, ct = task & 31;
      const int m = mt * 16 + l15;
      const int c0 = ct * 16 + lhi * 4;
      const u16* arow = Wa_ + (size_t)(ct * 16 + l15) * 512 + lhi * 8;
      const u16* brow = Kb + (size_t)m * 512 + lhi * 8;
      f4 acc = {0.f, 0.f, 0.f, 0.f};
      for (int k = 0; k < 512; k += 32)
        acc = MFMA(*(const bf8*)(arow + k), *(const bf8*)(brow + k), acc);
      u64 pk = 0;
#pragma unroll
      for (int j = 0; j < 4; ++j) pk |= (u64)f2bf(acc[j]) << (16 * j);
      *(u64*)(KAp + (size_t)m * 512 + c0) = pk;
    }
  }
}

// ----- fused decoder + vocab GEMM: blk<96 dec (round-6 proven); else vocab ----
// outs rows are t-major (row = t*32+b), written agent-scope so vocab tiles can
// consume them in-flight, gated on slotB progress + one acquire fence.
// Vocab ordering: XCD swizzle + ntile-major (15 same-ntile mtile-blocks land on
// one XCD -> B tile L2/L3-resident, read ~once). Output stored non-temporal so
// the 377MB write stream doesn't evict B from L3.
__global__ __launch_bounds__(256, 1) void k_decvoc(
    char* __restrict__ ws, float* __restrict__ out,
    const float* __restrict__ dec_bh, const float* __restrict__ bc,
    const float* __restrict__ bv)
{
  using namespace L;
  const int tid = threadIdx.x, blk = blockIdx.x;
  const int wave = tid >> 6, lane = tid & 63;
  const int l15 = lane & 15, lhi = lane >> 4;
  int* flags = (int*)(ws + o_flags);
  int* slotA = flags;        // 32
  int* slotB = flags + 64;   // 64

  __shared__ float hsm[512];
  __shared__ float ctxs[512];
  __shared__ float scb[64];
  __shared__ float wsb[64];
  __shared__ u16 attn_sm[256];
  __shared__ u16 vAs[2][128][40];
  __shared__ u16 vBs[2][128][40];

  u16* xb = (u16*)(ws + o_xbuf);
  u16* outs = (u16*)(ws + o_outsB);

  if (blk < 32) {
    // A-role: h_t = GRU from [attn_{t-1} ; h_{t-1}] via Wd2 (K=1024), n-gate split.
    const bool act = wave < 2;
    const u16* Wd2 = (const u16*)(ws + o_Wd2);
    const float* gst = (const float*)(ws + o_gistat);
    const float* gD = (const float*)(ws + o_giD);
    const int wid = (blk & 31) * 2 + (wave & 1);
    const int btile = wid >> 5, ctile = wid & 31;
    const int bl = btile * 16 + l15;
    const int c0 = ctile * 16 + lhi * 4;
    const u16* wr = Wd2 + (size_t)(ctile * 16 + l15) * 1024 + lhi * 8;
    const u16* wz = wr + (size_t)512 * 1024;
    const u16* wn = wz + (size_t)512 * 1024;
    f4 bhr4 = {0.f, 0.f, 0.f, 0.f}, bhz4 = bhr4, bhn4 = bhr4;
    f4 s0 = bhr4, s1 = bhr4, s2 = bhr4;
    if (act) {
      bhr4 = *(const f4*)(dec_bh + c0);
      bhz4 = *(const f4*)(dec_bh + 512 + c0);
      bhn4 = *(const f4*)(dec_bh + 1024 + c0);
      s0 = *(const f4*)(gst + bl * 1536 + c0);
      s1 = *(const f4*)(gst + bl * 1536 + 512 + c0);
      s2 = *(const f4*)(gst + bl * 1536 + 1024 + c0);
    }
    for (int t = 0; t < 59; ++t) {
      const u16* xin = xb + (t & 1) * (32 * 1024);
      u16* xout = xb + ((t & 1) ^ 1) * (32 * 1024);
      const u16* brow = xin + bl * 1024 + lhi * 8;
      f4 ar = {0.f, 0.f, 0.f, 0.f}, az = ar, anx = ar, anh = ar;
      u64 hq = 0;
      f4 d0 = ar, d1 = ar, d2 = ar;
      // ---- stage 1: needs h(t-1) = all A slots >= t ----
      if (t) {
        if (wave == 2) wait_slots(slotA, 32, t);
        __syncthreads();
      }
      if (act) {
        u64 flo[16], fhi[16];
#pragma unroll
        for (int kk = 0; kk < 16; ++kk) {
          flo[kk] = ldA64(brow + (16 + kk) * 32);
          fhi[kk] = ldA64(brow + (16 + kk) * 32 + 4);
        }
        hq = ldA64(xin + bl * 1024 + 512 + c0);
        const float* g2p = gD + (size_t)(t * 32 + bl) * 1536;   // static prefetch
        d0 = *(const f4*)(g2p + c0);
        d1 = *(const f4*)(g2p + 512 + c0);
        d2 = *(const f4*)(g2p + 1024 + c0);
#pragma unroll
        for (int kk = 0; kk < 16; ++kk) {
          const bf8 xf = pk_frag(flo[kk], fhi[kk]);
          ar = MFMA(*(const bf8*)(wr + (16 + kk) * 32), xf, ar);
          az = MFMA(*(const bf8*)(wz + (16 + kk) * 32), xf, az);
          anh = MFMA(*(const bf8*)(wn + (16 + kk) * 32), xf, anh);
        }
      }
      // ---- stage 2: needs attn(t-1) = all B slots >= t ----
      if (t) {
        if (wave == 2) wait_slots(slotB, 64, t);
        __syncthreads();
      }
      if (act) {
        u64 glo[16], ghi[16];
#pragma unroll
        for (int kk = 0; kk < 16; ++kk) {
          glo[kk] = ldA64(brow + kk * 32);
          ghi[kk] = ldA64(brow + kk * 32 + 4);
        }
#pragma unroll
        for (int kk = 0; kk < 16; ++kk) {
          const bf8 xf = pk_frag(glo[kk], ghi[kk]);
          ar = MFMA(*(const bf8*)(wr + kk * 32), xf, ar);
          az = MFMA(*(const bf8*)(wz + kk * 32), xf, az);
          anx = MFMA(*(const bf8*)(wn + kk * 32), xf, anx);
        }
        u64 pk = 0;
#pragma unroll
        for (int j = 0; j < 4; ++j) {
          const float r = sigmoid_(s0[j] + d0[j] + ar[j] + bhr4[j]);
          const float z = sigmoid_(s1[j] + d1[j] + az[j] + bhz4[j]);
          const float n = tanh_(s2[j] + d2[j] + anx[j] + r * (anh[j] + bhn4[j]));
          const float hold = bf2f((u16)(hq >> (16 * j)));
          pk |= (u64)f2bf((1.f - z) * n + z * hold) << (16 * j);
        }
        stA64(xout + bl * 1024 + 512 + c0, pk);
        stA64(outs + (size_t)(t * 32 + bl) * 1024 + c0, pk);  // t-major, visible
      }
      wait_vm0();
      __syncthreads();
      if (tid == 0) stA32(&slotA[blk], t + 1);   // slot write, no RMW
    }
  } else if (blk < 96) {
    // B-role: 2 blocks per batch element: scores -> softmax -> ctx -> attn
    const int idx = blk - 32;
    const int b = idx >> 1, half = idx & 1;
    const u16* KAp = (const u16*)(ws + o_KA);
    const u16* Kb = (const u16*)(ws + o_Kbuf);
    const uint4* wq = (const uint4*)(ws + o_wq);
    for (int t = 0; t < 59; ++t) {
      if (wave == 0) wait_slots(slotA, 32, t + 1);
      __syncthreads();
      const u16* xcur = xb + ((t & 1) ^ 1) * (32 * 1024);
      if (tid < 128) {  // coherent-load h (written by A this step)
        const u64 hv = ldA64(xcur + b * 1024 + 512 + tid * 4);
        const uint32 w0 = (uint32)hv, w1 = (uint32)(hv >> 32);
        hsm[tid * 4 + 0] = bfLO(w0);
        hsm[tid * 4 + 1] = bfHI(w0);
        hsm[tid * 4 + 2] = bfLO(w1);
        hsm[tid * 4 + 3] = bfHI(w1);
      }
      __syncthreads();
      if (tid < 240) {  // scores[s] = h . KA[s,b,:]   (2 accumulator chains)
        const int s = tid >> 2, q = tid & 3;
        const u16* kr = KAp + (size_t)(s * 32 + b) * 512 + q * 128;
        const float* hq = &hsm[q * 128];
        float acc0 = 0.f, acc1 = 0.f;
#pragma unroll 4
        for (int i = 0; i < 128; i += 8) {
          const uint2 k4 = *(const uint2*)(kr + i);
          const uint2 k5 = *(const uint2*)(kr + i + 4);
          const float4 h4 = *(const float4*)(hq + i);
          const float4 h5 = *(const float4*)(hq + i + 4);
          acc0 += h4.x * bfLO(k4.x) + h4.y * bfHI(k4.x)
                + h4.z * bfLO(k4.y) + h4.w * bfHI(k4.y);
          acc1 += h5.x * bfLO(k5.x) + h5.y * bfHI(k5.x)
                + h5.z * bfLO(k5.y) + h5.w * bfHI(k5.y);
        }
        float acc = acc0 + acc1;
        acc += __shfl_xor(acc, 1);
        acc += __shfl_xor(acc, 2);
        if ((tid & 3) == 0) scb[s] = acc;
      }
      __syncthreads();
      if (tid < 64) {  // softmax over 60
        const float v = (tid < 60) ? scb[tid] : -1e30f;
        float m = v;
#pragma unroll
        for (int d = 1; d < 64; d <<= 1) m = fmaxf(m, __shfl_xor(m, d));
        const float e = (tid < 60) ? __expf(v - m) : 0.f;
        float sm = e;
#pragma unroll
        for (int d = 1; d < 64; d <<= 1) sm += __shfl_xor(sm, d);
        const float w = e / sm;
        if (tid < 60) {
          wsb[tid] = w;
          if (half == 0) out[WOFF + (size_t)(b * 59 + t) * 60 + tid] = w;
        }
      }
      __syncthreads();
      {  // ctx = sum_s w[s] * K[s,b,:]  (4 accumulator chains)
        float c0a = 0.f, c0b = 0.f, c1a = 0.f, c1b = 0.f;
#pragma unroll 2
        for (int s = 0; s < 60; s += 2) {
          const float w0 = wsb[s], w1 = wsb[s + 1];
          const u16* kr0 = Kb + (size_t)(s * 32 + b) * 512;
          const u16* kr1 = Kb + (size_t)((s + 1) * 32 + b) * 512;
          c0a += w0 * bf2f(kr0[tid]);
          c1a += w0 * bf2f(kr0[tid + 256]);
          c0b += w1 * bf2f(kr1[tid]);
          c1b += w1 * bf2f(kr1[tid + 256]);
        }
        ctxs[tid] = c0a + c0b;
        ctxs[tid + 256] = c1a + c1b;
      }
      __syncthreads();
      const int jj = half * 256 + tid;  // attn[jj] = tanh(bc + ctx . Wc[jj,:])
      float faa[4] = {0.f, 0.f, 0.f, 0.f};
      float fbb[4] = {0.f, 0.f, 0.f, 0.f};
#pragma unroll 4
      for (int g4 = 0; g4 < 64; ++g4) {
        const uint4 wv4 = wq[g4 * 512 + jj];
        const float4 ca = *(const float4*)&ctxs[g4 * 8];
        const float4 cb2 = *(const float4*)&ctxs[g4 * 8 + 4];
        faa[g4 & 3] += ca.x * bfLO(wv4.x) + ca.y * bfHI(wv4.x)
                     + ca.z * bfLO(wv4.y) + ca.w * bfHI(wv4.y);
        fbb[g4 & 3] += cb2.x * bfLO(wv4.z) + cb2.y * bfHI(wv4.z)
                     + cb2.z * bfLO(wv4.w) + cb2.w * bfHI(wv4.w);
      }
      const float fa = bc[jj] + faa[0] + faa[1] + faa[2] + faa[3]
                     + fbb[0] + fbb[1] + fbb[2] + fbb[3];
      attn_sm[tid] = f2bf(tanh_(fa));
      __syncthreads();
      if (tid < 64) {  // pack 4 attn values -> coherent u64 store
        u16* xout = xb + ((t & 1) ^ 1) * (32 * 1024);
        const u64 pk = (u64)attn_sm[tid * 4] | ((u64)attn_sm[tid * 4 + 1] << 16)
                     | ((u64)attn_sm[tid * 4 + 2] << 32) | ((u64)attn_sm[tid * 4 + 3] << 48);
        const int cc = half * 256 + tid * 4;
        stA64(xout + b * 1024 + cc, pk);
        stA64(outs + (size_t)(t * 32 + b) * 1024 + 512 + cc, pk);  // t-major
      }
      wait_vm0();
      __syncthreads();
      if (tid == 0) stA32(&slotB[idx], t + 1);   // slot write, no RMW
    }
  } else {
    // ===== vocab role: 128x128 tile; XCD swizzle + ntile-major for B reuse =====
    const int vb = blk - 96;                 // 0..5879 ; 5880 = 8*735
    const int xcd = vb & 7, sub = vb >> 3;
    const int wgid = xcd * 735 + sub;        // bijective
    const int mtile = wgid % 15, ntile = wgid / 15;  // 15 same-ntile blocks adjacent
    const int rbase = mtile * 128, cbase = ntile * 128;
    const int tgt = (4 * mtile + 4 < 59) ? (4 * mtile + 4) : 59;
    if (wave == 0) {
      wait_slots(slotB, 64, tgt);
      __builtin_amdgcn_fence(__ATOMIC_ACQUIRE, "agent");  // invalidate stale L1/L2
    }
    __syncthreads();

    const u16* A = outs;                     // t-major rows
    const u16* Bm = (const u16*)(ws + o_WvB);
    float* rowsum = (float*)(ws + o_rowsum);
    const int m0 = (wave >> 1) * 64, n0 = (wave & 1) * 64;
    const int sr0 = tid >> 2, sk = (tid & 3) * 8;  // + row 64 offset for 2nd load

    f4 acc[4][4];
#pragma unroll
    for (int mi = 0; mi < 4; ++mi)
#pragma unroll
      for (int ni = 0; ni < 4; ++ni) acc[mi][ni] = (f4){0.f, 0.f, 0.f, 0.f};

    const u16* gA0 = A + (size_t)(rbase + sr0) * 1024 + sk;
    const u16* gA1 = A + (size_t)(rbase + 64 + sr0) * 1024 + sk;
    const u16* gB0 = Bm + (size_t)(cbase + sr0) * 1024 + sk;
    const u16* gB1 = Bm + (size_t)(cbase + 64 + sr0) * 1024 + sk;

    uint4 a0 = *(const uint4*)(gA0), a1 = *(const uint4*)(gA1);
    uint4 b0 = *(const uint4*)(gB0), b1 = *(const uint4*)(gB1);
    *(uint4*)&vAs[0][sr0][sk] = a0;
    *(uint4*)&vAs[0][64 + sr0][sk] = a1;
    *(uint4*)&vBs[0][sr0][sk] = b0;
    *(uint4*)&vBs[0][64 + sr0][sk] = b1;
    __syncthreads();

    int cur = 0;
#pragma unroll 1
    for (int kt = 0; kt < 32; ++kt) {
      if (kt < 31) {
        const int k0 = (kt + 1) * 32;
        a0 = *(const uint4*)(gA0 + k0);
        a1 = *(const uint4*)(gA1 + k0);
        b0 = *(const uint4*)(gB0 + k0);
        b1 = *(const uint4*)(gB1 + k0);
      }
      bf8 af[4], bfr[4];
#pragma unroll
      for (int mi = 0; mi < 4; ++mi)
        af[mi] = *(const bf8*)&vAs[cur][m0 + mi * 16 + l15][lhi * 8];
#pragma unroll
      for (int ni = 0; ni < 4; ++ni)
        bfr[ni] = *(const bf8*)&vBs[cur][n0 + ni * 16 + l15][lhi * 8];
#pragma unroll
      for (int mi = 0; mi < 4; ++mi)
#pragma unroll
        for (int ni = 0; ni < 4; ++ni)
          acc[mi][ni] = MFMA(af[mi], bfr[ni], acc[mi][ni]);
      if (kt < 31) {
        __syncthreads();
        *(uint4*)&vAs[cur ^ 1][sr0][sk] = a0;
        *(uint4*)&vAs[cur ^ 1][64 + sr0][sk] = a1;
        *(uint4*)&vBs[cur ^ 1][sr0][sk] = b0;
        *(uint4*)&vBs[cur ^ 1][64 + sr0][sk] = b1;
        __syncthreads();
        cur ^= 1;
      }
    }

    // epilogue: exp + NT-store (row mapped t-major -> b*59+t) + rowsum atomics
#pragma unroll
    for (int mi = 0; mi < 4; ++mi) {
      float rs[4] = {0.f, 0.f, 0.f, 0.f};
      int ro_[4]; bool rv[4];
#pragma unroll
      for (int j = 0; j < 4; ++j) {
        const int r = rbase + m0 + mi * 16 + lhi * 4 + j;
        const int tt = r >> 5, bb2 = r & 31;
        rv[j] = tt < 59;
        ro_[j] = bb2 * 59 + tt;
      }
#pragma unroll
      for (int ni = 0; ni < 4; ++ni) {
        const int c = cbase + n0 + ni * 16 + l15;
        if (c < 50000) {
          const float bb = bv[c];
#pragma unroll
          for (int j = 0; j < 4; ++j) {
            if (rv[j]) {
              const float e = __expf(acc[mi][ni][j] + bb);
              __builtin_nontemporal_store(e, &out[(size_t)ro_[j] * 50000 + c]);
              rs[j] += e;
            }
          }
        }
      }
#pragma unroll
      for (int j = 0; j < 4; ++j) {
#pragma unroll
        for (int d = 1; d < 16; d <<= 1) rs[j] += __shfl_xor(rs[j], d);
      }
      if (l15 == 0) {
#pragma unroll
        for (int j = 0; j < 4; ++j)
          if (rv[j]) atomicAdd(&rowsum[ro_[j]], rs[j]);
      }
    }
  }
}

// ---------------- vocab GEMM fallback (no bf16 Wv copy; t-major outs) ---------
__global__ __launch_bounds__(512) void k_vocab0(
    const u16* __restrict__ A, const float* __restrict__ WvF,
    const float* __restrict__ bv, float* __restrict__ out,
    float* __restrict__ rowsum)
{
  const int bid = blockIdx.x;
  const int x = bid & 7, jj = bid >> 3;
  const int mtile = jj % 15, nseq = jj / 15;
  const int ntile = nseq * 8 + x;
  if (ntile >= 196) return;
  const int w = threadIdx.x >> 6, lane = threadIdx.x & 63;
  const int l15 = lane & 15, lhi = lane >> 4;
  const int rbase = mtile * 128 + w * 16;
  const u16* arow = A + (size_t)(rbase + l15) * 1024 + lhi * 8;
  const int cbase = ntile * 256;
  f4 acc[16];
#pragma unroll
  for (int nn = 0; nn < 16; ++nn) acc[nn] = (f4){0.f, 0.f, 0.f, 0.f};
  for (int k = 0; k < 1024; k += 32) {
    const bf8 a = *(const bf8*)(arow + k);
#pragma unroll
    for (int nn = 0; nn < 16; ++nn) {
      const int cs = cbase + nn * 16;
      bf8 bfr = {0, 0, 0, 0, 0, 0, 0, 0};
      if (cs < 50000) {
        const float* p = WvF + (size_t)(cs + l15) * 1024 + k + lhi * 8;
        const float4 f0 = *(const float4*)p;
        const float4 f1 = *(const float4*)(p + 4);
        bfr[0] = (short)(__float_as_uint(f0.x) >> 16);
        bfr[1] = (short)(__float_as_uint(f0.y) >> 16);
        bfr[2] = (short)(__float_as_uint(f0.z) >> 16);
        bfr[3] = (short)(__float_as_uint(f0.w) >> 16);
        bfr[4] = (short)(__float_as_uint(f1.x) >> 16);
        bfr[5] = (short)(__float_as_uint(f1.y) >> 16);
        bfr[6] = (short)(__float_as_uint(f1.z) >> 16);
        bfr[7] = (short)(__float_as_uint(f1.w) >> 16);
      }
      acc[nn] = MFMA(a, bfr, acc[nn]);
    }
  }
#pragma unroll
  for (int j = 0; j < 4; ++j) {
    const int r = rbase + lhi * 4 + j;
    const int tt = r >> 5, bb2 = r & 31;
    if (tt >= 59) continue;
    const int ro = bb2 * 59 + tt;
    float rsv = 0.f;
#pragma unroll
    for (int nn = 0; nn < 16; ++nn) {
      const int cs = cbase + nn * 16;
      if (cs >= 50000) continue;
      const int c = cs + l15;
      const float e = __expf(acc[nn][j] + bv[c]);
      out[(size_t)ro * 50000 + c] = e;
      rsv += e;
    }
#pragma unroll
    for (int d = 1; d < 16; d <<= 1) rsv += __shfl_xor(rsv, d);
    if (l15 == 0) atomicAdd(&rowsum[ro], rsv);
  }
}

// ---------------- rowsum -> 1/rowsum ----------------
__global__ void k_invrow(float* rs)
{
  const int i = blockIdx.x * 256 + threadIdx.x;
  if (i < 1920) {
    const float s = rs[i];
    rs[i] = (s > 0.f) ? 1.f / s : 0.f;
  }
}

// ---------------- scale exp values by 1/rowsum ----------------
__global__ __launch_bounds__(256) void k_scale(float* __restrict__ out,
                                               const float* __restrict__ inv)
{
  const int bid = blockIdx.x;
  const int r = bid / 49, ch = bid - r * 49;
  const int c = ch * 1024 + threadIdx.x * 4;
  if (c < 50000) {
    const float s = inv[r];
    float4* p = (float4*)(out + (size_t)r * 50000 + c);
    float4 v = *p;
    v.x *= s; v.y *= s; v.z *= s; v.w *= s;
    *p = v;
  }
}

extern "C" void kernel_launch(void* const* d_in, const int* in_sizes, int n_in,
                              void* d_out, int out_size, void* d_ws, size_t ws_size,
                              hipStream_t stream) {
  const int* posts = (const int*)d_in[0];
  const int* resp = (const int*)d_in[1];
  const float* emb = (const float*)d_in[3];
  const float* aemb = (const float*)d_in[4];
  const float* encWi = (const float*)d_in[5];
  const float* encWh = (const float*)d_in[6];
  const float* enc_bi = (const float*)d_in[7];
  const float* enc_bh = (const float*)d_in[8];
  const float* affWi = (const float*)d_in[9];
  const float* affWh = (const float*)d_in[10];
  const float* aff_bi = (const float*)d_in[11];
  const float* aff_bh = (const float*)d_in[12];
  const float* Wp = (const float*)d_in[13];
  const float* bp = (const float*)d_in[14];
  const float* Wl = (const float*)d_in[15];
  const float* bl = (const float*)d_in[16];
  const float* dWi = (const float*)d_in[17];
  const float* dWh = (const float*)d_in[18];
  const float* dbi = (const float*)d_in[19];
  const float* dbh = (const float*)d_in[20];
  const float* Wa = (const float*)d_in[21];
  const float* Wc = (const float*)d_in[22];
  const float* bc = (const float*)d_in[23];
  const float* Wv = (const float*)d_in[24];
  const float* bv = (const float*)d_in[25];
  char* ws = (char*)d_ws;
  float* out = (float*)d_out;
  const bool useWvB = ws_size >= L::WS_FULL;

  kp_gather<<<4760, 256, 0, stream>>>(posts, resp, emb, aemb, ws);
  kp_wconv<<<19500, 256, 0, stream>>>(encWi, affWi, encWh, affWh, dWi, Wl, Wa, Wp, Wc, ws);
  kp_bcomb<<<6, 256, 0, stream>>>(dWi, bl, dbi, ws);

  // Wcomb = dec_Wi @ Wl  -> f32 [1536][1328]
  k_gemm_nt<<<dim3(96, 6), 256, 0, stream>>>(
      (const u16*)(ws + L::o_decWi), (const u16*)(ws + L::o_WlT),
      (float*)(ws + L::o_Wcomb), nullptr, 1536, 1328, 512);
  kp_pack2<<<11136, 256, 0, stream>>>((const float*)(ws + L::o_Wcomb), dWh, ws);

  // input-gate precomputes (giD is fused into k_encplus)
  k_gemm_nt<<<dim3(120, 6), 256, 0, stream>>>(
      (const u16*)(ws + L::o_embP), (const u16*)(ws + L::o_encWi),
      (float*)(ws + L::o_giE), enc_bi, 1920, 1536, 320);
  k_gemm_nt<<<dim3(120, 6), 256, 0, stream>>>(
      (const u16*)(ws + L::o_embA), (const u16*)(ws + L::o_affWi),
      (float*)(ws + L::o_giA), aff_bi, 1920, 1536, 320);

  // encoder chain + fused bulk (giD gemm + Wv->bf16 conversion)
  k_encplus<<<useWvB ? 50948 : 772, 256, 0, stream>>>(ws, enc_bh, aff_bh, Wv);
  k_mid<<<80, 256, 0, stream>>>(ws, bp);

  // decoder chain + fused, progress-gated vocab GEMM
  k_decvoc<<<useWvB ? 5976 : 96, 256, 0, stream>>>(ws, out, dbh, bc, bv);

  if (!useWvB)
    k_vocab0<<<2944, 512, 0, stream>>>(
        (const u16*)(ws + L::o_outsB), Wv, bv, out, (float*)(ws + L::o_rowsum));

  k_invrow<<<8, 256, 0, stream>>>((float*)(ws + L::o_rowsum));
  k_scale<<<92512, 256, 0, stream>>>(out, (const float*)(ws + L::o_rowsum));
}

// Round 11
// 2819.925 us; speedup vs baseline: 4.8340x; 1.0124x over previous
//
#include <hip/hip_runtime.h>

typedef unsigned int uint32;
typedef unsigned short u16;
typedef unsigned long long u64;
typedef __attribute__((ext_vector_type(8))) short bf8;   // 8 x bf16 (4 VGPRs)
typedef __attribute__((ext_vector_type(4))) float f4;    // 4 x f32
typedef __attribute__((ext_vector_type(4))) uint32 u32x4;

#define DEV static __device__ __forceinline__

DEV f4 MFMA(bf8 a, bf8 b, f4 c) {
  return __builtin_amdgcn_mfma_f32_16x16x32_bf16(a, b, c, 0, 0, 0);
}
DEV u16 f2bf(float f) {
  uint32 u = __float_as_uint(f);
  return (u16)((u + 0x7FFFu + ((u >> 16) & 1u)) >> 16);
}
DEV float bf2f(u16 h) { return __uint_as_float(((uint32)h) << 16); }
DEV float bfLO(uint32 u) { return __uint_as_float(u << 16); }
DEV float bfHI(uint32 u) { return __uint_as_float(u & 0xFFFF0000u); }
DEV float sigmoid_(float x) { return 1.f / (1.f + __expf(-x)); }
DEV float tanh_(float x) {
  float cx = fminf(fmaxf(x, -15.f), 15.f);
  float e = __expf(2.f * cx);
  return (e - 1.f) / (e + 1.f);
}

// ---- device-coherent (agent-scope, relaxed) data movement; compiler-tracked ----
DEV u64 ldA64(const void* p) {
  return __hip_atomic_load((u64*)p, __ATOMIC_RELAXED, __HIP_MEMORY_SCOPE_AGENT);
}
DEV void stA64(void* p, u64 v) {
  __hip_atomic_store((u64*)p, v, __ATOMIC_RELAXED, __HIP_MEMORY_SCOPE_AGENT);
}
DEV void stA32(int* p, int v) {
  __hip_atomic_store(p, v, __ATOMIC_RELAXED, __HIP_MEMORY_SCOPE_AGENT);
}
DEV bf8 pk_frag(u64 lo, u64 hi) {
  u32x4 v = {(uint32)lo, (uint32)(lo >> 32), (uint32)hi, (uint32)(hi >> 32)};
  return __builtin_bit_cast(bf8, v);
}

// ---- sync primitives ----
DEV void wait_vm0() { asm volatile("s_waitcnt vmcnt(0)" ::: "memory"); }
// slot-based barrier: producers WRITE slot[i]=tgt (no RMW); one wave polls all
// slots with a coalesced lane-load + ballot. Call from a full wave.
DEV void wait_slots(const int* slots, int n, int tgt) {
  const int lane = threadIdx.x & 63;
  for (int i = 0; i < (1 << 21); ++i) {
    int v = 0x7fffffff;
    if (lane < n)
      v = __hip_atomic_load((int*)(slots + lane), __ATOMIC_RELAXED,
                            __HIP_MEMORY_SCOPE_AGENT);
    if (__all(v >= tgt)) return;
    __builtin_amdgcn_s_sleep(1);
  }
}

namespace L {
// sizes: B=32,S=60,T=59,V=50000,E=300(pad320),H=512,3H=1536
constexpr size_t o_flags  = 0;          // 1024 int
constexpr size_t o_rowsum = 4096;       // 1920 f32
constexpr size_t o_bcomb  = 11776;      // 1536 f32
constexpr size_t o_gistat = 17920;      // 32x1536 f32
constexpr size_t o_xbuf   = 214528;     // 2x32x1024 bf16  (attn | h)
constexpr size_t o_henc   = 345600;     // 2x32x512 bf16
constexpr size_t o_haff   = 411136;     // 2x32x512 bf16
constexpr size_t o_cat    = 476672;     // 32x1024 bf16 (state_enc | state_aff)
constexpr size_t o_Kbuf   = 542208;     // 1920x512 bf16 (row = s*32+b)
constexpr size_t o_KA     = 2508288;    // 1920x512 bf16
constexpr size_t o_embP   = 4474368;    // 1920x320 bf16
constexpr size_t o_embA   = 5703168;    // 1920x320 bf16
constexpr size_t o_embD   = 6931968;    // 1888x320 bf16
constexpr size_t o_encWi  = 8140288;    // 1536x320 bf16
constexpr size_t o_affWi  = 9123328;    // 1536x320 bf16
constexpr size_t o_Whe    = 10106368;   // 1536x512 bf16
constexpr size_t o_Wha    = 11679232;   // 1536x512 bf16
constexpr size_t o_decWi  = 13252096;   // 1536x512 bf16
constexpr size_t o_WlT    = 14824960;   // 1328x512 bf16
constexpr size_t o_Wa     = 16184832;   // 512x512 bf16
constexpr size_t o_Wp     = 16709120;   // 512x1024 bf16
constexpr size_t o_wq     = 17757696;   // 32768 uint4 (packed Wc^T pairs)
constexpr size_t o_Wcomb  = 18281984;   // 1536x1328 f32
constexpr size_t o_WdE    = 26441216;   // 1536x320 bf16
constexpr size_t o_WdA    = 27424256;   // 1536x512 bf16
constexpr size_t o_Wd2    = 28997120;   // 1536x1024 bf16 (Wcomb_attn | dec_Wh)
constexpr size_t o_giE    = 32142848;   // 1920x1536 f32
constexpr size_t o_giA    = 43939328;   // 1920x1536 f32
constexpr size_t o_giD    = 55735808;   // 1888x1536 f32
constexpr size_t o_outsB  = 67335680;   // 1920x1024 bf16 (row = t*32+b : h|attn)
constexpr size_t o_WvB    = 71267840;   // 50176x1024 bf16 (optional)
constexpr size_t WS_FULL  = 174028288;
constexpr size_t WOFF = 94400000;       // weights output offset (floats)
// slots (ints): [0..31] dec A; [64..127] dec B; [128..159] enc g0; [192..223] enc g1
}

// ---------------- prep: embedding gathers -> bf16, padded K=320 ----------------
__global__ __launch_bounds__(256) void kp_gather(
    const int* __restrict__ posts, const int* __restrict__ resp,
    const float* __restrict__ emb, const float* __restrict__ aemb, char* ws)
{
  using namespace L;
  const int gid = blockIdx.x * 256 + threadIdx.x;
  const int r = gid / 320, e = gid - r * 320;
  u16* embP = (u16*)(ws + o_embP);
  u16* embA = (u16*)(ws + o_embA);
  u16* embD = (u16*)(ws + o_embD);
  if (r < 1920) {
    const int b = r & 31, s = r >> 5;
    const int tok = posts[b * 60 + s];
    embP[r * 320 + e] = f2bf(e < 300 ? emb[(size_t)tok * 300 + e] : 0.f);
    embA[r * 320 + e] = f2bf(e < 300 ? aemb[(size_t)tok * 300 + e] : 0.f);
  } else if (r < 3808) {
    const int r2 = r - 1920;
    const int b = r2 & 31, t = r2 >> 5;
    const int tok = resp[b * 60 + t];
    embD[r2 * 320 + e] = f2bf(e < 300 ? emb[(size_t)tok * 300 + e] : 0.f);
  }
}

// ---------------- prep: weight conversions / transposes / zeroing ----------------
__global__ __launch_bounds__(256) void kp_wconv(
    const float* __restrict__ encWi, const float* __restrict__ affWi,
    const float* __restrict__ encWh, const float* __restrict__ affWh,
    const float* __restrict__ dWi, const float* __restrict__ Wl,
    const float* __restrict__ Wa, const float* __restrict__ Wp,
    const float* __restrict__ Wc, char* ws)
{
  using namespace L;
  long gid = (long)blockIdx.x * 256 + threadIdx.x;
  if (gid < 983040) {  // enc_Wi / aff_Wi -> [1536][320] bf16 (pad)
    const int g = gid >= 491520;
    const long u = gid - (g ? 491520 : 0);
    const int n = (int)(u / 320), e = (int)(u - (long)n * 320);
    const float* src = g ? affWi : encWi;
    u16* dst = (u16*)(ws + (g ? o_affWi : o_encWi));
    dst[u] = f2bf(e < 300 ? src[(size_t)n * 300 + e] : 0.f);
    return;
  }
  gid -= 983040;
  if (gid < 2359296) {  // enc_Wh / aff_Wh / dec_Wi -> bf16 direct
    const int g = (int)(gid / 786432);
    const long u = gid - (long)g * 786432;
    const float* src = g == 0 ? encWh : (g == 1 ? affWh : dWi);
    u16* dst = (u16*)(ws + (g == 0 ? o_Whe : (g == 1 ? o_Wha : o_decWi)));
    dst[u] = f2bf(src[u]);
    return;
  }
  gid -= 2359296;
  if (gid < 679936) {  // Wl^T -> [1328][512] bf16 (pad rows)
    const int j = (int)(gid >> 9), k = (int)(gid & 511);
    ((u16*)(ws + o_WlT))[gid] = f2bf(j < 1324 ? Wl[(size_t)k * 1324 + j] : 0.f);
    return;
  }
  gid -= 679936;
  if (gid < 262144) { ((u16*)(ws + o_Wa))[gid] = f2bf(Wa[gid]); return; }
  gid -= 262144;
  if (gid < 524288) { ((u16*)(ws + o_Wp))[gid] = f2bf(Wp[gid]); return; }
  gid -= 524288;
  if (gid < 131072) {  // packed Wc^T pairs: u32 idx = (g4*512+j)*4+q ; d0 = g4*8+q*2
    const int q = (int)(gid & 3), j = (int)((gid >> 2) & 511), g4 = (int)(gid >> 11);
    const int d0 = g4 * 8 + q * 2;
    const uint32 lo = f2bf(Wc[(size_t)j * 512 + d0]);
    const uint32 hi = f2bf(Wc[(size_t)j * 512 + d0 + 1]);
    ((uint32*)(ws + o_wq))[gid] = lo | (hi << 16);
    return;
  }
  gid -= 131072;
  if (gid < 2944) {  // zero flags + rowsum
    if (gid < 1024) ((uint32*)(ws + o_flags))[gid] = 0;
    else ((uint32*)(ws + o_rowsum))[gid - 1024] = 0;
    return;
  }
  gid -= 2944;
  if (gid < 49152) {  // zero: outsB pad rows, henc, haff (u32 words)
    if (gid < 16384) ((uint32*)(ws + o_outsB + (size_t)1888 * 1024 * 2))[gid] = 0;
    else if (gid < 32768) ((uint32*)(ws + o_henc))[gid - 16384] = 0;
    else ((uint32*)(ws + o_haff))[gid - 32768] = 0;
  }
}

// ---------------- prep: bcomb = dec_Wi @ bl + dec_bi ----------------
__global__ __launch_bounds__(256) void kp_bcomb(
    const float* __restrict__ dWi, const float* __restrict__ bl,
    const float* __restrict__ dbi, char* ws)
{
  const int i = blockIdx.x * 256 + threadIdx.x;
  if (i >= 1536) return;
  float a = dbi[i];
  for (int k = 0; k < 512; ++k) a += dWi[(size_t)i * 512 + k] * bl[k];
  ((float*)(ws + L::o_bcomb))[i] = a;
}

// ---------------- prep: split Wcomb into bf16 pieces ----------------
__global__ __launch_bounds__(256) void kp_pack2(
    const float* __restrict__ Wcomb, const float* __restrict__ dWh, char* ws)
{
  using namespace L;
  long gid = (long)blockIdx.x * 256 + threadIdx.x;
  if (gid < 491520) {  // Wd_emb [1536][320] <- Wcomb[:,0:300]
    const int n = (int)(gid / 320), e = (int)(gid - (long)n * 320);
    ((u16*)(ws + o_WdE))[gid] = f2bf(e < 300 ? Wcomb[(size_t)n * 1328 + e] : 0.f);
    return;
  }
  gid -= 491520;
  if (gid < 786432) {  // Wd_aff [1536][512] <- Wcomb[:,300:812]
    const int n = (int)(gid >> 9), k = (int)(gid & 511);
    ((u16*)(ws + o_WdA))[gid] = f2bf(Wcomb[(size_t)n * 1328 + 300 + k]);
    return;
  }
  gid -= 786432;
  if (gid < 1572864) {  // Wd2 [1536][1024] = [Wcomb[:,812:1324] | dec_Wh]
    const int n = (int)(gid >> 10), k = (int)(gid & 1023);
    const float v = (k < 512) ? Wcomb[(size_t)n * 1328 + 812 + k]
                              : dWh[(size_t)n * 512 + (k - 512)];
    ((u16*)(ws + o_Wd2))[gid] = f2bf(v);
  }
}

// ---------------- generic MFMA GEMM: C[M][N] = A[M][Kp] * B[N][Kp]^T (+bias) ----------------
__global__ __launch_bounds__(256) void k_gemm_nt(
    const u16* __restrict__ A, const u16* __restrict__ Bm,
    float* __restrict__ C, const float* __restrict__ bias,
    const int M, const int N, const int Kp)
{
  const int mt = blockIdx.x, cb = blockIdx.y;
  const int w = threadIdx.x >> 6, lane = threadIdx.x & 63;
  const int l15 = lane & 15, lhi = lane >> 4;
  const u16* arow = A + (size_t)(mt * 16 + l15) * Kp + lhi * 8;
  const int c0 = cb * 256 + w * 64;
  f4 acc[4];
#pragma unroll
  for (int nn = 0; nn < 4; ++nn) acc[nn] = (f4){0.f, 0.f, 0.f, 0.f};
  for (int k = 0; k < Kp; k += 32) {
    const bf8 a = *(const bf8*)(arow + k);
#pragma unroll
    for (int nn = 0; nn < 4; ++nn) {
      const int cs = c0 + nn * 16;
      if (cs < N) {
        const bf8 b = *(const bf8*)(Bm + (size_t)(cs + l15) * Kp + k + lhi * 8);
        acc[nn] = MFMA(a, b, acc[nn]);
      }
    }
  }
#pragma unroll
  for (int nn = 0; nn < 4; ++nn) {
    const int cs = c0 + nn * 16;
    if (cs >= N) continue;
    const int c = cs + l15;
    const float bb = bias ? bias[c] : 0.f;
#pragma unroll
    for (int j = 0; j < 4; ++j) {
      const int r = mt * 16 + lhi * 4 + j;
      C[(size_t)r * N + c] = acc[nn][j] + bb;
    }
  }
}

// -------- encoder + fused bulk: blk<64 enc; blk<772 giD gemm; else Wv->bf16 ----
__global__ __launch_bounds__(256) void k_encplus(
    char* __restrict__ ws, const float* __restrict__ enc_bh,
    const float* __restrict__ aff_bh, const float* __restrict__ Wv)
{
  using namespace L;
  const int tid = threadIdx.x, blk = blockIdx.x;
  const int wave = tid >> 6, lane = tid & 63;
  const int l15 = lane & 15, lhi = lane >> 4;

  if (blk < 64) {
    // ===== encoder role (round-6 proven): 32 blocks per GRU, 2 active waves =====
    const int g = blk >> 5;
    const bool act = wave < 2;
    int* flags = (int*)(ws + o_flags);
    int* slotE = flags + 128 + g * 64;
    const u16* Wh = (const u16*)(ws + (g ? o_Wha : o_Whe));
    const float* gi = (const float*)(ws + (g ? o_giA : o_giE));
    const float* bh = g ? aff_bh : enc_bh;
    u16* hbuf = (u16*)(ws + (g ? o_haff : o_henc));
    u16* cat = (u16*)(ws + o_cat);
    u16* Kb = (u16*)(ws + o_Kbuf);

    const int wid = (blk & 31) * 2 + (wave & 1);     // 0..63 when act
    const int btile = wid >> 5, ctile = wid & 31;
    const int bl = btile * 16 + l15;
    const int c0 = ctile * 16 + lhi * 4;
    const u16* wr0 = Wh + (size_t)(ctile * 16 + l15) * 512 + lhi * 8;
    const u16* wr1 = wr0 + (size_t)512 * 512;
    const u16* wr2 = wr1 + (size_t)512 * 512;
    f4 bhr4 = {0.f, 0.f, 0.f, 0.f}, bhz4 = bhr4, bhn4 = bhr4;
    if (act) {
      bhr4 = *(const f4*)(bh + c0);
      bhz4 = *(const f4*)(bh + 512 + c0);
      bhn4 = *(const f4*)(bh + 1024 + c0);
    }
    for (int s = 0; s < 60; ++s) {
      const u16* hin = hbuf + (s & 1) * (32 * 512);
      u16* hout = hbuf + ((s & 1) ^ 1) * (32 * 512);
      if (act) {
        const u16* brow = hin + bl * 512 + lhi * 8;
        u64 flo[16], fhi[16];
#pragma unroll
        for (int kk = 0; kk < 16; ++kk) {      // batched: one exposed latency
          flo[kk] = ldA64(brow + kk * 32);
          fhi[kk] = ldA64(brow + kk * 32 + 4);
        }
        const u64 hq = ldA64(hin + bl * 512 + c0);
        f4 ar = {0.f, 0.f, 0.f, 0.f}, az = ar, an = ar;
#pragma unroll
        for (int kk = 0; kk < 16; ++kk) {
          const bf8 hf = pk_frag(flo[kk], fhi[kk]);
          ar = MFMA(*(const bf8*)(wr0 + kk * 32), hf, ar);
          az = MFMA(*(const bf8*)(wr1 + kk * 32), hf, az);
          an = MFMA(*(const bf8*)(wr2 + kk * 32), hf, an);
        }
        const float* gr = gi + (size_t)(s * 32 + bl) * 1536;
        const f4 g0 = *(const f4*)(gr + c0);
        const f4 g1 = *(const f4*)(gr + 512 + c0);
        const f4 g2 = *(const f4*)(gr + 1024 + c0);
        u64 pk = 0;
#pragma unroll
        for (int j = 0; j < 4; ++j) {
          const float r = sigmoid_(g0[j] + ar[j] + bhr4[j]);
          const float z = sigmoid_(g1[j] + az[j] + bhz4[j]);
          const float n = tanh_(g2[j] + r * (an[j] + bhn4[j]));
          const float hold = bf2f((u16)(hq >> (16 * j)));
          pk |= (u64)f2bf((1.f - z) * n + z * hold) << (16 * j);
        }
        stA64(hout + bl * 512 + c0, pk);
        if (g) *(u64*)(Kb + (size_t)(s * 32 + bl) * 512 + c0) = pk;  // next kernel
        if (s == 59) *(u64*)(cat + bl * 1024 + g * 512 + c0) = pk;   // next kernel
      }
      wait_vm0();
      __syncthreads();
      if (tid == 0) stA32(&slotE[blk & 31], s + 1);   // slot write, no RMW
      if (wave == 2) wait_slots(slotE, 32, s + 1);    // idle wave polls
      __syncthreads();
    }
  } else if (blk < 772) {
    // ===== giD = embD @ WdE^T  (fused; consumed by next-next kernel) =====
    const int bb = blk - 64;
    const int mt = bb % 118, cb = bb / 118;
    const u16* A = (const u16*)(ws + o_embD);
    const u16* Bm = (const u16*)(ws + o_WdE);
    float* C = (float*)(ws + o_giD);
    const int Kp = 320, N = 1536;
    const int w = wave;
    const u16* arow = A + (size_t)(mt * 16 + l15) * Kp + lhi * 8;
    const int c0 = cb * 256 + w * 64;
    f4 acc[4];
#pragma unroll
    for (int nn = 0; nn < 4; ++nn) acc[nn] = (f4){0.f, 0.f, 0.f, 0.f};
    for (int k = 0; k < Kp; k += 32) {
      const bf8 a = *(const bf8*)(arow + k);
#pragma unroll
      for (int nn = 0; nn < 4; ++nn) {
        const bf8 b = *(const bf8*)(Bm + (size_t)(c0 + nn * 16 + l15) * Kp + k + lhi * 8);
        acc[nn] = MFMA(a, b, acc[nn]);
      }
    }
#pragma unroll
    for (int nn = 0; nn < 4; ++nn) {
      const int c = c0 + nn * 16 + l15;
#pragma unroll
      for (int j = 0; j < 4; ++j)
        C[(size_t)(mt * 16 + lhi * 4 + j) * N + c] = acc[nn][j];
    }
  } else {
    // ===== Wv -> bf16 (padded rows) fused =====
    const long gid = (long)(blk - 772) * 256 + tid;
    const int r = (int)(gid >> 8), q = (int)(gid & 255);
    u16* WvB = (u16*)(ws + o_WvB);
    uint2 o;
    if (r < 50000) {
      const float4 f = *(const float4*)(Wv + (size_t)r * 1024 + q * 4);
      o.x = (uint32)f2bf(f.x) | ((uint32)f2bf(f.y) << 16);
      o.y = (uint32)f2bf(f.z) | ((uint32)f2bf(f.w) << 16);
    } else { o.x = 0u; o.y = 0u; }
    if (r < 50176) *(uint2*)(WvB + (size_t)r * 1024 + q * 4) = o;
  }
}

// ---------------- mid kernel: state0 | gi_static | KA (no sync needed) ----------
__global__ __launch_bounds__(256) void k_mid(char* __restrict__ ws,
                                             const float* __restrict__ bp)
{
  using namespace L;
  const int tid = threadIdx.x, blk = blockIdx.x;
  const int wave = tid >> 6, lane = tid & 63;
  const int l15 = lane & 15, lhi = lane >> 4;
  u16* xb = (u16*)(ws + o_xbuf);
  u16* cat = (u16*)(ws + o_cat);
  u16* Kb = (u16*)(ws + o_Kbuf);

  if (blk < 16) {  // state0 = tanh(cat @ Wp^T + bp) -> xbuf[0]; zero attn half
    const u16* Wp_ = (const u16*)(ws + o_Wp);
    const int wid = blk * 4 + wave;
    const int btile = wid >> 5, ctile = wid & 31;
    const int bl = btile * 16 + l15;
    const int c0 = ctile * 16 + lhi * 4;
    const u16* arow = Wp_ + (size_t)(ctile * 16 + l15) * 1024 + lhi * 8;
    const u16* brow = cat + bl * 1024 + lhi * 8;
    f4 acc = {0.f, 0.f, 0.f, 0.f};
    for (int k = 0; k < 1024; k += 32)
      acc = MFMA(*(const bf8*)(arow + k), *(const bf8*)(brow + k), acc);
    const f4 bp4 = *(const f4*)(bp + c0);
    u64 pk = 0;
#pragma unroll
    for (int j = 0; j < 4; ++j)
      pk |= (u64)f2bf(tanh_(acc[j] + bp4[j])) << (16 * j);
    *(u64*)(xb + bl * 1024 + 512 + c0) = pk;
    *(u64*)(xb + bl * 1024 + c0) = 0;          // init attn = 0
  } else if (blk < 32) {  // gi_static = ctx_aff @ Wd_aff^T + bcomb
    const u16* WdA = (const u16*)(ws + o_WdA);
    const float* bco = (const float*)(ws + o_bcomb);
    float* gst = (float*)(ws + o_gistat);
    const int wid = (blk - 16) * 4 + wave;
    const int btile = wid >> 5, ctb = wid & 31;
    const int bl = btile * 16 + l15;
    const int c0 = ctb * 16 + lhi * 4;
    const u16* brow = cat + bl * 1024 + 512 + lhi * 8;
    const u16* a0p = WdA + (size_t)(ctb * 16 + l15) * 512 + lhi * 8;
    const u16* a1p = a0p + (size_t)512 * 512;
    const u16* a2p = a1p + (size_t)512 * 512;
    f4 a0 = {0.f, 0.f, 0.f, 0.f}, a1 = a0, a2 = a0;
    for (int k = 0; k < 512; k += 32) {
      const bf8 bfr = *(const bf8*)(brow + k);
      a0 = MFMA(*(const bf8*)(a0p + k), bfr, a0);
      a1 = MFMA(*(const bf8*)(a1p + k), bfr, a1);
      a2 = MFMA(*(const bf8*)(a2p + k), bfr, a2);
    }
    const f4 v0 = *(const f4*)(bco + c0);
    const f4 v1 = *(const f4*)(bco + 512 + c0);
    const f4 v2 = *(const f4*)(bco + 1024 + c0);
    *(f4*)(gst + bl * 1536 + c0) = a0 + v0;
    *(f4*)(gst + bl * 1536 + 512 + c0) = a1 + v1;
    *(f4*)(gst + bl * 1536 + 1024 + c0) = a2 + v2;
  } else {  // KA = K @ Wa^T
    const u16* Wa_ = (const u16*)(ws + o_Wa);
    u16* KAp = (u16*)(ws + o_KA);
    const int widK = (blk - 32) * 4 + wave;
    for (int task = widK; task < 3840; task += 192) {
      const int mt = task >> 5, ct = task & 31;
      const int m = mt * 16 + l15;
      const int c0 = ct * 16 + lhi * 4;
      const u16* arow = Wa_ + (size_t)(ct * 16 + l15) * 512 + lhi * 8;
      const u16* brow = Kb + (size_t)m * 512 + lhi * 8;
      f4 acc = {0.f, 0.f, 0.f, 0.f};
      for (int k = 0; k < 512; k += 32)
        acc = MFMA(*(const bf8*)(arow + k), *(const bf8*)(brow + k), acc);
      u64 pk = 0;
#pragma unroll
      for (int j = 0; j < 4; ++j) pk |= (u64)f2bf(acc[j]) << (16 * j);
      *(u64*)(KAp + (size_t)m * 512 + c0) = pk;
    }
  }
}

// ----- fused decoder + vocab GEMM: blk<96 dec (round-6 proven); else vocab ----
// outs rows are t-major (row = t*32+b), written agent-scope so vocab tiles can
// consume them in-flight, gated on slotB progress. Vocab ordering is
// PASS-MAJOR (mtile = vb/392): dispatch order == gate order, so resident
// blocks never spin long (no CU-slot starvation). B reuse across the 15
// passes relies on L3 (100MB < 256MB) protected by NT output stores.
// NO acquire fence: outs rows are written once (agent-scope, pre-slot-update)
// and first touched by this XCD after the gate -> no stale copies possible.
__global__ __launch_bounds__(256, 1) void k_decvoc(
    char* __restrict__ ws, float* __restrict__ out,
    const float* __restrict__ dec_bh, const float* __restrict__ bc,
    const float* __restrict__ bv)
{
  using namespace L;
  const int tid = threadIdx.x, blk = blockIdx.x;
  const int wave = tid >> 6, lane = tid & 63;
  const int l15 = lane & 15, lhi = lane >> 4;
  int* flags = (int*)(ws + o_flags);
  int* slotA = flags;        // 32
  int* slotB = flags + 64;   // 64

  __shared__ float hsm[512];
  __shared__ float ctxs[512];
  __shared__ float scb[64];
  __shared__ float wsb[64];
  __shared__ u16 attn_sm[256];
  __shared__ u16 vAs[2][128][40];
  __shared__ u16 vBs[2][128][40];

  u16* xb = (u16*)(ws + o_xbuf);
  u16* outs = (u16*)(ws + o_outsB);

  if (blk < 32) {
    // A-role: h_t = GRU from [attn_{t-1} ; h_{t-1}] via Wd2 (K=1024), n-gate split.
    const bool act = wave < 2;
    const u16* Wd2 = (const u16*)(ws + o_Wd2);
    const float* gst = (const float*)(ws + o_gistat);
    const float* gD = (const float*)(ws + o_giD);
    const int wid = (blk & 31) * 2 + (wave & 1);
    const int btile = wid >> 5, ctile = wid & 31;
    const int bl = btile * 16 + l15;
    const int c0 = ctile * 16 + lhi * 4;
    const u16* wr = Wd2 + (size_t)(ctile * 16 + l15) * 1024 + lhi * 8;
    const u16* wz = wr + (size_t)512 * 1024;
    const u16* wn = wz + (size_t)512 * 1024;
    f4 bhr4 = {0.f, 0.f, 0.f, 0.f}, bhz4 = bhr4, bhn4 = bhr4;
    f4 s0 = bhr4, s1 = bhr4, s2 = bhr4;
    if (act) {
      bhr4 = *(const f4*)(dec_bh + c0);
      bhz4 = *(const f4*)(dec_bh + 512 + c0);
      bhn4 = *(const f4*)(dec_bh + 1024 + c0);
      s0 = *(const f4*)(gst + bl * 1536 + c0);
      s1 = *(const f4*)(gst + bl * 1536 + 512 + c0);
      s2 = *(const f4*)(gst + bl * 1536 + 1024 + c0);
    }
    for (int t = 0; t < 59; ++t) {
      const u16* xin = xb + (t & 1) * (32 * 1024);
      u16* xout = xb + ((t & 1) ^ 1) * (32 * 1024);
      const u16* brow = xin + bl * 1024 + lhi * 8;
      f4 ar = {0.f, 0.f, 0.f, 0.f}, az = ar, anx = ar, anh = ar;
      u64 hq = 0;
      f4 d0 = ar, d1 = ar, d2 = ar;
      // ---- stage 1: needs h(t-1) = all A slots >= t ----
      if (t) {
        if (wave == 2) wait_slots(slotA, 32, t);
        __syncthreads();
      }
      if (act) {
        u64 flo[16], fhi[16];
#pragma unroll
        for (int kk = 0; kk < 16; ++kk) {
          flo[kk] = ldA64(brow + (16 + kk) * 32);
          fhi[kk] = ldA64(brow + (16 + kk) * 32 + 4);
        }
        hq = ldA64(xin + bl * 1024 + 512 + c0);
        const float* g2p = gD + (size_t)(t * 32 + bl) * 1536;   // static prefetch
        d0 = *(const f4*)(g2p + c0);
        d1 = *(const f4*)(g2p + 512 + c0);
        d2 = *(const f4*)(g2p + 1024 + c0);
#pragma unroll
        for (int kk = 0; kk < 16; ++kk) {
          const bf8 xf = pk_frag(flo[kk], fhi[kk]);
          ar = MFMA(*(const bf8*)(wr + (16 + kk) * 32), xf, ar);
          az = MFMA(*(const bf8*)(wz + (16 + kk) * 32), xf, az);
          anh = MFMA(*(const bf8*)(wn + (16 + kk) * 32), xf, anh);
        }
      }
      // ---- stage 2: needs attn(t-1) = all B slots >= t ----
      if (t) {
        if (wave == 2) wait_slots(slotB, 64, t);
        __syncthreads();
      }
      if (act) {
        u64 glo[16], ghi[16];
#pragma unroll
        for (int kk = 0; kk < 16; ++kk) {
          glo[kk] = ldA64(brow + kk * 32);
          ghi[kk] = ldA64(brow + kk * 32 + 4);
        }
#pragma unroll
        for (int kk = 0; kk < 16; ++kk) {
          const bf8 xf = pk_frag(glo[kk], ghi[kk]);
          ar = MFMA(*(const bf8*)(wr + kk * 32), xf, ar);
          az = MFMA(*(const bf8*)(wz + kk * 32), xf, az);
          anx = MFMA(*(const bf8*)(wn + kk * 32), xf, anx);
        }
        u64 pk = 0;
#pragma unroll
        for (int j = 0; j < 4; ++j) {
          const float r = sigmoid_(s0[j] + d0[j] + ar[j] + bhr4[j]);
          const float z = sigmoid_(s1[j] + d1[j] + az[j] + bhz4[j]);
          const float n = tanh_(s2[j] + d2[j] + anx[j] + r * (anh[j] + bhn4[j]));
          const float hold = bf2f((u16)(hq >> (16 * j)));
          pk |= (u64)f2bf((1.f - z) * n + z * hold) << (16 * j);
        }
        stA64(xout + bl * 1024 + 512 + c0, pk);
        stA64(outs + (size_t)(t * 32 + bl) * 1024 + c0, pk);  // t-major, visible
      }
      wait_vm0();
      __syncthreads();
      if (tid == 0) stA32(&slotA[blk], t + 1);   // slot write, no RMW
    }
  } else if (blk < 96) {
    // B-role: 2 blocks per batch element: scores -> softmax -> ctx -> attn
    const int idx = blk - 32;
    const int b = idx >> 1, half = idx & 1;
    const u16* KAp = (const u16*)(ws + o_KA);
    const u16* Kb = (const u16*)(ws + o_Kbuf);
    const uint4* wq = (const uint4*)(ws + o_wq);
    for (int t = 0; t < 59; ++t) {
      if (wave == 0) wait_slots(slotA, 32, t + 1);
      __syncthreads();
      const u16* xcur = xb + ((t & 1) ^ 1) * (32 * 1024);
      if (tid < 128) {  // coherent-load h (written by A this step)
        const u64 hv = ldA64(xcur + b * 1024 + 512 + tid * 4);
        const uint32 w0 = (uint32)hv, w1 = (uint32)(hv >> 32);
        hsm[tid * 4 + 0] = bfLO(w0);
        hsm[tid * 4 + 1] = bfHI(w0);
        hsm[tid * 4 + 2] = bfLO(w1);
        hsm[tid * 4 + 3] = bfHI(w1);
      }
      __syncthreads();
      if (tid < 240) {  // scores[s] = h . KA[s,b,:]   (2 accumulator chains)
        const int s = tid >> 2, q = tid & 3;
        const u16* kr = KAp + (size_t)(s * 32 + b) * 512 + q * 128;
        const float* hq = &hsm[q * 128];
        float acc0 = 0.f, acc1 = 0.f;
#pragma unroll 4
        for (int i = 0; i < 128; i += 8) {
          const uint2 k4 = *(const uint2*)(kr + i);
          const uint2 k5 = *(const uint2*)(kr + i + 4);
          const float4 h4 = *(const float4*)(hq + i);
          const float4 h5 = *(const float4*)(hq + i + 4);
          acc0 += h4.x * bfLO(k4.x) + h4.y * bfHI(k4.x)
                + h4.z * bfLO(k4.y) + h4.w * bfHI(k4.y);
          acc1 += h5.x * bfLO(k5.x) + h5.y * bfHI(k5.x)
                + h5.z * bfLO(k5.y) + h5.w * bfHI(k5.y);
        }
        float acc = acc0 + acc1;
        acc += __shfl_xor(acc, 1);
        acc += __shfl_xor(acc, 2);
        if ((tid & 3) == 0) scb[s] = acc;
      }
      __syncthreads();
      if (tid < 64) {  // softmax over 60
        const float v = (tid < 60) ? scb[tid] : -1e30f;
        float m = v;
#pragma unroll
        for (int d = 1; d < 64; d <<= 1) m = fmaxf(m, __shfl_xor(m, d));
        const float e = (tid < 60) ? __expf(v - m) : 0.f;
        float sm = e;
#pragma unroll
        for (int d = 1; d < 64; d <<= 1) sm += __shfl_xor(sm, d);
        const float w = e / sm;
        if (tid < 60) {
          wsb[tid] = w;
          if (half == 0) out[WOFF + (size_t)(b * 59 + t) * 60 + tid] = w;
        }
      }
      __syncthreads();
      {  // ctx = sum_s w[s] * K[s,b,:]  (4 accumulator chains)
        float c0a = 0.f, c0b = 0.f, c1a = 0.f, c1b = 0.f;
#pragma unroll 2
        for (int s = 0; s < 60; s += 2) {
          const float w0 = wsb[s], w1 = wsb[s + 1];
          const u16* kr0 = Kb + (size_t)(s * 32 + b) * 512;
          const u16* kr1 = Kb + (size_t)((s + 1) * 32 + b) * 512;
          c0a += w0 * bf2f(kr0[tid]);
          c1a += w0 * bf2f(kr0[tid + 256]);
          c0b += w1 * bf2f(kr1[tid]);
          c1b += w1 * bf2f(kr1[tid + 256]);
        }
        ctxs[tid] = c0a + c0b;
        ctxs[tid + 256] = c1a + c1b;
      }
      __syncthreads();
      const int jj = half * 256 + tid;  // attn[jj] = tanh(bc + ctx . Wc[jj,:])
      float faa[4] = {0.f, 0.f, 0.f, 0.f};
      float fbb[4] = {0.f, 0.f, 0.f, 0.f};
#pragma unroll 4
      for (int g4 = 0; g4 < 64; ++g4) {
        const uint4 wv4 = wq[g4 * 512 + jj];
        const float4 ca = *(const float4*)&ctxs[g4 * 8];
        const float4 cb2 = *(const float4*)&ctxs[g4 * 8 + 4];
        faa[g4 & 3] += ca.x * bfLO(wv4.x) + ca.y * bfHI(wv4.x)
                     + ca.z * bfLO(wv4.y) + ca.w * bfHI(wv4.y);
        fbb[g4 & 3] += cb2.x * bfLO(wv4.z) + cb2.y * bfHI(wv4.z)
                     + cb2.z * bfLO(wv4.w) + cb2.w * bfHI(wv4.w);
      }
      const float fa = bc[jj] + faa[0] + faa[1] + faa[2] + faa[3]
                     + fbb[0] + fbb[1] + fbb[2] + fbb[3];
      attn_sm[tid] = f2bf(tanh_(fa));
      __syncthreads();
      if (tid < 64) {  // pack 4 attn values -> coherent u64 store
        u16* xout = xb + ((t & 1) ^ 1) * (32 * 1024);
        const u64 pk = (u64)attn_sm[tid * 4] | ((u64)attn_sm[tid * 4 + 1] << 16)
                     | ((u64)attn_sm[tid * 4 + 2] << 32) | ((u64)attn_sm[tid * 4 + 3] << 48);
        const int cc = half * 256 + tid * 4;
        stA64(xout + b * 1024 + cc, pk);
        stA64(outs + (size_t)(t * 32 + b) * 1024 + 512 + cc, pk);  // t-major
      }
      wait_vm0();
      __syncthreads();
      if (tid == 0) stA32(&slotB[idx], t + 1);   // slot write, no RMW
    }
  } else {
    // ===== vocab role: 128x128 tile; PASS-MAJOR (gate-monotone dispatch) =====
    const int vb = blk - 96;                 // 0..5879
    const int mtile = vb / 392, ntile = vb % 392;
    const int rbase = mtile * 128, cbase = ntile * 128;
    const int tgt = (4 * mtile + 4 < 59) ? (4 * mtile + 4) : 59;
    if (wave == 0) wait_slots(slotB, 64, tgt);
    __syncthreads();
    // (no acquire fence -- see header comment)

    const u16* A = outs;                     // t-major rows
    const u16* Bm = (const u16*)(ws + o_WvB);
    float* rowsum = (float*)(ws + o_rowsum);
    const int m0 = (wave >> 1) * 64, n0 = (wave & 1) * 64;
    const int sr0 = tid >> 2, sk = (tid & 3) * 8;  // + row 64 offset for 2nd load

    f4 acc[4][4];
#pragma unroll
    for (int mi = 0; mi < 4; ++mi)
#pragma unroll
      for (int ni = 0; ni < 4; ++ni) acc[mi][ni] = (f4){0.f, 0.f, 0.f, 0.f};

    const u16* gA0 = A + (size_t)(rbase + sr0) * 1024 + sk;
    const u16* gA1 = A + (size_t)(rbase + 64 + sr0) * 1024 + sk;
    const u16* gB0 = Bm + (size_t)(cbase + sr0) * 1024 + sk;
    const u16* gB1 = Bm + (size_t)(cbase + 64 + sr0) * 1024 + sk;

    uint4 a0 = *(const uint4*)(gA0), a1 = *(const uint4*)(gA1);
    uint4 b0 = *(const uint4*)(gB0), b1 = *(const uint4*)(gB1);
    *(uint4*)&vAs[0][sr0][sk] = a0;
    *(uint4*)&vAs[0][64 + sr0][sk] = a1;
    *(uint4*)&vBs[0][sr0][sk] = b0;
    *(uint4*)&vBs[0][64 + sr0][sk] = b1;
    __syncthreads();

    int cur = 0;
#pragma unroll 1
    for (int kt = 0; kt < 32; ++kt) {
      if (kt < 31) {
        const int k0 = (kt + 1) * 32;
        a0 = *(const uint4*)(gA0 + k0);
        a1 = *(const uint4*)(gA1 + k0);
        b0 = *(const uint4*)(gB0 + k0);
        b1 = *(const uint4*)(gB1 + k0);
      }
      bf8 af[4], bfr[4];
#pragma unroll
      for (int mi = 0; mi < 4; ++mi)
        af[mi] = *(const bf8*)&vAs[cur][m0 + mi * 16 + l15][lhi * 8];
#pragma unroll
      for (int ni = 0; ni < 4; ++ni)
        bfr[ni] = *(const bf8*)&vBs[cur][n0 + ni * 16 + l15][lhi * 8];
#pragma unroll
      for (int mi = 0; mi < 4; ++mi)
#pragma unroll
        for (int ni = 0; ni < 4; ++ni)
          acc[mi][ni] = MFMA(af[mi], bfr[ni], acc[mi][ni]);
      if (kt < 31) {
        __syncthreads();
        *(uint4*)&vAs[cur ^ 1][sr0][sk] = a0;
        *(uint4*)&vAs[cur ^ 1][64 + sr0][sk] = a1;
        *(uint4*)&vBs[cur ^ 1][sr0][sk] = b0;
        *(uint4*)&vBs[cur ^ 1][64 + sr0][sk] = b1;
        __syncthreads();
        cur ^= 1;
      }
    }

    // epilogue: exp + NT-store (row mapped t-major -> b*59+t) + rowsum atomics
#pragma unroll
    for (int mi = 0; mi < 4; ++mi) {
      float rs[4] = {0.f, 0.f, 0.f, 0.f};
      int ro_[4]; bool rv[4];
#pragma unroll
      for (int j = 0; j < 4; ++j) {
        const int r = rbase + m0 + mi * 16 + lhi * 4 + j;
        const int tt = r >> 5, bb2 = r & 31;
        rv[j] = tt < 59;
        ro_[j] = bb2 * 59 + tt;
      }
#pragma unroll
      for (int ni = 0; ni < 4; ++ni) {
        const int c = cbase + n0 + ni * 16 + l15;
        if (c < 50000) {
          const float bb = bv[c];
#pragma unroll
          for (int j = 0; j < 4; ++j) {
            if (rv[j]) {
              const float e = __expf(acc[mi][ni][j] + bb);
              __builtin_nontemporal_store(e, &out[(size_t)ro_[j] * 50000 + c]);
              rs[j] += e;
            }
          }
        }
      }
#pragma unroll
      for (int j = 0; j < 4; ++j) {
#pragma unroll
        for (int d = 1; d < 16; d <<= 1) rs[j] += __shfl_xor(rs[j], d);
      }
      if (l15 == 0) {
#pragma unroll
        for (int j = 0; j < 4; ++j)
          if (rv[j]) atomicAdd(&rowsum[ro_[j]], rs[j]);
      }
    }
  }
}

// ---------------- vocab GEMM fallback (no bf16 Wv copy; t-major outs) ---------
__global__ __launch_bounds__(512) void k_vocab0(
    const u16* __restrict__ A, const float* __restrict__ WvF,
    const float* __restrict__ bv, float* __restrict__ out,
    float* __restrict__ rowsum)
{
  const int bid = blockIdx.x;
  const int x = bid & 7, jj = bid >> 3;
  const int mtile = jj % 15, nseq = jj / 15;
  const int ntile = nseq * 8 + x;
  if (ntile >= 196) return;
  const int w = threadIdx.x >> 6, lane = threadIdx.x & 63;
  const int l15 = lane & 15, lhi = lane >> 4;
  const int rbase = mtile * 128 + w * 16;
  const u16* arow = A + (size_t)(rbase + l15) * 1024 + lhi * 8;
  const int cbase = ntile * 256;
  f4 acc[16];
#pragma unroll
  for (int nn = 0; nn < 16; ++nn) acc[nn] = (f4){0.f, 0.f, 0.f, 0.f};
  for (int k = 0; k < 1024; k += 32) {
    const bf8 a = *(const bf8*)(arow + k);
#pragma unroll
    for (int nn = 0; nn < 16; ++nn) {
      const int cs = cbase + nn * 16;
      bf8 bfr = {0, 0, 0, 0, 0, 0, 0, 0};
      if (cs < 50000) {
        const float* p = WvF + (size_t)(cs + l15) * 1024 + k + lhi * 8;
        const float4 f0 = *(const float4*)p;
        const float4 f1 = *(const float4*)(p + 4);
        bfr[0] = (short)(__float_as_uint(f0.x) >> 16);
        bfr[1] = (short)(__float_as_uint(f0.y) >> 16);
        bfr[2] = (short)(__float_as_uint(f0.z) >> 16);
        bfr[3] = (short)(__float_as_uint(f0.w) >> 16);
        bfr[4] = (short)(__float_as_uint(f1.x) >> 16);
        bfr[5] = (short)(__float_as_uint(f1.y) >> 16);
        bfr[6] = (short)(__float_as_uint(f1.z) >> 16);
        bfr[7] = (short)(__float_as_uint(f1.w) >> 16);
      }
      acc[nn] = MFMA(a, bfr, acc[nn]);
    }
  }
#pragma unroll
  for (int j = 0; j < 4; ++j) {
    const int r = rbase + lhi * 4 + j;
    const int tt = r >> 5, bb2 = r & 31;
    if (tt >= 59) continue;
    const int ro = bb2 * 59 + tt;
    float rsv = 0.f;
#pragma unroll
    for (int nn = 0; nn < 16; ++nn) {
      const int cs = cbase + nn * 16;
      if (cs >= 50000) continue;
      const int c = cs + l15;
      const float e = __expf(acc[nn][j] + bv[c]);
      out[(size_t)ro * 50000 + c] = e;
      rsv += e;
    }
#pragma unroll
    for (int d = 1; d < 16; d <<= 1) rsv += __shfl_xor(rsv, d);
    if (l15 == 0) atomicAdd(&rowsum[ro], rsv);
  }
}

// ---------------- rowsum -> 1/rowsum ----------------
__global__ void k_invrow(float* rs)
{
  const int i = blockIdx.x * 256 + threadIdx.x;
  if (i < 1920) {
    const float s = rs[i];
    rs[i] = (s > 0.f) ? 1.f / s : 0.f;
  }
}

// ---------------- scale exp values by 1/rowsum ----------------
__global__ __launch_bounds__(256) void k_scale(float* __restrict__ out,
                                               const float* __restrict__ inv)
{
  const int bid = blockIdx.x;
  const int r = bid / 49, ch = bid - r * 49;
  const int c = ch * 1024 + threadIdx.x * 4;
  if (c < 50000) {
    const float s = inv[r];
    float4* p = (float4*)(out + (size_t)r * 50000 + c);
    float4 v = *p;
    v.x *= s; v.y *= s; v.z *= s; v.w *= s;
    *p = v;
  }
}

extern "C" void kernel_launch(void* const* d_in, const int* in_sizes, int n_in,
                              void* d_out, int out_size, void* d_ws, size_t ws_size,
                              hipStream_t stream) {
  const int* posts = (const int*)d_in[0];
  const int* resp = (const int*)d_in[1];
  const float* emb = (const float*)d_in[3];
  const float* aemb = (const float*)d_in[4];
  const float* encWi = (const float*)d_in[5];
  const float* encWh = (const float*)d_in[6];
  const float* enc_bi = (const float*)d_in[7];
  const float* enc_bh = (const float*)d_in[8];
  const float* affWi = (const float*)d_in[9];
  const float* affWh = (const float*)d_in[10];
  const float* aff_bi = (const float*)d_in[11];
  const float* aff_bh = (const float*)d_in[12];
  const float* Wp = (const float*)d_in[13];
  const float* bp = (const float*)d_in[14];
  const float* Wl = (const float*)d_in[15];
  const float* bl = (const float*)d_in[16];
  const float* dWi = (const float*)d_in[17];
  const float* dWh = (const float*)d_in[18];
  const float* dbi = (const float*)d_in[19];
  const float* dbh = (const float*)d_in[20];
  const float* Wa = (const float*)d_in[21];
  const float* Wc = (const float*)d_in[22];
  const float* bc = (const float*)d_in[23];
  const float* Wv = (const float*)d_in[24];
  const float* bv = (const float*)d_in[25];
  char* ws = (char*)d_ws;
  float* out = (float*)d_out;
  const bool useWvB = ws_size >= L::WS_FULL;

  kp_gather<<<4760, 256, 0, stream>>>(posts, resp, emb, aemb, ws);
  kp_wconv<<<19500, 256, 0, stream>>>(encWi, affWi, encWh, affWh, dWi, Wl, Wa, Wp, Wc, ws);
  kp_bcomb<<<6, 256, 0, stream>>>(dWi, bl, dbi, ws);

  // Wcomb = dec_Wi @ Wl  -> f32 [1536][1328]
  k_gemm_nt<<<dim3(96, 6), 256, 0, stream>>>(
      (const u16*)(ws + L::o_decWi), (const u16*)(ws + L::o_WlT),
      (float*)(ws + L::o_Wcomb), nullptr, 1536, 1328, 512);
  kp_pack2<<<11136, 256, 0, stream>>>((const float*)(ws + L::o_Wcomb), dWh, ws);

  // input-gate precomputes (giD is fused into k_encplus)
  k_gemm_nt<<<dim3(120, 6), 256, 0, stream>>>(
      (const u16*)(ws + L::o_embP), (const u16*)(ws + L::o_encWi),
      (float*)(ws + L::o_giE), enc_bi, 1920, 1536, 320);
  k_gemm_nt<<<dim3(120, 6), 256, 0, stream>>>(
      (const u16*)(ws + L::o_embA), (const u16*)(ws + L::o_affWi),
      (float*)(ws + L::o_giA), aff_bi, 1920, 1536, 320);

  // encoder chain + fused bulk (giD gemm + Wv->bf16 conversion)
  k_encplus<<<useWvB ? 50948 : 772, 256, 0, stream>>>(ws, enc_bh, aff_bh, Wv);
  k_mid<<<80, 256, 0, stream>>>(ws, bp);

  // decoder chain + fused, progress-gated vocab GEMM (pass-major order)
  k_decvoc<<<useWvB ? 5976 : 96, 256, 0, stream>>>(ws, out, dbh, bc, bv);

  if (!useWvB)
    k_vocab0<<<2944, 512, 0, stream>>>(
        (const u16*)(ws + L::o_outsB), Wv, bv, out, (float*)(ws + L::o_rowsum));

  k_invrow<<<8, 256, 0, stream>>>((float*)(ws + L::o_rowsum));
  k_scale<<<92512, 256, 0, stream>>>(out, (const float*)(ws + L::o_rowsum));
}

// Round 12
// 2557.478 us; speedup vs baseline: 5.3300x; 1.1026x over previous
//
#include <hip/hip_runtime.h>

typedef unsigned int uint32;
typedef unsigned short u16;
typedef unsigned long long u64;
typedef __attribute__((ext_vector_type(8))) short bf8;   // 8 x bf16 (4 VGPRs)
typedef __attribute__((ext_vector_type(4))) float f4;    // 4 x f32
typedef __attribute__((ext_vector_type(4))) uint32 u32x4;

#define DEV static __device__ __forceinline__

DEV f4 MFMA(bf8 a, bf8 b, f4 c) {
  return __builtin_amdgcn_mfma_f32_16x16x32_bf16(a, b, c, 0, 0, 0);
}
DEV u16 f2bf(float f) {
  uint32 u = __float_as_uint(f);
  return (u16)((u + 0x7FFFu + ((u >> 16) & 1u)) >> 16);
}
DEV float bf2f(u16 h) { return __uint_as_float(((uint32)h) << 16); }
DEV float bfLO(uint32 u) { return __uint_as_float(u << 16); }
DEV float bfHI(uint32 u) { return __uint_as_float(u & 0xFFFF0000u); }
DEV float sigmoid_(float x) { return 1.f / (1.f + __expf(-x)); }
DEV float tanh_(float x) {
  float cx = fminf(fmaxf(x, -15.f), 15.f);
  float e = __expf(2.f * cx);
  return (e - 1.f) / (e + 1.f);
}

// ---- device-coherent (agent-scope, relaxed) data movement; compiler-tracked ----
DEV u64 ldA64(const void* p) {
  return __hip_atomic_load((u64*)p, __ATOMIC_RELAXED, __HIP_MEMORY_SCOPE_AGENT);
}
DEV void stA64(void* p, u64 v) {
  __hip_atomic_store((u64*)p, v, __ATOMIC_RELAXED, __HIP_MEMORY_SCOPE_AGENT);
}
DEV void stA32(int* p, int v) {
  __hip_atomic_store(p, v, __ATOMIC_RELAXED, __HIP_MEMORY_SCOPE_AGENT);
}
DEV bf8 pk_frag(u64 lo, u64 hi) {
  u32x4 v = {(uint32)lo, (uint32)(lo >> 32), (uint32)hi, (uint32)(hi >> 32)};
  return __builtin_bit_cast(bf8, v);
}

// ---- sync primitives ----
DEV void wait_vm0() { asm volatile("s_waitcnt vmcnt(0)" ::: "memory"); }
// slot-based barrier: producers WRITE slot[i]=tgt (no RMW); one wave polls all
// slots with a coalesced lane-load + ballot. Call from a full wave.
DEV void wait_slots(const int* slots, int n, int tgt) {
  const int lane = threadIdx.x & 63;
  for (int i = 0; i < (1 << 21); ++i) {
    int v = 0x7fffffff;
    if (lane < n)
      v = __hip_atomic_load((int*)(slots + lane), __ATOMIC_RELAXED,
                            __HIP_MEMORY_SCOPE_AGENT);
    if (__all(v >= tgt)) return;
    __builtin_amdgcn_s_sleep(1);
  }
}

namespace L {
// sizes: B=32,S=60,T=59,V=50000,E=300(pad320),H=512,3H=1536
constexpr size_t o_flags  = 0;          // 1024 int
constexpr size_t o_rowsum = 4096;       // 1920 f32
constexpr size_t o_bcomb  = 11776;      // 1536 f32
constexpr size_t o_gistat = 17920;      // 32x1536 f32
constexpr size_t o_xbuf   = 214528;     // 2x32x1024 bf16  (attn | h)
constexpr size_t o_henc   = 345600;     // 2x32x512 bf16
constexpr size_t o_haff   = 411136;     // 2x32x512 bf16
constexpr size_t o_cat    = 476672;     // 32x1024 bf16 (state_enc | state_aff)
constexpr size_t o_Kbuf   = 542208;     // 1920x512 bf16 (row = s*32+b)
constexpr size_t o_KA     = 2508288;    // 1920x512 bf16
constexpr size_t o_embP   = 4474368;    // 1920x320 bf16
constexpr size_t o_embA   = 5703168;    // 1920x320 bf16
constexpr size_t o_embD   = 6931968;    // 1888x320 bf16
constexpr size_t o_encWi  = 8140288;    // 1536x320 bf16
constexpr size_t o_affWi  = 9123328;    // 1536x320 bf16
constexpr size_t o_Whe    = 10106368;   // 1536x512 bf16
constexpr size_t o_Wha    = 11679232;   // 1536x512 bf16
constexpr size_t o_decWi  = 13252096;   // 1536x512 bf16
constexpr size_t o_WlT    = 14824960;   // 1328x512 bf16
constexpr size_t o_Wa     = 16184832;   // 512x512 bf16
constexpr size_t o_Wp     = 16709120;   // 512x1024 bf16
constexpr size_t o_wq     = 17757696;   // 32768 uint4 (packed Wc^T pairs)
constexpr size_t o_Wcomb  = 18281984;   // 1536x1328 f32
constexpr size_t o_WdE    = 26441216;   // 1536x320 bf16
constexpr size_t o_WdA    = 27424256;   // 1536x512 bf16
constexpr size_t o_Wd2    = 28997120;   // 1536x1024 bf16 (Wcomb_attn | dec_Wh)
constexpr size_t o_giE    = 32142848;   // 1920x1536 f32
constexpr size_t o_giA    = 43939328;   // 1920x1536 f32
constexpr size_t o_giD    = 55735808;   // 1888x1536 f32
constexpr size_t o_outsB  = 67335680;   // 1920x1024 bf16 (row = t*32+b : h|attn)
constexpr size_t o_WvB    = 71267840;   // 50176x1024 bf16 (optional)
constexpr size_t WS_FULL  = 174028288;
constexpr size_t WOFF = 94400000;       // weights output offset (floats)
// slots (ints): [0..31] dec A; [64..127] dec B; [128..159] enc g0; [192..223] enc g1
}

// ---------------- prep (merged): gather | wconv | bcomb ----------------
__global__ __launch_bounds__(256) void kp_all(
    const int* __restrict__ posts, const int* __restrict__ resp,
    const float* __restrict__ emb, const float* __restrict__ aemb,
    const float* __restrict__ encWi, const float* __restrict__ affWi,
    const float* __restrict__ encWh, const float* __restrict__ affWh,
    const float* __restrict__ dWi, const float* __restrict__ Wl,
    const float* __restrict__ Wa, const float* __restrict__ Wp,
    const float* __restrict__ Wc, const float* __restrict__ bl,
    const float* __restrict__ dbi, char* ws)
{
  using namespace L;
  long gid = (long)blockIdx.x * 256 + threadIdx.x;
  if (gid < 1218560) {  // ---- gather: embeddings -> bf16, padded K=320 ----
    const int r = (int)(gid / 320), e = (int)(gid - (long)r * 320);
    u16* embP = (u16*)(ws + o_embP);
    u16* embA = (u16*)(ws + o_embA);
    u16* embD = (u16*)(ws + o_embD);
    if (r < 1920) {
      const int b = r & 31, s = r >> 5;
      const int tok = posts[b * 60 + s];
      embP[r * 320 + e] = f2bf(e < 300 ? emb[(size_t)tok * 300 + e] : 0.f);
      embA[r * 320 + e] = f2bf(e < 300 ? aemb[(size_t)tok * 300 + e] : 0.f);
    } else if (r < 3808) {
      const int r2 = r - 1920;
      const int b = r2 & 31, t = r2 >> 5;
      const int tok = resp[b * 60 + t];
      embD[r2 * 320 + e] = f2bf(e < 300 ? emb[(size_t)tok * 300 + e] : 0.f);
    }
    return;
  }
  gid -= 1218560;
  if (gid < 983040) {  // enc_Wi / aff_Wi -> [1536][320] bf16 (pad)
    const int g = gid >= 491520;
    const long u = gid - (g ? 491520 : 0);
    const int n = (int)(u / 320), e = (int)(u - (long)n * 320);
    const float* src = g ? affWi : encWi;
    u16* dst = (u16*)(ws + (g ? o_affWi : o_encWi));
    dst[u] = f2bf(e < 300 ? src[(size_t)n * 300 + e] : 0.f);
    return;
  }
  gid -= 983040;
  if (gid < 2359296) {  // enc_Wh / aff_Wh / dec_Wi -> bf16 direct
    const int g = (int)(gid / 786432);
    const long u = gid - (long)g * 786432;
    const float* src = g == 0 ? encWh : (g == 1 ? affWh : dWi);
    u16* dst = (u16*)(ws + (g == 0 ? o_Whe : (g == 1 ? o_Wha : o_decWi)));
    dst[u] = f2bf(src[u]);
    return;
  }
  gid -= 2359296;
  if (gid < 679936) {  // Wl^T -> [1328][512] bf16 (pad rows)
    const int j = (int)(gid >> 9), k = (int)(gid & 511);
    ((u16*)(ws + o_WlT))[gid] = f2bf(j < 1324 ? Wl[(size_t)k * 1324 + j] : 0.f);
    return;
  }
  gid -= 679936;
  if (gid < 262144) { ((u16*)(ws + o_Wa))[gid] = f2bf(Wa[gid]); return; }
  gid -= 262144;
  if (gid < 524288) { ((u16*)(ws + o_Wp))[gid] = f2bf(Wp[gid]); return; }
  gid -= 524288;
  if (gid < 131072) {  // packed Wc^T pairs: u32 idx = (g4*512+j)*4+q ; d0 = g4*8+q*2
    const int q = (int)(gid & 3), j = (int)((gid >> 2) & 511), g4 = (int)(gid >> 11);
    const int d0 = g4 * 8 + q * 2;
    const uint32 lo = f2bf(Wc[(size_t)j * 512 + d0]);
    const uint32 hi = f2bf(Wc[(size_t)j * 512 + d0 + 1]);
    ((uint32*)(ws + o_wq))[gid] = lo | (hi << 16);
    return;
  }
  gid -= 131072;
  if (gid < 2944) {  // zero flags + rowsum
    if (gid < 1024) ((uint32*)(ws + o_flags))[gid] = 0;
    else ((uint32*)(ws + o_rowsum))[gid - 1024] = 0;
    return;
  }
  gid -= 2944;
  if (gid < 49152) {  // zero: outsB pad rows, henc, haff (u32 words)
    if (gid < 16384) ((uint32*)(ws + o_outsB + (size_t)1888 * 1024 * 2))[gid] = 0;
    else if (gid < 32768) ((uint32*)(ws + o_henc))[gid - 16384] = 0;
    else ((uint32*)(ws + o_haff))[gid - 32768] = 0;
    return;
  }
  gid -= 49152;
  if (gid < 1536) {  // bcomb = dec_Wi @ bl + dec_bi
    const int i = (int)gid;
    float a = dbi[i];
    for (int k = 0; k < 512; ++k) a += dWi[(size_t)i * 512 + k] * bl[k];
    ((float*)(ws + L::o_bcomb))[i] = a;
  }
}

// ---------------- prep: split Wcomb into bf16 pieces ----------------
__global__ __launch_bounds__(256) void kp_pack2(
    const float* __restrict__ Wcomb, const float* __restrict__ dWh, char* ws)
{
  using namespace L;
  long gid = (long)blockIdx.x * 256 + threadIdx.x;
  if (gid < 491520) {  // Wd_emb [1536][320] <- Wcomb[:,0:300]
    const int n = (int)(gid / 320), e = (int)(gid - (long)n * 320);
    ((u16*)(ws + o_WdE))[gid] = f2bf(e < 300 ? Wcomb[(size_t)n * 1328 + e] : 0.f);
    return;
  }
  gid -= 491520;
  if (gid < 786432) {  // Wd_aff [1536][512] <- Wcomb[:,300:812]
    const int n = (int)(gid >> 9), k = (int)(gid & 511);
    ((u16*)(ws + o_WdA))[gid] = f2bf(Wcomb[(size_t)n * 1328 + 300 + k]);
    return;
  }
  gid -= 786432;
  if (gid < 1572864) {  // Wd2 [1536][1024] = [Wcomb[:,812:1324] | dec_Wh]
    const int n = (int)(gid >> 10), k = (int)(gid & 1023);
    const float v = (k < 512) ? Wcomb[(size_t)n * 1328 + 812 + k]
                              : dWh[(size_t)n * 512 + (k - 512)];
    ((u16*)(ws + o_Wd2))[gid] = f2bf(v);
  }
}

// ---------------- generic MFMA GEMM: C[M][N] = A[M][Kp] * B[N][Kp]^T (+bias) ----------------
__global__ __launch_bounds__(256) void k_gemm_nt(
    const u16* __restrict__ A, const u16* __restrict__ Bm,
    float* __restrict__ C, const float* __restrict__ bias,
    const int M, const int N, const int Kp)
{
  const int mt = blockIdx.x, cb = blockIdx.y;
  const int w = threadIdx.x >> 6, lane = threadIdx.x & 63;
  const int l15 = lane & 15, lhi = lane >> 4;
  const u16* arow = A + (size_t)(mt * 16 + l15) * Kp + lhi * 8;
  const int c0 = cb * 256 + w * 64;
  f4 acc[4];
#pragma unroll
  for (int nn = 0; nn < 4; ++nn) acc[nn] = (f4){0.f, 0.f, 0.f, 0.f};
  for (int k = 0; k < Kp; k += 32) {
    const bf8 a = *(const bf8*)(arow + k);
#pragma unroll
    for (int nn = 0; nn < 4; ++nn) {
      const int cs = c0 + nn * 16;
      if (cs < N) {
        const bf8 b = *(const bf8*)(Bm + (size_t)(cs + l15) * Kp + k + lhi * 8);
        acc[nn] = MFMA(a, b, acc[nn]);
      }
    }
  }
#pragma unroll
  for (int nn = 0; nn < 4; ++nn) {
    const int cs = c0 + nn * 16;
    if (cs >= N) continue;
    const int c = cs + l15;
    const float bb = bias ? bias[c] : 0.f;
#pragma unroll
    for (int j = 0; j < 4; ++j) {
      const int r = mt * 16 + lhi * 4 + j;
      C[(size_t)r * N + c] = acc[nn][j] + bb;
    }
  }
}

// ---------------- giE + giA in one launch (z selects) ----------------
__global__ __launch_bounds__(256) void k_gemm_gi(
    char* __restrict__ ws, const float* __restrict__ enc_bi,
    const float* __restrict__ aff_bi)
{
  using namespace L;
  const int z = blockIdx.z;
  const u16* A = (const u16*)(ws + (z ? o_embA : o_embP));
  const u16* Bm = (const u16*)(ws + (z ? o_affWi : o_encWi));
  float* C = (float*)(ws + (z ? o_giA : o_giE));
  const float* bias = z ? aff_bi : enc_bi;
  const int Kp = 320, N = 1536;
  const int mt = blockIdx.x, cb = blockIdx.y;
  const int w = threadIdx.x >> 6, lane = threadIdx.x & 63;
  const int l15 = lane & 15, lhi = lane >> 4;
  const u16* arow = A + (size_t)(mt * 16 + l15) * Kp + lhi * 8;
  const int c0 = cb * 256 + w * 64;
  f4 acc[4];
#pragma unroll
  for (int nn = 0; nn < 4; ++nn) acc[nn] = (f4){0.f, 0.f, 0.f, 0.f};
  for (int k = 0; k < Kp; k += 32) {
    const bf8 a = *(const bf8*)(arow + k);
#pragma unroll
    for (int nn = 0; nn < 4; ++nn) {
      const bf8 b = *(const bf8*)(Bm + (size_t)(c0 + nn * 16 + l15) * Kp + k + lhi * 8);
      acc[nn] = MFMA(a, b, acc[nn]);
    }
  }
#pragma unroll
  for (int nn = 0; nn < 4; ++nn) {
    const int c = c0 + nn * 16 + l15;
    const float bb = bias[c];
#pragma unroll
    for (int j = 0; j < 4; ++j)
      C[(size_t)(mt * 16 + lhi * 4 + j) * N + c] = acc[nn][j] + bb;
  }
}

// -------- encoder + fused bulk: blk<64 enc; blk<772 giD gemm; else Wv->bf16 ----
__global__ __launch_bounds__(256) void k_encplus(
    char* __restrict__ ws, const float* __restrict__ enc_bh,
    const float* __restrict__ aff_bh, const float* __restrict__ Wv)
{
  using namespace L;
  const int tid = threadIdx.x, blk = blockIdx.x;
  const int wave = tid >> 6, lane = tid & 63;
  const int l15 = lane & 15, lhi = lane >> 4;

  if (blk < 64) {
    // ===== encoder role (round-6 proven): 32 blocks per GRU, 2 active waves =====
    const int g = blk >> 5;
    const bool act = wave < 2;
    int* flags = (int*)(ws + o_flags);
    int* slotE = flags + 128 + g * 64;
    const u16* Wh = (const u16*)(ws + (g ? o_Wha : o_Whe));
    const float* gi = (const float*)(ws + (g ? o_giA : o_giE));
    const float* bh = g ? aff_bh : enc_bh;
    u16* hbuf = (u16*)(ws + (g ? o_haff : o_henc));
    u16* cat = (u16*)(ws + o_cat);
    u16* Kb = (u16*)(ws + o_Kbuf);

    const int wid = (blk & 31) * 2 + (wave & 1);     // 0..63 when act
    const int btile = wid >> 5, ctile = wid & 31;
    const int bl = btile * 16 + l15;
    const int c0 = ctile * 16 + lhi * 4;
    const u16* wr0 = Wh + (size_t)(ctile * 16 + l15) * 512 + lhi * 8;
    const u16* wr1 = wr0 + (size_t)512 * 512;
    const u16* wr2 = wr1 + (size_t)512 * 512;
    f4 bhr4 = {0.f, 0.f, 0.f, 0.f}, bhz4 = bhr4, bhn4 = bhr4;
    if (act) {
      bhr4 = *(const f4*)(bh + c0);
      bhz4 = *(const f4*)(bh + 512 + c0);
      bhn4 = *(const f4*)(bh + 1024 + c0);
    }
    for (int s = 0; s < 60; ++s) {
      const u16* hin = hbuf + (s & 1) * (32 * 512);
      u16* hout = hbuf + ((s & 1) ^ 1) * (32 * 512);
      if (act) {
        const u16* brow = hin + bl * 512 + lhi * 8;
        u64 flo[16], fhi[16];
#pragma unroll
        for (int kk = 0; kk < 16; ++kk) {      // batched: one exposed latency
          flo[kk] = ldA64(brow + kk * 32);
          fhi[kk] = ldA64(brow + kk * 32 + 4);
        }
        const u64 hq = ldA64(hin + bl * 512 + c0);
        f4 ar = {0.f, 0.f, 0.f, 0.f}, az = ar, an = ar;
#pragma unroll
        for (int kk = 0; kk < 16; ++kk) {
          const bf8 hf = pk_frag(flo[kk], fhi[kk]);
          ar = MFMA(*(const bf8*)(wr0 + kk * 32), hf, ar);
          az = MFMA(*(const bf8*)(wr1 + kk * 32), hf, az);
          an = MFMA(*(const bf8*)(wr2 + kk * 32), hf, an);
        }
        const float* gr = gi + (size_t)(s * 32 + bl) * 1536;
        const f4 g0 = *(const f4*)(gr + c0);
        const f4 g1 = *(const f4*)(gr + 512 + c0);
        const f4 g2 = *(const f4*)(gr + 1024 + c0);
        u64 pk = 0;
#pragma unroll
        for (int j = 0; j < 4; ++j) {
          const float r = sigmoid_(g0[j] + ar[j] + bhr4[j]);
          const float z = sigmoid_(g1[j] + az[j] + bhz4[j]);
          const float n = tanh_(g2[j] + r * (an[j] + bhn4[j]));
          const float hold = bf2f((u16)(hq >> (16 * j)));
          pk |= (u64)f2bf((1.f - z) * n + z * hold) << (16 * j);
        }
        stA64(hout + bl * 512 + c0, pk);
        if (g) *(u64*)(Kb + (size_t)(s * 32 + bl) * 512 + c0) = pk;  // next kernel
        if (s == 59) *(u64*)(cat + bl * 1024 + g * 512 + c0) = pk;   // next kernel
      }
      wait_vm0();
      __syncthreads();
      if (tid == 0) stA32(&slotE[blk & 31], s + 1);   // slot write, no RMW
      if (wave == 2) wait_slots(slotE, 32, s + 1);    // idle wave polls
      __syncthreads();
    }
  } else if (blk < 772) {
    // ===== giD = embD @ WdE^T  (fused; consumed by k_dec) =====
    const int bb = blk - 64;
    const int mt = bb % 118, cb = bb / 118;
    const u16* A = (const u16*)(ws + o_embD);
    const u16* Bm = (const u16*)(ws + o_WdE);
    float* C = (float*)(ws + o_giD);
    const int Kp = 320, N = 1536;
    const int w = wave;
    const u16* arow = A + (size_t)(mt * 16 + l15) * Kp + lhi * 8;
    const int c0 = cb * 256 + w * 64;
    f4 acc[4];
#pragma unroll
    for (int nn = 0; nn < 4; ++nn) acc[nn] = (f4){0.f, 0.f, 0.f, 0.f};
    for (int k = 0; k < Kp; k += 32) {
      const bf8 a = *(const bf8*)(arow + k);
#pragma unroll
      for (int nn = 0; nn < 4; ++nn) {
        const bf8 b = *(const bf8*)(Bm + (size_t)(c0 + nn * 16 + l15) * Kp + k + lhi * 8);
        acc[nn] = MFMA(a, b, acc[nn]);
      }
    }
#pragma unroll
    for (int nn = 0; nn < 4; ++nn) {
      const int c = c0 + nn * 16 + l15;
#pragma unroll
      for (int j = 0; j < 4; ++j)
        C[(size_t)(mt * 16 + lhi * 4 + j) * N + c] = acc[nn][j];
    }
  } else {
    // ===== Wv -> bf16 (padded rows) fused =====
    const long gid = (long)(blk - 772) * 256 + tid;
    const int r = (int)(gid >> 8), q = (int)(gid & 255);
    u16* WvB = (u16*)(ws + o_WvB);
    uint2 o;
    if (r < 50000) {
      const float4 f = *(const float4*)(Wv + (size_t)r * 1024 + q * 4);
      o.x = (uint32)f2bf(f.x) | ((uint32)f2bf(f.y) << 16);
      o.y = (uint32)f2bf(f.z) | ((uint32)f2bf(f.w) << 16);
    } else { o.x = 0u; o.y = 0u; }
    if (r < 50176) *(uint2*)(WvB + (size_t)r * 1024 + q * 4) = o;
  }
}

// ---------------- mid kernel: state0 | gi_static | KA (no sync needed) ----------
__global__ __launch_bounds__(256) void k_mid(char* __restrict__ ws,
                                             const float* __restrict__ bp)
{
  using namespace L;
  const int tid = threadIdx.x, blk = blockIdx.x;
  const int wave = tid >> 6, lane = tid & 63;
  const int l15 = lane & 15, lhi = lane >> 4;
  u16* xb = (u16*)(ws + o_xbuf);
  u16* cat = (u16*)(ws + o_cat);
  u16* Kb = (u16*)(ws + o_Kbuf);

  if (blk < 16) {  // state0 = tanh(cat @ Wp^T + bp) -> xbuf[0]; zero attn half
    const u16* Wp_ = (const u16*)(ws + o_Wp);
    const int wid = blk * 4 + wave;
    const int btile = wid >> 5, ctile = wid & 31;
    const int bl = btile * 16 + l15;
    const int c0 = ctile * 16 + lhi * 4;
    const u16* arow = Wp_ + (size_t)(ctile * 16 + l15) * 1024 + lhi * 8;
    const u16* brow = cat + bl * 1024 + lhi * 8;
    f4 acc = {0.f, 0.f, 0.f, 0.f};
    for (int k = 0; k < 1024; k += 32)
      acc = MFMA(*(const bf8*)(arow + k), *(const bf8*)(brow + k), acc);
    const f4 bp4 = *(const f4*)(bp + c0);
    u64 pk = 0;
#pragma unroll
    for (int j = 0; j < 4; ++j)
      pk |= (u64)f2bf(tanh_(acc[j] + bp4[j])) << (16 * j);
    *(u64*)(xb + bl * 1024 + 512 + c0) = pk;
    *(u64*)(xb + bl * 1024 + c0) = 0;          // init attn = 0
  } else if (blk < 32) {  // gi_static = ctx_aff @ Wd_aff^T + bcomb
    const u16* WdA = (const u16*)(ws + o_WdA);
    const float* bco = (const float*)(ws + o_bcomb);
    float* gst = (float*)(ws + o_gistat);
    const int wid = (blk - 16) * 4 + wave;
    const int btile = wid >> 5, ctb = wid & 31;
    const int bl = btile * 16 + l15;
    const int c0 = ctb * 16 + lhi * 4;
    const u16* brow = cat + bl * 1024 + 512 + lhi * 8;
    const u16* a0p = WdA + (size_t)(ctb * 16 + l15) * 512 + lhi * 8;
    const u16* a1p = a0p + (size_t)512 * 512;
    const u16* a2p = a1p + (size_t)512 * 512;
    f4 a0 = {0.f, 0.f, 0.f, 0.f}, a1 = a0, a2 = a0;
    for (int k = 0; k < 512; k += 32) {
      const bf8 bfr = *(const bf8*)(brow + k);
      a0 = MFMA(*(const bf8*)(a0p + k), bfr, a0);
      a1 = MFMA(*(const bf8*)(a1p + k), bfr, a1);
      a2 = MFMA(*(const bf8*)(a2p + k), bfr, a2);
    }
    const f4 v0 = *(const f4*)(bco + c0);
    const f4 v1 = *(const f4*)(bco + 512 + c0);
    const f4 v2 = *(const f4*)(bco + 1024 + c0);
    *(f4*)(gst + bl * 1536 + c0) = a0 + v0;
    *(f4*)(gst + bl * 1536 + 512 + c0) = a1 + v1;
    *(f4*)(gst + bl * 1536 + 1024 + c0) = a2 + v2;
  } else {  // KA = K @ Wa^T
    const u16* Wa_ = (const u16*)(ws + o_Wa);
    u16* KAp = (u16*)(ws + o_KA);
    const int widK = (blk - 32) * 4 + wave;
    for (int task = widK; task < 3840; task += 192) {
      const int mt = task >> 5, ct = task & 31;
      const int m = mt * 16 + l15;
      const int c0 = ct * 16 + lhi * 4;
      const u16* arow = Wa_ + (size_t)(ct * 16 + l15) * 512 + lhi * 8;
      const u16* brow = Kb + (size_t)m * 512 + lhi * 8;
      f4 acc = {0.f, 0.f, 0.f, 0.f};
      for (int k = 0; k < 512; k += 32)
        acc = MFMA(*(const bf8*)(arow + k), *(const bf8*)(brow + k), acc);
      u64 pk = 0;
#pragma unroll
      for (int j = 0; j < 4; ++j) pk |= (u64)f2bf(acc[j]) << (16 * j);
      *(u64*)(KAp + (size_t)m * 512 + c0) = pk;
    }
  }
}

// ---------------- decoder chain (round-6 proven): A=32 blocks, B=64 blocks ----
__global__ __launch_bounds__(256, 1) void k_dec(
    char* __restrict__ ws, float* __restrict__ out,
    const float* __restrict__ dec_bh, const float* __restrict__ bc)
{
  using namespace L;
  const int tid = threadIdx.x, blk = blockIdx.x;
  const int wave = tid >> 6, lane = tid & 63;
  const int l15 = lane & 15, lhi = lane >> 4;
  int* flags = (int*)(ws + o_flags);
  int* slotA = flags;        // 32
  int* slotB = flags + 64;   // 64

  __shared__ float hsm[512];
  __shared__ float ctxs[512];
  __shared__ float scb[64];
  __shared__ float wsb[64];
  __shared__ u16 attn_sm[256];

  u16* xb = (u16*)(ws + o_xbuf);
  u16* outs = (u16*)(ws + o_outsB);

  if (blk < 32) {
    // A-role: h_t = GRU from [attn_{t-1} ; h_{t-1}] via Wd2 (K=1024), n-gate split.
    const bool act = wave < 2;
    const u16* Wd2 = (const u16*)(ws + o_Wd2);
    const float* gst = (const float*)(ws + o_gistat);
    const float* gD = (const float*)(ws + o_giD);
    const int wid = (blk & 31) * 2 + (wave & 1);
    const int btile = wid >> 5, ctile = wid & 31;
    const int bl = btile * 16 + l15;
    const int c0 = ctile * 16 + lhi * 4;
    const u16* wr = Wd2 + (size_t)(ctile * 16 + l15) * 1024 + lhi * 8;
    const u16* wz = wr + (size_t)512 * 1024;
    const u16* wn = wz + (size_t)512 * 1024;
    f4 bhr4 = {0.f, 0.f, 0.f, 0.f}, bhz4 = bhr4, bhn4 = bhr4;
    f4 s0 = bhr4, s1 = bhr4, s2 = bhr4;
    if (act) {
      bhr4 = *(const f4*)(dec_bh + c0);
      bhz4 = *(const f4*)(dec_bh + 512 + c0);
      bhn4 = *(const f4*)(dec_bh + 1024 + c0);
      s0 = *(const f4*)(gst + bl * 1536 + c0);
      s1 = *(const f4*)(gst + bl * 1536 + 512 + c0);
      s2 = *(const f4*)(gst + bl * 1536 + 1024 + c0);
    }
    for (int t = 0; t < 59; ++t) {
      const u16* xin = xb + (t & 1) * (32 * 1024);
      u16* xout = xb + ((t & 1) ^ 1) * (32 * 1024);
      const u16* brow = xin + bl * 1024 + lhi * 8;
      f4 ar = {0.f, 0.f, 0.f, 0.f}, az = ar, anx = ar, anh = ar;
      u64 hq = 0;
      f4 d0 = ar, d1 = ar, d2 = ar;
      // ---- stage 1: needs h(t-1) = all A slots >= t ----
      if (t) {
        if (wave == 2) wait_slots(slotA, 32, t);
        __syncthreads();
      }
      if (act) {
        u64 flo[16], fhi[16];
#pragma unroll
        for (int kk = 0; kk < 16; ++kk) {
          flo[kk] = ldA64(brow + (16 + kk) * 32);
          fhi[kk] = ldA64(brow + (16 + kk) * 32 + 4);
        }
        hq = ldA64(xin + bl * 1024 + 512 + c0);
        const float* g2p = gD + (size_t)(t * 32 + bl) * 1536;   // static prefetch
        d0 = *(const f4*)(g2p + c0);
        d1 = *(const f4*)(g2p + 512 + c0);
        d2 = *(const f4*)(g2p + 1024 + c0);
#pragma unroll
        for (int kk = 0; kk < 16; ++kk) {
          const bf8 xf = pk_frag(flo[kk], fhi[kk]);
          ar = MFMA(*(const bf8*)(wr + (16 + kk) * 32), xf, ar);
          az = MFMA(*(const bf8*)(wz + (16 + kk) * 32), xf, az);
          anh = MFMA(*(const bf8*)(wn + (16 + kk) * 32), xf, anh);
        }
      }
      // ---- stage 2: needs attn(t-1) = all B slots >= t ----
      if (t) {
        if (wave == 2) wait_slots(slotB, 64, t);
        __syncthreads();
      }
      if (act) {
        u64 glo[16], ghi[16];
#pragma unroll
        for (int kk = 0; kk < 16; ++kk) {
          glo[kk] = ldA64(brow + kk * 32);
          ghi[kk] = ldA64(brow + kk * 32 + 4);
        }
#pragma unroll
        for (int kk = 0; kk < 16; ++kk) {
          const bf8 xf = pk_frag(glo[kk], ghi[kk]);
          ar = MFMA(*(const bf8*)(wr + kk * 32), xf, ar);
          az = MFMA(*(const bf8*)(wz + kk * 32), xf, az);
          anx = MFMA(*(const bf8*)(wn + kk * 32), xf, anx);
        }
        u64 pk = 0;
#pragma unroll
        for (int j = 0; j < 4; ++j) {
          const float r = sigmoid_(s0[j] + d0[j] + ar[j] + bhr4[j]);
          const float z = sigmoid_(s1[j] + d1[j] + az[j] + bhz4[j]);
          const float n = tanh_(s2[j] + d2[j] + anx[j] + r * (anh[j] + bhn4[j]));
          const float hold = bf2f((u16)(hq >> (16 * j)));
          pk |= (u64)f2bf((1.f - z) * n + z * hold) << (16 * j);
        }
        stA64(xout + bl * 1024 + 512 + c0, pk);
        stA64(outs + (size_t)(t * 32 + bl) * 1024 + c0, pk);  // t-major
      }
      wait_vm0();
      __syncthreads();
      if (tid == 0) stA32(&slotA[blk], t + 1);   // slot write, no RMW
    }
  } else {
    // B-role: 2 blocks per batch element: scores -> softmax -> ctx -> attn
    const int idx = blk - 32;
    const int b = idx >> 1, half = idx & 1;
    const u16* KAp = (const u16*)(ws + o_KA);
    const u16* Kb = (const u16*)(ws + o_Kbuf);
    const uint4* wq = (const uint4*)(ws + o_wq);
    for (int t = 0; t < 59; ++t) {
      if (wave == 0) wait_slots(slotA, 32, t + 1);
      __syncthreads();
      const u16* xcur = xb + ((t & 1) ^ 1) * (32 * 1024);
      if (tid < 128) {  // coherent-load h (written by A this step)
        const u64 hv = ldA64(xcur + b * 1024 + 512 + tid * 4);
        const uint32 w0 = (uint32)hv, w1 = (uint32)(hv >> 32);
        hsm[tid * 4 + 0] = bfLO(w0);
        hsm[tid * 4 + 1] = bfHI(w0);
        hsm[tid * 4 + 2] = bfLO(w1);
        hsm[tid * 4 + 3] = bfHI(w1);
      }
      __syncthreads();
      if (tid < 240) {  // scores[s] = h . KA[s,b,:]   (2 accumulator chains)
        const int s = tid >> 2, q = tid & 3;
        const u16* kr = KAp + (size_t)(s * 32 + b) * 512 + q * 128;
        const float* hq = &hsm[q * 128];
        float acc0 = 0.f, acc1 = 0.f;
#pragma unroll 4
        for (int i = 0; i < 128; i += 8) {
          const uint2 k4 = *(const uint2*)(kr + i);
          const uint2 k5 = *(const uint2*)(kr + i + 4);
          const float4 h4 = *(const float4*)(hq + i);
          const float4 h5 = *(const float4*)(hq + i + 4);
          acc0 += h4.x * bfLO(k4.x) + h4.y * bfHI(k4.x)
                + h4.z * bfLO(k4.y) + h4.w * bfHI(k4.y);
          acc1 += h5.x * bfLO(k5.x) + h5.y * bfHI(k5.x)
                + h5.z * bfLO(k5.y) + h5.w * bfHI(k5.y);
        }
        float acc = acc0 + acc1;
        acc += __shfl_xor(acc, 1);
        acc += __shfl_xor(acc, 2);
        if ((tid & 3) == 0) scb[s] = acc;
      }
      __syncthreads();
      if (tid < 64) {  // softmax over 60
        const float v = (tid < 60) ? scb[tid] : -1e30f;
        float m = v;
#pragma unroll
        for (int d = 1; d < 64; d <<= 1) m = fmaxf(m, __shfl_xor(m, d));
        const float e = (tid < 60) ? __expf(v - m) : 0.f;
        float sm = e;
#pragma unroll
        for (int d = 1; d < 64; d <<= 1) sm += __shfl_xor(sm, d);
        const float w = e / sm;
        if (tid < 60) {
          wsb[tid] = w;
          if (half == 0) out[WOFF + (size_t)(b * 59 + t) * 60 + tid] = w;
        }
      }
      __syncthreads();
      {  // ctx = sum_s w[s] * K[s,b,:]  (4 accumulator chains)
        float c0a = 0.f, c0b = 0.f, c1a = 0.f, c1b = 0.f;
#pragma unroll 2
        for (int s = 0; s < 60; s += 2) {
          const float w0 = wsb[s], w1 = wsb[s + 1];
          const u16* kr0 = Kb + (size_t)(s * 32 + b) * 512;
          const u16* kr1 = Kb + (size_t)((s + 1) * 32 + b) * 512;
          c0a += w0 * bf2f(kr0[tid]);
          c1a += w0 * bf2f(kr0[tid + 256]);
          c0b += w1 * bf2f(kr1[tid]);
          c1b += w1 * bf2f(kr1[tid + 256]);
        }
        ctxs[tid] = c0a + c0b;
        ctxs[tid + 256] = c1a + c1b;
      }
      __syncthreads();
      const int jj = half * 256 + tid;  // attn[jj] = tanh(bc + ctx . Wc[jj,:])
      float faa[4] = {0.f, 0.f, 0.f, 0.f};
      float fbb[4] = {0.f, 0.f, 0.f, 0.f};
#pragma unroll 4
      for (int g4 = 0; g4 < 64; ++g4) {
        const uint4 wv4 = wq[g4 * 512 + jj];
        const float4 ca = *(const float4*)&ctxs[g4 * 8];
        const float4 cb2 = *(const float4*)&ctxs[g4 * 8 + 4];
        faa[g4 & 3] += ca.x * bfLO(wv4.x) + ca.y * bfHI(wv4.x)
                     + ca.z * bfLO(wv4.y) + ca.w * bfHI(wv4.y);
        fbb[g4 & 3] += cb2.x * bfLO(wv4.z) + cb2.y * bfHI(wv4.z)
                     + cb2.z * bfLO(wv4.w) + cb2.w * bfHI(wv4.w);
      }
      const float fa = bc[jj] + faa[0] + faa[1] + faa[2] + faa[3]
                     + fbb[0] + fbb[1] + fbb[2] + fbb[3];
      attn_sm[tid] = f2bf(tanh_(fa));
      __syncthreads();
      if (tid < 64) {  // pack 4 attn values -> coherent u64 store
        u16* xout = xb + ((t & 1) ^ 1) * (32 * 1024);
        const u64 pk = (u64)attn_sm[tid * 4] | ((u64)attn_sm[tid * 4 + 1] << 16)
                     | ((u64)attn_sm[tid * 4 + 2] << 32) | ((u64)attn_sm[tid * 4 + 3] << 48);
        const int cc = half * 256 + tid * 4;
        stA64(xout + b * 1024 + cc, pk);
        stA64(outs + (size_t)(t * 32 + b) * 1024 + 512 + cc, pk);  // t-major
      }
      wait_vm0();
      __syncthreads();
      if (tid == 0) stA32(&slotB[idx], t + 1);   // slot write, no RMW
    }
  }
}

// ---------------- vocab GEMM (sequential, round-5 proven): LDS-staged --------
// C rows are t-major outs (row r -> out row (r&31)*59 + (r>>5), valid r>>5<59).
__global__ __launch_bounds__(512, 2) void k_vocab2s(
    const u16* __restrict__ A, const u16* __restrict__ Bm,
    const float* __restrict__ bvv, float* __restrict__ out,
    float* __restrict__ rowsum)
{
  __shared__ u16 As[2][128][40];
  __shared__ u16 Bs[2][256][40];
  const int tid = threadIdx.x;
  // bijective XCD swizzle (nwg=2940: q=367,r=4), then ntile-major for L2 reuse
  const int bid = blockIdx.x;
  const int xcd = bid & 7, sub = bid >> 3;
  const int wgid = (xcd < 4 ? xcd * 368 : 4 * 368 + (xcd - 4) * 367) + sub;
  const int mtile = wgid % 15, ntile = wgid / 15;
  const int rbase = mtile * 128, cbase = ntile * 256;

  const int wave = tid >> 6, lane = tid & 63;
  const int l15 = lane & 15, lhi = lane >> 4;
  const int m0 = (wave >> 2) * 64, n0 = (wave & 3) * 64;

  const int sar = tid >> 2, sak = (tid & 3) * 8;
  const u16* gA = A + (size_t)(rbase + sar) * 1024 + sak;
  const u16* gB0 = Bm + (size_t)(cbase + sar) * 1024 + sak;
  const u16* gB1 = Bm + (size_t)(cbase + 128 + sar) * 1024 + sak;

  f4 acc[4][4];
#pragma unroll
  for (int mi = 0; mi < 4; ++mi)
#pragma unroll
    for (int ni = 0; ni < 4; ++ni) acc[mi][ni] = (f4){0.f, 0.f, 0.f, 0.f};

  uint4 ra, rb0, rb1;
  ra = *(const uint4*)(gA);
  rb0 = *(const uint4*)(gB0);
  rb1 = *(const uint4*)(gB1);
  *(uint4*)&As[0][sar][sak] = ra;
  *(uint4*)&Bs[0][sar][sak] = rb0;
  *(uint4*)&Bs[0][128 + sar][sak] = rb1;
  __syncthreads();

  int cur = 0;
#pragma unroll 1
  for (int t = 0; t < 32; ++t) {
    if (t < 31) {
      const int k0 = (t + 1) * 32;
      ra = *(const uint4*)(gA + k0);
      rb0 = *(const uint4*)(gB0 + k0);
      rb1 = *(const uint4*)(gB1 + k0);
    }
    bf8 af[4], bfr[4];
#pragma unroll
    for (int mi = 0; mi < 4; ++mi)
      af[mi] = *(const bf8*)&As[cur][m0 + mi * 16 + l15][lhi * 8];
#pragma unroll
    for (int ni = 0; ni < 4; ++ni)
      bfr[ni] = *(const bf8*)&Bs[cur][n0 + ni * 16 + l15][lhi * 8];
#pragma unroll
    for (int mi = 0; mi < 4; ++mi)
#pragma unroll
      for (int ni = 0; ni < 4; ++ni)
        acc[mi][ni] = MFMA(af[mi], bfr[ni], acc[mi][ni]);
    if (t < 31) {
      __syncthreads();
      *(uint4*)&As[cur ^ 1][sar][sak] = ra;
      *(uint4*)&Bs[cur ^ 1][sar][sak] = rb0;
      *(uint4*)&Bs[cur ^ 1][128 + sar][sak] = rb1;
      __syncthreads();
      cur ^= 1;
    }
  }

  // epilogue: exp(acc + bv), store (t-major row -> b*59+t), rowsum atomics
#pragma unroll
  for (int mi = 0; mi < 4; ++mi) {
    float rs[4] = {0.f, 0.f, 0.f, 0.f};
    int ro_[4]; bool rv[4];
#pragma unroll
    for (int j = 0; j < 4; ++j) {
      const int r = rbase + m0 + mi * 16 + lhi * 4 + j;
      const int tt = r >> 5, bb2 = r & 31;
      rv[j] = tt < 59;
      ro_[j] = bb2 * 59 + tt;
    }
#pragma unroll
    for (int ni = 0; ni < 4; ++ni) {
      const int c = cbase + n0 + ni * 16 + l15;
      if (c < 50000) {
        const float bb = bvv[c];
#pragma unroll
        for (int j = 0; j < 4; ++j) {
          if (rv[j]) {
            const float e = __expf(acc[mi][ni][j] + bb);
            out[(size_t)ro_[j] * 50000 + c] = e;
            rs[j] += e;
          }
        }
      }
    }
#pragma unroll
    for (int j = 0; j < 4; ++j) {
#pragma unroll
      for (int d = 1; d < 16; d <<= 1) rs[j] += __shfl_xor(rs[j], d);
    }
    if (l15 == 0) {
#pragma unroll
      for (int j = 0; j < 4; ++j)
        if (rv[j]) atomicAdd(&rowsum[ro_[j]], rs[j]);
    }
  }
}

// ---------------- vocab GEMM fallback (no bf16 Wv copy; t-major outs) ---------
__global__ __launch_bounds__(512) void k_vocab0(
    const u16* __restrict__ A, const float* __restrict__ WvF,
    const float* __restrict__ bv, float* __restrict__ out,
    float* __restrict__ rowsum)
{
  const int bid = blockIdx.x;
  const int x = bid & 7, jj = bid >> 3;
  const int mtile = jj % 15, nseq = jj / 15;
  const int ntile = nseq * 8 + x;
  if (ntile >= 196) return;
  const int w = threadIdx.x >> 6, lane = threadIdx.x & 63;
  const int l15 = lane & 15, lhi = lane >> 4;
  const int rbase = mtile * 128 + w * 16;
  const u16* arow = A + (size_t)(rbase + l15) * 1024 + lhi * 8;
  const int cbase = ntile * 256;
  f4 acc[16];
#pragma unroll
  for (int nn = 0; nn < 16; ++nn) acc[nn] = (f4){0.f, 0.f, 0.f, 0.f};
  for (int k = 0; k < 1024; k += 32) {
    const bf8 a = *(const bf8*)(arow + k);
#pragma unroll
    for (int nn = 0; nn < 16; ++nn) {
      const int cs = cbase + nn * 16;
      bf8 bfr = {0, 0, 0, 0, 0, 0, 0, 0};
      if (cs < 50000) {
        const float* p = WvF + (size_t)(cs + l15) * 1024 + k + lhi * 8;
        const float4 f0 = *(const float4*)p;
        const float4 f1 = *(const float4*)(p + 4);
        bfr[0] = (short)(__float_as_uint(f0.x) >> 16);
        bfr[1] = (short)(__float_as_uint(f0.y) >> 16);
        bfr[2] = (short)(__float_as_uint(f0.z) >> 16);
        bfr[3] = (short)(__float_as_uint(f0.w) >> 16);
        bfr[4] = (short)(__float_as_uint(f1.x) >> 16);
        bfr[5] = (short)(__float_as_uint(f1.y) >> 16);
        bfr[6] = (short)(__float_as_uint(f1.z) >> 16);
        bfr[7] = (short)(__float_as_uint(f1.w) >> 16);
      }
      acc[nn] = MFMA(a, bfr, acc[nn]);
    }
  }
#pragma unroll
  for (int j = 0; j < 4; ++j) {
    const int r = rbase + lhi * 4 + j;
    const int tt = r >> 5, bb2 = r & 31;
    if (tt >= 59) continue;
    const int ro = bb2 * 59 + tt;
    float rsv = 0.f;
#pragma unroll
    for (int nn = 0; nn < 16; ++nn) {
      const int cs = cbase + nn * 16;
      if (cs >= 50000) continue;
      const int c = cs + l15;
      const float e = __expf(acc[nn][j] + bv[c]);
      out[(size_t)ro * 50000 + c] = e;
      rsv += e;
    }
#pragma unroll
    for (int d = 1; d < 16; d <<= 1) rsv += __shfl_xor(rsv, d);
    if (l15 == 0) atomicAdd(&rowsum[ro], rsv);
  }
}

// ---------------- scale exp values by 1/rowsum (reciprocal inline) ------------
__global__ __launch_bounds__(256) void k_scale(float* __restrict__ out,
                                               const float* __restrict__ rowsum)
{
  const int bid = blockIdx.x;
  const int r = bid / 49, ch = bid - r * 49;
  const int c = ch * 1024 + threadIdx.x * 4;
  if (c < 50000) {
    const float sden = rowsum[r];
    const float s = (sden > 0.f) ? 1.f / sden : 0.f;
    float4* p = (float4*)(out + (size_t)r * 50000 + c);
    float4 v = *p;
    v.x *= s; v.y *= s; v.z *= s; v.w *= s;
    *p = v;
  }
}

extern "C" void kernel_launch(void* const* d_in, const int* in_sizes, int n_in,
                              void* d_out, int out_size, void* d_ws, size_t ws_size,
                              hipStream_t stream) {
  const int* posts = (const int*)d_in[0];
  const int* resp = (const int*)d_in[1];
  const float* emb = (const float*)d_in[3];
  const float* aemb = (const float*)d_in[4];
  const float* encWi = (const float*)d_in[5];
  const float* encWh = (const float*)d_in[6];
  const float* enc_bi = (const float*)d_in[7];
  const float* enc_bh = (const float*)d_in[8];
  const float* affWi = (const float*)d_in[9];
  const float* affWh = (const float*)d_in[10];
  const float* aff_bi = (const float*)d_in[11];
  const float* aff_bh = (const float*)d_in[12];
  const float* Wp = (const float*)d_in[13];
  const float* bp = (const float*)d_in[14];
  const float* Wl = (const float*)d_in[15];
  const float* bl = (const float*)d_in[16];
  const float* dWi = (const float*)d_in[17];
  const float* dWh = (const float*)d_in[18];
  const float* dbi = (const float*)d_in[19];
  const float* dbh = (const float*)d_in[20];
  const float* Wa = (const float*)d_in[21];
  const float* Wc = (const float*)d_in[22];
  const float* bc = (const float*)d_in[23];
  const float* Wv = (const float*)d_in[24];
  const float* bv = (const float*)d_in[25];
  char* ws = (char*)d_ws;
  float* out = (float*)d_out;
  const bool useWvB = ws_size >= L::WS_FULL;

  // prep: gather + weight conversions + bcomb (merged)
  kp_all<<<24266, 256, 0, stream>>>(posts, resp, emb, aemb, encWi, affWi,
                                    encWh, affWh, dWi, Wl, Wa, Wp, Wc, bl,
                                    dbi, ws);

  // Wcomb = dec_Wi @ Wl  -> f32 [1536][1328]
  k_gemm_nt<<<dim3(96, 6), 256, 0, stream>>>(
      (const u16*)(ws + L::o_decWi), (const u16*)(ws + L::o_WlT),
      (float*)(ws + L::o_Wcomb), nullptr, 1536, 1328, 512);
  kp_pack2<<<11136, 256, 0, stream>>>((const float*)(ws + L::o_Wcomb), dWh, ws);

  // input-gate precomputes giE + giA (one launch; giD fused into k_encplus)
  k_gemm_gi<<<dim3(120, 6, 2), 256, 0, stream>>>(ws, enc_bi, aff_bi);

  // encoder chain + fused bulk (giD gemm + Wv->bf16 conversion)
  k_encplus<<<useWvB ? 50948 : 772, 256, 0, stream>>>(ws, enc_bh, aff_bh, Wv);
  k_mid<<<80, 256, 0, stream>>>(ws, bp);

  // decoder chain (pure, round-6 proven)
  k_dec<<<96, 256, 0, stream>>>(ws, out, dbh, bc);

  // vocab GEMM (sequential, LDS-staged, XCD-swizzled for B reuse)
  if (useWvB)
    k_vocab2s<<<2940, 512, 0, stream>>>(
        (const u16*)(ws + L::o_outsB), (const u16*)(ws + L::o_WvB),
        bv, out, (float*)(ws + L::o_rowsum));
  else
    k_vocab0<<<2944, 512, 0, stream>>>(
        (const u16*)(ws + L::o_outsB), Wv, bv, out, (float*)(ws + L::o_rowsum));

  k_scale<<<92512, 256, 0, stream>>>(out, (const float*)(ws + L::o_rowsum));
}